// Round 1
// baseline (13414.847 us; speedup 1.0000x reference)
//
#include <hip/hip_runtime.h>

// Problem constants (match reference)
constexpr int Nn   = 100000;   // nodes
constexpr int Ne   = 1600000;  // edges
constexpr int NF   = 16;       // input features
constexpr int HID  = 64;
constexpr int NOUT = 4;

// ---------------- norm precompute ----------------

__global__ __launch_bounds__(256) void deg_kernel(const int* __restrict__ dst,
                                                  float* __restrict__ deg) {
    int e = blockIdx.x * 256 + threadIdx.x;
    if (e < Ne) atomicAdd(&deg[dst[e]], 1.0f);
}

__global__ __launch_bounds__(256) void dinv_kernel(float* __restrict__ deg) {
    int i = blockIdx.x * 256 + threadIdx.x;
    if (i < Nn) {
        float d = deg[i];
        deg[i] = d > 0.0f ? 1.0f / sqrtf(d) : 0.0f;
    }
}

__global__ __launch_bounds__(256) void norm_kernel(const int* __restrict__ src,
                                                   const int* __restrict__ dst,
                                                   const float* __restrict__ dinv,
                                                   float* __restrict__ norm) {
    int e = blockIdx.x * 256 + threadIdx.x;
    if (e < Ne) norm[e] = dinv[src[e]] * dinv[dst[e]];
}

// ---------------- propagation (scatter/push, atomics) ----------------
// F = feature width (16 or 64). F/4 threads per edge, float4 gather.

template <int F>
__global__ __launch_bounds__(256) void propagate_kernel(const float* __restrict__ hin,
                                                        const float* __restrict__ norm,
                                                        const int* __restrict__ src,
                                                        const int* __restrict__ dst,
                                                        float* __restrict__ hout) {
    constexpr int TPE = F / 4;
    long long tid = (long long)blockIdx.x * 256 + threadIdx.x;
    int e = (int)(tid / TPE);
    int q = (int)(tid % TPE);
    if (e >= Ne) return;
    int s = src[e];
    int d = dst[e];
    float w = norm[e];
    float4 v = reinterpret_cast<const float4*>(hin + (size_t)s * F)[q];
    float* o = hout + (size_t)d * F + q * 4;
    atomicAdd(o + 0, w * v.x);
    atomicAdd(o + 1, w * v.y);
    atomicAdd(o + 2, w * v.z);
    atomicAdd(o + 3, w * v.w);
}

// ---------------- small-K GEMM: out[N,64] (+)= h[N,FIN] @ W[FIN,64] ----------------
// MODE 0: acc = h@W ; MODE 1: acc += h@W ; MODE 2: out = maybe_relu(accin + h@W + bias)

template <int FIN, int MODE>
__global__ __launch_bounds__(256) void gemm_kernel(const float* __restrict__ h,
                                                   const float* __restrict__ W,
                                                   const float* __restrict__ bias,
                                                   const float* __restrict__ accin,
                                                   float* __restrict__ out,
                                                   int do_relu) {
    __shared__ float Wl[FIN * HID];
    __shared__ float hl[4][FIN];
    int tid = threadIdx.x;
    for (int i = tid; i < FIN * HID; i += 256) Wl[i] = W[i];
    int r0 = blockIdx.x * 4;
    for (int i = tid; i < 4 * FIN; i += 256)
        hl[i / FIN][i % FIN] = h[(size_t)(r0 + i / FIN) * FIN + (i % FIN)];
    __syncthreads();

    int rl = tid >> 6;
    int c  = tid & 63;
    size_t r = (size_t)(r0 + rl);

    float a = (MODE == 0) ? 0.0f : accin[r * HID + c];
#pragma unroll
    for (int f = 0; f < FIN; ++f) a += hl[rl][f] * Wl[f * HID + c];

    if (MODE == 2) {
        a += bias[c];
        if (do_relu) a = fmaxf(a, 0.0f);
    }
    out[r * HID + c] = a;
}

// ---------------- final FC: out[N,4] = h[N,64] @ fcW[64,4] + fcb ----------------

__global__ __launch_bounds__(256) void fc_kernel(const float* __restrict__ h,
                                                 const float* __restrict__ W,
                                                 const float* __restrict__ b,
                                                 float* __restrict__ out) {
    __shared__ float Wl[HID * NOUT];
    int tid = threadIdx.x;
    for (int i = tid; i < HID * NOUT; i += 256) Wl[i] = W[i];
    __syncthreads();
    int r = blockIdx.x * 256 + tid;
    if (r >= Nn) return;
    const float4* hp = reinterpret_cast<const float4*>(h + (size_t)r * HID);
    float acc0 = 0.f, acc1 = 0.f, acc2 = 0.f, acc3 = 0.f;
#pragma unroll
    for (int q = 0; q < HID / 4; ++q) {
        float4 v = hp[q];
#pragma unroll
        for (int j = 0; j < 4; ++j) {
            float wv = v.x * Wl[(q * 4 + 0) * NOUT + j] + v.y * Wl[(q * 4 + 1) * NOUT + j] +
                       v.z * Wl[(q * 4 + 2) * NOUT + j] + v.w * Wl[(q * 4 + 3) * NOUT + j];
            if (j == 0) acc0 += wv;
            else if (j == 1) acc1 += wv;
            else if (j == 2) acc2 += wv;
            else acc3 += wv;
        }
    }
    float* o = out + (size_t)r * NOUT;
    o[0] = acc0 + b[0];
    o[1] = acc1 + b[1];
    o[2] = acc2 + b[2];
    o[3] = acc3 + b[3];
}

// ---------------- host-side conv driver ----------------

template <int FIN>
static void run_conv(const float* hin,        // [N, FIN] layer input
                     const float* W,          // [K+1, FIN, HID]
                     const float* bias,       // [HID]
                     int do_relu,
                     const int* src, const int* dst, const float* norm,
                     float* bufA, float* bufB, float* acc, float* hout,
                     hipStream_t stream) {
    constexpr int TPE = FIN / 4;
    const int gemm_grid = Nn / 4;
    const int prop_grid = (int)(((long long)Ne * TPE + 255) / 256);
    const size_t pbytes = (size_t)Nn * FIN * sizeof(float);

    // k=0
    gemm_kernel<FIN, 0><<<gemm_grid, 256, 0, stream>>>(hin, W, nullptr, nullptr, acc, 0);
    // k=1: hin -> bufA
    hipMemsetAsync(bufA, 0, pbytes, stream);
    propagate_kernel<FIN><<<prop_grid, 256, 0, stream>>>(hin, norm, src, dst, bufA);
    gemm_kernel<FIN, 1><<<gemm_grid, 256, 0, stream>>>(bufA, W + 1 * FIN * HID, nullptr, acc, acc, 0);
    // k=2: bufA -> bufB  (layer input no longer needed)
    hipMemsetAsync(bufB, 0, pbytes, stream);
    propagate_kernel<FIN><<<prop_grid, 256, 0, stream>>>(bufA, norm, src, dst, bufB);
    gemm_kernel<FIN, 1><<<gemm_grid, 256, 0, stream>>>(bufB, W + 2 * FIN * HID, nullptr, acc, acc, 0);
    // k=3: bufB -> bufA
    hipMemsetAsync(bufA, 0, pbytes, stream);
    propagate_kernel<FIN><<<prop_grid, 256, 0, stream>>>(bufB, norm, src, dst, bufA);
    // final: hout = maybe_relu(acc + bufA@W3 + bias)   (hout may alias bufB: safe, bufB consumed)
    gemm_kernel<FIN, 2><<<gemm_grid, 256, 0, stream>>>(bufA, W + 3 * FIN * HID, bias, acc, hout, do_relu);
}

extern "C" void kernel_launch(void* const* d_in, const int* in_sizes, int n_in,
                              void* d_out, int out_size, void* d_ws, size_t ws_size,
                              hipStream_t stream) {
    const float* x   = (const float*)d_in[0];
    const int*   ei  = (const int*)d_in[1];   // [2, E] int32
    const float* W0  = (const float*)d_in[2]; // [4,16,64]
    const float* b0  = (const float*)d_in[3]; // [64]
    const float* Wh  = (const float*)d_in[4]; // [3,4,64,64]
    const float* bh  = (const float*)d_in[5]; // [3,64]
    const float* fcW = (const float*)d_in[6]; // [64,4]
    const float* fcb = (const float*)d_in[7]; // [4]
    float* out = (float*)d_out;

    const int* src = ei;
    const int* dst = ei + Ne;

    // workspace layout (floats): deg[N] | norm[E] | bufA[N*64] | bufB[N*64] | acc[N*64]
    float* ws   = (float*)d_ws;
    float* deg  = ws;
    float* norm = ws + Nn;
    float* bufA = norm + Ne;
    float* bufB = bufA + (size_t)Nn * HID;
    float* acc  = bufB + (size_t)Nn * HID;

    // --- GCN norm ---
    hipMemsetAsync(deg, 0, Nn * sizeof(float), stream);
    deg_kernel<<<(Ne + 255) / 256, 256, 0, stream>>>(dst, deg);
    dinv_kernel<<<(Nn + 255) / 256, 256, 0, stream>>>(deg);
    norm_kernel<<<(Ne + 255) / 256, 256, 0, stream>>>(src, dst, deg, norm);

    // --- conv0: x[N,16] -> bufB[N,64], relu ---
    run_conv<NF>(x, W0, b0, /*relu=*/1, src, dst, norm, bufA, bufB, acc, bufB, stream);

    // --- middle convs (relu) + last conv (no relu): bufB -> bufB ---
    for (int l = 0; l < 3; ++l) {
        int relu = (l < 2) ? 1 : 0;
        run_conv<HID>(bufB, Wh + (size_t)l * 4 * HID * HID, bh + (size_t)l * HID, relu,
                      src, dst, norm, bufA, bufB, acc, bufB, stream);
    }

    // --- final FC ---
    fc_kernel<<<(Nn + 255) / 256, 256, 0, stream>>>(bufB, fcW, fcb, out);
}

// Round 2
// 1991.100 us; speedup vs baseline: 6.7374x; 6.7374x over previous
//
#include <hip/hip_runtime.h>

// Problem constants (match reference)
constexpr int Nn   = 100000;   // nodes
constexpr int Ne   = 1600000;  // edges
constexpr int NF   = 16;       // input features
constexpr int HID  = 64;
constexpr int NOUT = 4;

// ---------------- CSR build ----------------

__global__ __launch_bounds__(256) void hist_kernel(const int* __restrict__ dst,
                                                   int* __restrict__ cnt) {
    int e = blockIdx.x * 256 + threadIdx.x;
    if (e < Ne) atomicAdd(&cnt[dst[e]], 1);
}

// single-block exclusive scan of cnt[N] -> rowptr[N+1]; also dinv = 1/sqrt(deg)
__global__ __launch_bounds__(1024) void scan_kernel(const int* __restrict__ cnt,
                                                    int* __restrict__ rowptr,
                                                    float* __restrict__ dinv) {
    __shared__ int part[1024];
    const int t = threadIdx.x;
    const int chunk = (Nn + 1023) / 1024;  // 98
    const int lo = t * chunk;
    const int hi = lo + chunk < Nn ? lo + chunk : Nn;
    int s = 0;
    for (int i = lo; i < hi; ++i) s += cnt[i];
    part[t] = s;
    __syncthreads();
    // Hillis-Steele inclusive scan over 1024 partials
    for (int off = 1; off < 1024; off <<= 1) {
        int v = part[t];
        int u = (t >= off) ? part[t - off] : 0;
        __syncthreads();
        part[t] = v + u;
        __syncthreads();
    }
    int run = (t > 0) ? part[t - 1] : 0;
    for (int i = lo; i < hi; ++i) {
        rowptr[i] = run;
        int c = cnt[i];
        run += c;
        dinv[i] = c > 0 ? 1.0f / sqrtf((float)c) : 0.0f;
    }
    if (t == 1023) rowptr[Nn] = part[1023];
}

__global__ __launch_bounds__(256) void scatter_kernel(const int* __restrict__ src,
                                                      const int* __restrict__ dst,
                                                      const int* __restrict__ rowptr,
                                                      int* __restrict__ cnt,
                                                      int* __restrict__ col) {
    int e = blockIdx.x * 256 + threadIdx.x;
    if (e < Ne) {
        int d = dst[e];
        int p = rowptr[d] + atomicAdd(&cnt[d], 1);
        col[p] = src[e];
    }
}

// ---------------- pull-mode propagation ----------------
// F lanes per node; each lane owns one feature column. One row-gather per edge.
// hout[n,:] = dinv[n] * sum_{e in row n} dinv[col[e]] * hin[col[e],:]

template <int F>
__global__ __launch_bounds__(256) void pull_kernel(const float* __restrict__ hin,
                                                   const int* __restrict__ rowptr,
                                                   const int* __restrict__ col,
                                                   const float* __restrict__ dinv,
                                                   float* __restrict__ hout) {
    constexpr int NPB = 256 / F;
    int n = blockIdx.x * NPB + threadIdx.x / F;
    int c = threadIdx.x % F;
    if (n >= Nn) return;
    int r0 = rowptr[n];
    int r1 = rowptr[n + 1];
    float dn = dinv[n];
    float acc = 0.0f;
    int e = r0;
    for (; e + 4 <= r1; e += 4) {
        int s0 = col[e + 0], s1 = col[e + 1], s2 = col[e + 2], s3 = col[e + 3];
        float w0 = dinv[s0], w1 = dinv[s1], w2 = dinv[s2], w3 = dinv[s3];
        float v0 = hin[(size_t)s0 * F + c];
        float v1 = hin[(size_t)s1 * F + c];
        float v2 = hin[(size_t)s2 * F + c];
        float v3 = hin[(size_t)s3 * F + c];
        acc += w0 * v0;
        acc += w1 * v1;
        acc += w2 * v2;
        acc += w3 * v3;
    }
    for (; e < r1; ++e) {
        int s = col[e];
        acc += dinv[s] * hin[(size_t)s * F + c];
    }
    hout[(size_t)n * F + c] = acc * dn;
}

// ---------------- small-K GEMM: out[N,64] (+)= h[N,FIN] @ W[FIN,64] ----------------
// MODE 0: acc = h@W ; MODE 1: acc += h@W ; MODE 2: out = maybe_relu(accin + h@W + bias)

template <int FIN, int MODE>
__global__ __launch_bounds__(256) void gemm_kernel(const float* __restrict__ h,
                                                   const float* __restrict__ W,
                                                   const float* __restrict__ bias,
                                                   const float* __restrict__ accin,
                                                   float* __restrict__ out,
                                                   int do_relu) {
    __shared__ float Wl[FIN * HID];
    __shared__ float hl[4][FIN];
    int tid = threadIdx.x;
    for (int i = tid; i < FIN * HID; i += 256) Wl[i] = W[i];
    int r0 = blockIdx.x * 4;
    for (int i = tid; i < 4 * FIN; i += 256)
        hl[i / FIN][i % FIN] = h[(size_t)(r0 + i / FIN) * FIN + (i % FIN)];
    __syncthreads();

    int rl = tid >> 6;
    int c  = tid & 63;
    size_t r = (size_t)(r0 + rl);

    float a = (MODE == 0) ? 0.0f : accin[r * HID + c];
#pragma unroll
    for (int f = 0; f < FIN; ++f) a += hl[rl][f] * Wl[f * HID + c];

    if (MODE == 2) {
        a += bias[c];
        if (do_relu) a = fmaxf(a, 0.0f);
    }
    out[r * HID + c] = a;
}

// ---------------- final FC: out[N,4] = h[N,64] @ fcW[64,4] + fcb ----------------

__global__ __launch_bounds__(256) void fc_kernel(const float* __restrict__ h,
                                                 const float* __restrict__ W,
                                                 const float* __restrict__ b,
                                                 float* __restrict__ out) {
    __shared__ float Wl[HID * NOUT];
    int tid = threadIdx.x;
    for (int i = tid; i < HID * NOUT; i += 256) Wl[i] = W[i];
    __syncthreads();
    int r = blockIdx.x * 256 + tid;
    if (r >= Nn) return;
    const float4* hp = reinterpret_cast<const float4*>(h + (size_t)r * HID);
    float acc0 = 0.f, acc1 = 0.f, acc2 = 0.f, acc3 = 0.f;
#pragma unroll
    for (int q = 0; q < HID / 4; ++q) {
        float4 v = hp[q];
#pragma unroll
        for (int j = 0; j < 4; ++j) {
            float wv = v.x * Wl[(q * 4 + 0) * NOUT + j] + v.y * Wl[(q * 4 + 1) * NOUT + j] +
                       v.z * Wl[(q * 4 + 2) * NOUT + j] + v.w * Wl[(q * 4 + 3) * NOUT + j];
            if (j == 0) acc0 += wv;
            else if (j == 1) acc1 += wv;
            else if (j == 2) acc2 += wv;
            else acc3 += wv;
        }
    }
    float* o = out + (size_t)r * NOUT;
    o[0] = acc0 + b[0];
    o[1] = acc1 + b[1];
    o[2] = acc2 + b[2];
    o[3] = acc3 + b[3];
}

// ---------------- host-side conv driver ----------------

template <int FIN>
static void run_conv(const float* hin,        // [N, FIN] layer input
                     const float* W,          // [K+1, FIN, HID]
                     const float* bias,       // [HID]
                     int do_relu,
                     const int* rowptr, const int* col, const float* dinv,
                     float* bufA, float* bufB, float* acc, float* hout,
                     hipStream_t stream) {
    const int gemm_grid = Nn / 4;
    constexpr int NPB = 256 / FIN;
    const int pull_grid = (Nn + NPB - 1) / NPB;

    // k=0
    gemm_kernel<FIN, 0><<<gemm_grid, 256, 0, stream>>>(hin, W, nullptr, nullptr, acc, 0);
    // k=1: hin -> bufA
    pull_kernel<FIN><<<pull_grid, 256, 0, stream>>>(hin, rowptr, col, dinv, bufA);
    gemm_kernel<FIN, 1><<<gemm_grid, 256, 0, stream>>>(bufA, W + 1 * FIN * HID, nullptr, acc, acc, 0);
    // k=2: bufA -> bufB  (layer input no longer needed afterwards)
    pull_kernel<FIN><<<pull_grid, 256, 0, stream>>>(bufA, rowptr, col, dinv, bufB);
    gemm_kernel<FIN, 1><<<gemm_grid, 256, 0, stream>>>(bufB, W + 2 * FIN * HID, nullptr, acc, acc, 0);
    // k=3: bufB -> bufA
    pull_kernel<FIN><<<pull_grid, 256, 0, stream>>>(bufB, rowptr, col, dinv, bufA);
    // final: hout = maybe_relu(acc + bufA@W3 + bias)
    gemm_kernel<FIN, 2><<<gemm_grid, 256, 0, stream>>>(bufA, W + 3 * FIN * HID, bias, acc, hout, do_relu);
}

extern "C" void kernel_launch(void* const* d_in, const int* in_sizes, int n_in,
                              void* d_out, int out_size, void* d_ws, size_t ws_size,
                              hipStream_t stream) {
    const float* x   = (const float*)d_in[0];
    const int*   ei  = (const int*)d_in[1];   // [2, E] int32
    const float* W0  = (const float*)d_in[2]; // [4,16,64]
    const float* b0  = (const float*)d_in[3]; // [64]
    const float* Wh  = (const float*)d_in[4]; // [3,4,64,64]
    const float* bh  = (const float*)d_in[5]; // [3,64]
    const float* fcW = (const float*)d_in[6]; // [64,4]
    const float* fcb = (const float*)d_in[7]; // [4]
    float* out = (float*)d_out;

    const int* src = ei;
    const int* dst = ei + Ne;

    // workspace layout: rowptr[N+1] int | col[E] int | dinv[N] f32 | bufA[N*64] | bufB[N*64] | acc[N*64]
    int*   rowptr = (int*)d_ws;
    int*   col    = rowptr + (Nn + 1);
    float* dinv   = (float*)(col + Ne);
    float* bufA   = dinv + Nn;
    float* bufB   = bufA + (size_t)Nn * HID;
    float* acc    = bufB + (size_t)Nn * HID;
    int*   cnt    = (int*)bufA;  // build-time alias; bufA reused afterwards

    // --- CSR build + dinv ---
    hipMemsetAsync(cnt, 0, Nn * sizeof(int), stream);
    hist_kernel<<<(Ne + 255) / 256, 256, 0, stream>>>(dst, cnt);
    scan_kernel<<<1, 1024, 0, stream>>>(cnt, rowptr, dinv);
    hipMemsetAsync(cnt, 0, Nn * sizeof(int), stream);
    scatter_kernel<<<(Ne + 255) / 256, 256, 0, stream>>>(src, dst, rowptr, cnt, col);

    // --- conv0: x[N,16] -> bufB[N,64], relu ---
    run_conv<NF>(x, W0, b0, /*relu=*/1, rowptr, col, dinv, bufA, bufB, acc, bufB, stream);

    // --- middle convs (relu) + last conv (no relu): bufB -> bufB ---
    for (int l = 0; l < 3; ++l) {
        int relu = (l < 2) ? 1 : 0;
        run_conv<HID>(bufB, Wh + (size_t)l * 4 * HID * HID, bh + (size_t)l * HID, relu,
                      rowptr, col, dinv, bufA, bufB, acc, bufB, stream);
    }

    // --- final FC ---
    fc_kernel<<<(Nn + 255) / 256, 256, 0, stream>>>(bufB, fcW, fcb, out);
}

// Round 3
// 1211.494 us; speedup vs baseline: 11.0730x; 1.6435x over previous
//
#include <hip/hip_runtime.h>

// Problem constants (match reference)
constexpr int Nn   = 100000;   // nodes
constexpr int Ne   = 1600000;  // edges
constexpr int NF   = 16;       // input features
constexpr int HID  = 64;
constexpr int NOUT = 4;

// ================= CSR build =================

__global__ __launch_bounds__(256) void hist_kernel(const int* __restrict__ dst,
                                                   int* __restrict__ cnt) {
    int e = blockIdx.x * 256 + threadIdx.x;
    if (e < Ne) atomicAdd(&cnt[dst[e]], 1);
}

// phase1: each block scans 1024 elements (4/thread), local exclusive scan -> rowptr,
// block total -> bsum[b]
__global__ __launch_bounds__(256) void scan1_kernel(const int* __restrict__ cnt,
                                                    int* __restrict__ rowptr,
                                                    int* __restrict__ bsum) {
    __shared__ int lds[256];
    int t = threadIdx.x;
    int base = blockIdx.x * 1024 + t * 4;
    int v0 = (base + 0 < Nn) ? cnt[base + 0] : 0;
    int v1 = (base + 1 < Nn) ? cnt[base + 1] : 0;
    int v2 = (base + 2 < Nn) ? cnt[base + 2] : 0;
    int v3 = (base + 3 < Nn) ? cnt[base + 3] : 0;
    lds[t] = v0 + v1 + v2 + v3;
    __syncthreads();
    for (int off = 1; off < 256; off <<= 1) {
        int a = lds[t];
        int b = (t >= off) ? lds[t - off] : 0;
        __syncthreads();
        lds[t] = a + b;
        __syncthreads();
    }
    int excl = (t > 0) ? lds[t - 1] : 0;
    if (base + 0 < Nn) rowptr[base + 0] = excl;
    if (base + 1 < Nn) rowptr[base + 1] = excl + v0;
    if (base + 2 < Nn) rowptr[base + 2] = excl + v0 + v1;
    if (base + 3 < Nn) rowptr[base + 3] = excl + v0 + v1 + v2;
    if (t == 255) bsum[blockIdx.x] = lds[255];
}

// phase2: one block scans block sums -> exclusive offsets (nb <= 128)
__global__ __launch_bounds__(128) void scan2_kernel(int* __restrict__ bsum, int nb) {
    __shared__ int lds[128];
    int t = threadIdx.x;
    int v = (t < nb) ? bsum[t] : 0;
    lds[t] = v;
    __syncthreads();
    for (int off = 1; off < 128; off <<= 1) {
        int a = lds[t];
        int b = (t >= off) ? lds[t - off] : 0;
        __syncthreads();
        lds[t] = a + b;
        __syncthreads();
    }
    if (t < nb) bsum[t] = lds[t] - v;  // exclusive
}

// phase3: add block offsets, compute dinv, write rowptr[Nn]
__global__ __launch_bounds__(256) void scan3_kernel(const int* __restrict__ cnt,
                                                    int* __restrict__ rowptr,
                                                    const int* __restrict__ bsum,
                                                    float* __restrict__ dinv) {
    int i = blockIdx.x * 256 + threadIdx.x;
    if (i < Nn) {
        rowptr[i] += bsum[i >> 10];
        int c = cnt[i];
        dinv[i] = (c > 0) ? 1.0f / sqrtf((float)c) : 0.0f;
    }
    if (i == 0) rowptr[Nn] = Ne;
}

// scatter edges into CSR; also precompute per-edge weight wcol = dinv[src]
__global__ __launch_bounds__(256) void scatter_kernel(const int* __restrict__ src,
                                                      const int* __restrict__ dst,
                                                      const int* __restrict__ rowptr,
                                                      int* __restrict__ cnt,
                                                      const float* __restrict__ dinv,
                                                      int* __restrict__ col,
                                                      float* __restrict__ wcol) {
    int e = blockIdx.x * 256 + threadIdx.x;
    if (e < Ne) {
        int d = dst[e];
        int s = src[e];
        int p = rowptr[d] + atomicAdd(&cnt[d], 1);
        col[p] = s;
        wcol[p] = dinv[s];
    }
}

// ================= pull-mode propagation =================
// One wave per node. QL = F/4 lanes cover the feature row via float4;
// EO = 64/QL edges processed in parallel; shfl_xor tree combines them.

template <int F>
__global__ __launch_bounds__(256) void pull_kernel(const float* __restrict__ hin,
                                                   const int* __restrict__ rowptr,
                                                   const int* __restrict__ col,
                                                   const float* __restrict__ wcol,
                                                   const float* __restrict__ dinv,
                                                   float* __restrict__ hout) {
    constexpr int QL = F / 4;
    constexpr int EO = 64 / QL;
    int lane = threadIdx.x & 63;
    int q = lane % QL;
    int eo = lane / QL;
    int n = blockIdx.x * 4 + (threadIdx.x >> 6);
    if (n >= Nn) return;
    int r0 = rowptr[n];
    int r1 = rowptr[n + 1];
    float ax = 0.f, ay = 0.f, az = 0.f, aw = 0.f;
    for (int e = r0 + eo; e < r1; e += EO) {
        int s = col[e];
        float w = wcol[e];
        float4 v = *reinterpret_cast<const float4*>(hin + (size_t)s * F + q * 4);
        ax += w * v.x;
        ay += w * v.y;
        az += w * v.z;
        aw += w * v.w;
    }
#pragma unroll
    for (int off = QL; off < 64; off <<= 1) {
        ax += __shfl_xor(ax, off);
        ay += __shfl_xor(ay, off);
        az += __shfl_xor(az, off);
        aw += __shfl_xor(aw, off);
    }
    if (eo == 0) {
        float dn = dinv[n];
        float4 o;
        o.x = ax * dn; o.y = ay * dn; o.z = az * dn; o.w = aw * dn;
        *reinterpret_cast<float4*>(hout + (size_t)n * F + q * 4) = o;
    }
}

// ================= fused 4-source GEMM =================
// out[N,64] = relu( sum_{k=0..3} Sk[N,KS] @ W[k][KS,64] + bias )
// Block tile: 128 rows x 64 cols, 256 threads, 8r x 4c register tile.
// Thread t: cols 4*(t&15).., rows (t>>4) + 16*j (strided -> conflict-free LDS reads).

template <int KS>
__global__ __launch_bounds__(256) void gemm4_kernel(const float* __restrict__ S0,
                                                    const float* __restrict__ S1,
                                                    const float* __restrict__ S2,
                                                    const float* __restrict__ S3,
                                                    const float* __restrict__ W,
                                                    const float* __restrict__ bias,
                                                    float* __restrict__ out) {
    constexpr int PITCH = KS + 4;
    __shared__ float Ht[128 * PITCH];
    __shared__ float Wt[KS * 64];
    int t = threadIdx.x;
    int c4 = t & 15;
    int r8 = t >> 4;  // 0..15
    int r0 = blockIdx.x * 128;
    float acc[8][4];
#pragma unroll
    for (int j = 0; j < 8; ++j)
#pragma unroll
        for (int d = 0; d < 4; ++d) acc[j][d] = 0.f;

    const float* Ss[4] = {S0, S1, S2, S3};
#pragma unroll
    for (int k = 0; k < 4; ++k) {
        const float* S = Ss[k];
        // stage W[k]: KS*64 floats, float4
        for (int i = t; i < KS * 16; i += 256)
            *reinterpret_cast<float4*>(&Wt[i * 4]) =
                *reinterpret_cast<const float4*>(W + (size_t)k * KS * 64 + i * 4);
        // stage H tile: 128 rows x KS floats
        for (int i = t; i < 128 * (KS / 4); i += 256) {
            int r = i / (KS / 4);
            int fq = i % (KS / 4);
            int row = r0 + r;
            float4 v;
            if (row < Nn)
                v = *reinterpret_cast<const float4*>(S + (size_t)row * KS + fq * 4);
            else { v.x = v.y = v.z = v.w = 0.f; }
            *reinterpret_cast<float4*>(&Ht[r * PITCH + fq * 4]) = v;
        }
        __syncthreads();
#pragma unroll 4
        for (int f = 0; f < KS; ++f) {
            float4 b4 = *reinterpret_cast<const float4*>(&Wt[f * 64 + c4 * 4]);
#pragma unroll
            for (int j = 0; j < 8; ++j) {
                float a = Ht[(r8 + 16 * j) * PITCH + f];
                acc[j][0] += a * b4.x;
                acc[j][1] += a * b4.y;
                acc[j][2] += a * b4.z;
                acc[j][3] += a * b4.w;
            }
        }
        __syncthreads();
    }
    float4 bi = *reinterpret_cast<const float4*>(bias + c4 * 4);
#pragma unroll
    for (int j = 0; j < 8; ++j) {
        int row = r0 + r8 + 16 * j;
        if (row < Nn) {
            float4 o;
            o.x = fmaxf(acc[j][0] + bi.x, 0.f);
            o.y = fmaxf(acc[j][1] + bi.y, 0.f);
            o.z = fmaxf(acc[j][2] + bi.z, 0.f);
            o.w = fmaxf(acc[j][3] + bi.w, 0.f);
            *reinterpret_cast<float4*>(out + (size_t)row * 64 + c4 * 4) = o;
        }
    }
}

// ================= last conv + FC, fused =================
// Weff[k][f][j] = Wh[2][k][f][:] @ fcW[:,j];  beff = bh[2] @ fcW + fcb
__global__ __launch_bounds__(256) void weff_kernel(const float* __restrict__ W,   // Wh[2]: [4][64][64]
                                                   const float* __restrict__ b,   // bh[2]: [64]
                                                   const float* __restrict__ fcW, // [64][4]
                                                   const float* __restrict__ fcb, // [4]
                                                   float* __restrict__ Weff,      // [256][4]
                                                   float* __restrict__ beff) {    // [4]
    int t = threadIdx.x;  // t = k*64 + f
    const float* wrow = W + (size_t)t * 64;
    float a0 = 0.f, a1 = 0.f, a2 = 0.f, a3 = 0.f;
    for (int c = 0; c < 64; ++c) {
        float w = wrow[c];
        a0 += w * fcW[c * 4 + 0];
        a1 += w * fcW[c * 4 + 1];
        a2 += w * fcW[c * 4 + 2];
        a3 += w * fcW[c * 4 + 3];
    }
    float4 o; o.x = a0; o.y = a1; o.z = a2; o.w = a3;
    *reinterpret_cast<float4*>(Weff + t * 4) = o;
    if (t < 4) {
        float s = fcb[t];
        for (int c = 0; c < 64; ++c) s += b[c] * fcW[c * 4 + t];
        beff[t] = s;
    }
}

// out[N,4] = sum_k Sk[N,64] @ Weff[k] + beff  (no relu)
__global__ __launch_bounds__(256) void last_kernel(const float* __restrict__ S0,
                                                   const float* __restrict__ S1,
                                                   const float* __restrict__ S2,
                                                   const float* __restrict__ S3,
                                                   const float* __restrict__ Weff,
                                                   const float* __restrict__ beff,
                                                   float* __restrict__ out) {
    __shared__ float Wl[1024];
    int t = threadIdx.x;
    for (int i = t; i < 256; i += 256)
        *reinterpret_cast<float4*>(&Wl[i * 4]) = *reinterpret_cast<const float4*>(Weff + i * 4);
    __syncthreads();
    int r = blockIdx.x * 256 + t;
    if (r >= Nn) return;
    float a0 = beff[0], a1 = beff[1], a2 = beff[2], a3 = beff[3];
    const float* Ss[4] = {S0, S1, S2, S3};
#pragma unroll
    for (int k = 0; k < 4; ++k) {
        const float4* sp = reinterpret_cast<const float4*>(Ss[k] + (size_t)r * 64);
#pragma unroll
        for (int qq = 0; qq < 16; ++qq) {
            float4 v = sp[qq];
            const float* wp = &Wl[(k * 64 + qq * 4) * 4];
            a0 += v.x * wp[0] + v.y * wp[4] + v.z * wp[8]  + v.w * wp[12];
            a1 += v.x * wp[1] + v.y * wp[5] + v.z * wp[9]  + v.w * wp[13];
            a2 += v.x * wp[2] + v.y * wp[6] + v.z * wp[10] + v.w * wp[14];
            a3 += v.x * wp[3] + v.y * wp[7] + v.z * wp[11] + v.w * wp[15];
        }
    }
    float4 o; o.x = a0; o.y = a1; o.z = a2; o.w = a3;
    *reinterpret_cast<float4*>(out + (size_t)r * 4) = o;
}

// ================= host driver =================

extern "C" void kernel_launch(void* const* d_in, const int* in_sizes, int n_in,
                              void* d_out, int out_size, void* d_ws, size_t ws_size,
                              hipStream_t stream) {
    const float* x   = (const float*)d_in[0];
    const int*   ei  = (const int*)d_in[1];   // [2, E] int32
    const float* W0  = (const float*)d_in[2]; // [4,16,64]
    const float* b0  = (const float*)d_in[3]; // [64]
    const float* Wh  = (const float*)d_in[4]; // [3,4,64,64]
    const float* bh  = (const float*)d_in[5]; // [3,64]
    const float* fcW = (const float*)d_in[6]; // [64,4]
    const float* fcb = (const float*)d_in[7]; // [4]
    float* out = (float*)d_out;

    const int* src = ei;
    const int* dst = ei + Ne;

    // ws layout (4B elems, all 16B-aligned):
    // rowptr[100004] | col[E] | wcol[E] | dinv[N] | bsum[128] | Weff[1024] | beff[4+pad12]
    // | H0[N*64] | H1[N*64] | H2[N*64] | H3[N*64]
    int*   rowptr = (int*)d_ws;
    int*   col    = rowptr + 100004;
    float* wcol   = (float*)(col + Ne);
    float* dinv   = wcol + Ne;
    int*   bsum   = (int*)(dinv + Nn);
    float* Weff   = (float*)(bsum + 128);
    float* beff   = Weff + 1024;
    float* H0     = beff + 16;
    float* H1     = H0 + (size_t)Nn * HID;
    float* H2     = H1 + (size_t)Nn * HID;
    float* H3     = H2 + (size_t)Nn * HID;
    int*   cnt    = (int*)H3;  // alias during CSR build only

    const int egrid = (Ne + 255) / 256;
    const int ngrid = (Nn + 255) / 256;
    const int sgrid = (Nn + 1023) / 1024;  // 98
    const int pgrid = Nn / 4;              // 25000
    const int ggrid = (Nn + 127) / 128;    // 782

    // --- CSR build + dinv + wcol ---
    hipMemsetAsync(cnt, 0, Nn * sizeof(int), stream);
    hist_kernel<<<egrid, 256, 0, stream>>>(dst, cnt);
    scan1_kernel<<<sgrid, 256, 0, stream>>>(cnt, rowptr, bsum);
    scan2_kernel<<<1, 128, 0, stream>>>(bsum, sgrid);
    scan3_kernel<<<ngrid, 256, 0, stream>>>(cnt, rowptr, bsum, dinv);
    hipMemsetAsync(cnt, 0, Nn * sizeof(int), stream);
    scatter_kernel<<<egrid, 256, 0, stream>>>(src, dst, rowptr, cnt, dinv, col, wcol);
    weff_kernel<<<1, 256, 0, stream>>>(Wh + 2 * 4 * 64 * 64, bh + 2 * 64, fcW, fcb, Weff, beff);

    // --- conv0 (F=16 hops, relu) -> H0 ---
    pull_kernel<NF><<<pgrid, 256, 0, stream>>>(x,  rowptr, col, wcol, dinv, H1);
    pull_kernel<NF><<<pgrid, 256, 0, stream>>>(H1, rowptr, col, wcol, dinv, H2);
    pull_kernel<NF><<<pgrid, 256, 0, stream>>>(H2, rowptr, col, wcol, dinv, H3);
    gemm4_kernel<NF><<<ggrid, 256, 0, stream>>>(x, H1, H2, H3, W0, b0, H0);

    // --- conv1, conv2 (relu) : H0 -> H0 ---
    for (int l = 0; l < 2; ++l) {
        pull_kernel<HID><<<pgrid, 256, 0, stream>>>(H0, rowptr, col, wcol, dinv, H1);
        pull_kernel<HID><<<pgrid, 256, 0, stream>>>(H1, rowptr, col, wcol, dinv, H2);
        pull_kernel<HID><<<pgrid, 256, 0, stream>>>(H2, rowptr, col, wcol, dinv, H3);
        gemm4_kernel<HID><<<ggrid, 256, 0, stream>>>(H0, H1, H2, H3,
                                                     Wh + (size_t)l * 4 * HID * HID,
                                                     bh + (size_t)l * HID, H0);
    }

    // --- conv3 (no relu) + FC, fused ---
    pull_kernel<HID><<<pgrid, 256, 0, stream>>>(H0, rowptr, col, wcol, dinv, H1);
    pull_kernel<HID><<<pgrid, 256, 0, stream>>>(H1, rowptr, col, wcol, dinv, H2);
    pull_kernel<HID><<<pgrid, 256, 0, stream>>>(H2, rowptr, col, wcol, dinv, H3);
    last_kernel<<<ngrid, 256, 0, stream>>>(H0, H1, H2, H3, Weff, beff, out);
}

// Round 4
// 962.784 us; speedup vs baseline: 13.9334x; 1.2583x over previous
//
#include <hip/hip_runtime.h>

// Problem constants (match reference)
constexpr int Nn   = 100000;   // nodes
constexpr int Ne   = 1600000;  // edges
constexpr int NF   = 16;       // input features
constexpr int HID  = 64;
constexpr int NOUT = 4;

// ================= CSR build =================

__global__ __launch_bounds__(256) void hist_kernel(const int* __restrict__ dst,
                                                   int* __restrict__ cnt) {
    int e = blockIdx.x * 256 + threadIdx.x;
    if (e < Ne) atomicAdd(&cnt[dst[e]], 1);
}

// phase1: each block scans 1024 elements (4/thread), local exclusive scan -> rowptr,
// block total -> bsum[b]
__global__ __launch_bounds__(256) void scan1_kernel(const int* __restrict__ cnt,
                                                    int* __restrict__ rowptr,
                                                    int* __restrict__ bsum) {
    __shared__ int lds[256];
    int t = threadIdx.x;
    int base = blockIdx.x * 1024 + t * 4;
    int v0 = (base + 0 < Nn) ? cnt[base + 0] : 0;
    int v1 = (base + 1 < Nn) ? cnt[base + 1] : 0;
    int v2 = (base + 2 < Nn) ? cnt[base + 2] : 0;
    int v3 = (base + 3 < Nn) ? cnt[base + 3] : 0;
    lds[t] = v0 + v1 + v2 + v3;
    __syncthreads();
    for (int off = 1; off < 256; off <<= 1) {
        int a = lds[t];
        int b = (t >= off) ? lds[t - off] : 0;
        __syncthreads();
        lds[t] = a + b;
        __syncthreads();
    }
    int excl = (t > 0) ? lds[t - 1] : 0;
    if (base + 0 < Nn) rowptr[base + 0] = excl;
    if (base + 1 < Nn) rowptr[base + 1] = excl + v0;
    if (base + 2 < Nn) rowptr[base + 2] = excl + v0 + v1;
    if (base + 3 < Nn) rowptr[base + 3] = excl + v0 + v1 + v2;
    if (t == 255) bsum[blockIdx.x] = lds[255];
}

// phase2: one block scans block sums -> exclusive offsets (nb <= 128)
__global__ __launch_bounds__(128) void scan2_kernel(int* __restrict__ bsum, int nb) {
    __shared__ int lds[128];
    int t = threadIdx.x;
    int v = (t < nb) ? bsum[t] : 0;
    lds[t] = v;
    __syncthreads();
    for (int off = 1; off < 128; off <<= 1) {
        int a = lds[t];
        int b = (t >= off) ? lds[t - off] : 0;
        __syncthreads();
        lds[t] = a + b;
        __syncthreads();
    }
    if (t < nb) bsum[t] = lds[t] - v;  // exclusive
}

// phase3: add block offsets, compute dinv, write rowptr[Nn]
__global__ __launch_bounds__(256) void scan3_kernel(const int* __restrict__ cnt,
                                                    int* __restrict__ rowptr,
                                                    const int* __restrict__ bsum,
                                                    float* __restrict__ dinv) {
    int i = blockIdx.x * 256 + threadIdx.x;
    if (i < Nn) {
        rowptr[i] += bsum[i >> 10];
        int c = cnt[i];
        dinv[i] = (c > 0) ? 1.0f / sqrtf((float)c) : 0.0f;
    }
    if (i == 0) rowptr[Nn] = Ne;
}

// scatter edges into CSR as interleaved {src, dinv[src]} 8B records
__global__ __launch_bounds__(256) void scatter_kernel(const int* __restrict__ src,
                                                      const int* __restrict__ dst,
                                                      const int* __restrict__ rowptr,
                                                      int* __restrict__ cnt,
                                                      const float* __restrict__ dinv,
                                                      int2* __restrict__ edge2) {
    int e = blockIdx.x * 256 + threadIdx.x;
    if (e < Ne) {
        int d = dst[e];
        int s = src[e];
        int p = rowptr[d] + atomicAdd(&cnt[d], 1);
        edge2[p] = make_int2(s, __float_as_int(dinv[s]));
    }
}

// ================= pull-mode propagation =================
// One wave per node. QL = F/4 lanes cover the feature row via float4;
// EO = 64/QL edges processed in parallel; shfl_xor tree combines them.

template <int F>
__global__ __launch_bounds__(256) void pull_kernel(const float* __restrict__ hin,
                                                   const int* __restrict__ rowptr,
                                                   const int2* __restrict__ edge2,
                                                   const float* __restrict__ dinv,
                                                   float* __restrict__ hout) {
    constexpr int QL = F / 4;
    constexpr int EO = 64 / QL;
    int lane = threadIdx.x & 63;
    int q = lane % QL;
    int eo = lane / QL;
    int n = blockIdx.x * 4 + (threadIdx.x >> 6);
    if (n >= Nn) return;
    int r0 = rowptr[n];
    int r1 = rowptr[n + 1];
    float ax = 0.f, ay = 0.f, az = 0.f, aw = 0.f;
    for (int e = r0 + eo; e < r1; e += EO) {
        int2 ed = edge2[e];
        int s = ed.x;
        float w = __int_as_float(ed.y);
        float4 v = *reinterpret_cast<const float4*>(hin + (size_t)s * F + q * 4);
        ax += w * v.x;
        ay += w * v.y;
        az += w * v.z;
        aw += w * v.w;
    }
#pragma unroll
    for (int off = QL; off < 64; off <<= 1) {
        ax += __shfl_xor(ax, off);
        ay += __shfl_xor(ay, off);
        az += __shfl_xor(az, off);
        aw += __shfl_xor(aw, off);
    }
    if (eo == 0) {
        float dn = dinv[n];
        float4 o;
        o.x = ax * dn; o.y = ay * dn; o.z = az * dn; o.w = aw * dn;
        *reinterpret_cast<float4*>(hout + (size_t)n * F + q * 4) = o;
    }
}

// width-4 pull with fused add: out[n] = gadd[n] + dinv[n]*sum w*uin[s]  (+beff)
// 16 lanes per node (16 edges in parallel, each lane holds the full float4 row).
template <int ADDBIAS>
__global__ __launch_bounds__(256) void pull4_kernel(const float* __restrict__ uin,
                                                    const float* __restrict__ gadd,
                                                    const int* __restrict__ rowptr,
                                                    const int2* __restrict__ edge2,
                                                    const float* __restrict__ dinv,
                                                    const float* __restrict__ beff,
                                                    float* __restrict__ out) {
    int lane = threadIdx.x & 63;
    int eo = lane & 15;
    int n = blockIdx.x * 16 + ((threadIdx.x >> 6) << 2) + (lane >> 4);
    if (n >= Nn) return;
    int r0 = rowptr[n];
    int r1 = rowptr[n + 1];
    float ax = 0.f, ay = 0.f, az = 0.f, aw = 0.f;
    for (int e = r0 + eo; e < r1; e += 16) {
        int2 ed = edge2[e];
        int s = ed.x;
        float w = __int_as_float(ed.y);
        float4 v = *reinterpret_cast<const float4*>(uin + (size_t)s * 4);
        ax += w * v.x;
        ay += w * v.y;
        az += w * v.z;
        aw += w * v.w;
    }
#pragma unroll
    for (int off = 1; off < 16; off <<= 1) {
        ax += __shfl_xor(ax, off);
        ay += __shfl_xor(ay, off);
        az += __shfl_xor(az, off);
        aw += __shfl_xor(aw, off);
    }
    if (eo == 0) {
        float dn = dinv[n];
        float4 g = *reinterpret_cast<const float4*>(gadd + (size_t)n * 4);
        float4 o;
        o.x = g.x + dn * ax;
        o.y = g.y + dn * ay;
        o.z = g.z + dn * az;
        o.w = g.w + dn * aw;
        if (ADDBIAS) {
            o.x += beff[0]; o.y += beff[1]; o.z += beff[2]; o.w += beff[3];
        }
        *reinterpret_cast<float4*>(out + (size_t)n * 4) = o;
    }
}

// ================= fused 4-source GEMM =================
// out[N,64] = relu( sum_{k=0..3} Sk[N,KS] @ W[k][KS,64] + bias )

template <int KS>
__global__ __launch_bounds__(256) void gemm4_kernel(const float* __restrict__ S0,
                                                    const float* __restrict__ S1,
                                                    const float* __restrict__ S2,
                                                    const float* __restrict__ S3,
                                                    const float* __restrict__ W,
                                                    const float* __restrict__ bias,
                                                    float* __restrict__ out) {
    constexpr int PITCH = KS + 4;
    __shared__ float Ht[128 * PITCH];
    __shared__ float Wt[KS * 64];
    int t = threadIdx.x;
    int c4 = t & 15;
    int r8 = t >> 4;  // 0..15
    int r0 = blockIdx.x * 128;
    float acc[8][4];
#pragma unroll
    for (int j = 0; j < 8; ++j)
#pragma unroll
        for (int d = 0; d < 4; ++d) acc[j][d] = 0.f;

    const float* Ss[4] = {S0, S1, S2, S3};
#pragma unroll
    for (int k = 0; k < 4; ++k) {
        const float* S = Ss[k];
        for (int i = t; i < KS * 16; i += 256)
            *reinterpret_cast<float4*>(&Wt[i * 4]) =
                *reinterpret_cast<const float4*>(W + (size_t)k * KS * 64 + i * 4);
        for (int i = t; i < 128 * (KS / 4); i += 256) {
            int r = i / (KS / 4);
            int fq = i % (KS / 4);
            int row = r0 + r;
            float4 v;
            if (row < Nn)
                v = *reinterpret_cast<const float4*>(S + (size_t)row * KS + fq * 4);
            else { v.x = v.y = v.z = v.w = 0.f; }
            *reinterpret_cast<float4*>(&Ht[r * PITCH + fq * 4]) = v;
        }
        __syncthreads();
#pragma unroll 4
        for (int f = 0; f < KS; ++f) {
            float4 b4 = *reinterpret_cast<const float4*>(&Wt[f * 64 + c4 * 4]);
#pragma unroll
            for (int j = 0; j < 8; ++j) {
                float a = Ht[(r8 + 16 * j) * PITCH + f];
                acc[j][0] += a * b4.x;
                acc[j][1] += a * b4.y;
                acc[j][2] += a * b4.z;
                acc[j][3] += a * b4.w;
            }
        }
        __syncthreads();
    }
    float4 bi = *reinterpret_cast<const float4*>(bias + c4 * 4);
#pragma unroll
    for (int j = 0; j < 8; ++j) {
        int row = r0 + r8 + 16 * j;
        if (row < Nn) {
            float4 o;
            o.x = fmaxf(acc[j][0] + bi.x, 0.f);
            o.y = fmaxf(acc[j][1] + bi.y, 0.f);
            o.z = fmaxf(acc[j][2] + bi.z, 0.f);
            o.w = fmaxf(acc[j][3] + bi.w, 0.f);
            *reinterpret_cast<float4*>(out + (size_t)row * 64 + c4 * 4) = o;
        }
    }
}

// ================= last conv + FC folding =================
// Wg[k][c][j] = Wh[2][k][c][:] @ fcW[:,j]  (stored Wg + k*256 + c*4 + j)
// beff = bh[2] @ fcW + fcb
__global__ __launch_bounds__(256) void weff_kernel(const float* __restrict__ W,   // Wh[2]: [4][64][64]
                                                   const float* __restrict__ b,   // bh[2]: [64]
                                                   const float* __restrict__ fcW, // [64][4]
                                                   const float* __restrict__ fcb, // [4]
                                                   float* __restrict__ Wg,        // [4][64][4]
                                                   float* __restrict__ beff) {    // [4]
    int t = threadIdx.x;  // t = k*64 + c
    int k = t >> 6, c = t & 63;
    const float* wrow = W + (size_t)t * 64;
    float a0 = 0.f, a1 = 0.f, a2 = 0.f, a3 = 0.f;
    for (int d = 0; d < 64; ++d) {
        float w = wrow[d];
        a0 += w * fcW[d * 4 + 0];
        a1 += w * fcW[d * 4 + 1];
        a2 += w * fcW[d * 4 + 2];
        a3 += w * fcW[d * 4 + 3];
    }
    float4 o; o.x = a0; o.y = a1; o.z = a2; o.w = a3;
    *reinterpret_cast<float4*>(Wg + k * 256 + c * 4) = o;
    if (t < 4) {
        float s = fcb[t];
        for (int d = 0; d < 64; ++d) s += b[d] * fcW[d * 4 + t];
        beff[t] = s;
    }
}

// Gk[n][j] = sum_c h[n][c] * Wg[k][c][j]  -> four [N,4] buffers (G stride N*4)
__global__ __launch_bounds__(256) void gemmG_kernel(const float* __restrict__ h,
                                                    const float* __restrict__ Wg,
                                                    float* __restrict__ G) {
    __shared__ float Ht[64 * 65];
    __shared__ float Wl[1024];
    int t = threadIdx.x;
    int r0 = blockIdx.x * 64;
    for (int i = t; i < 256; i += 256)
        *reinterpret_cast<float4*>(&Wl[i * 4]) = *reinterpret_cast<const float4*>(Wg + i * 4);
    for (int i = t; i < 64 * 16; i += 256) {
        int r = i >> 4;
        int fq = i & 15;
        int row = r0 + r;
        float4 v;
        if (row < Nn)
            v = *reinterpret_cast<const float4*>(h + (size_t)row * 64 + fq * 4);
        else { v.x = v.y = v.z = v.w = 0.f; }
        *reinterpret_cast<float4*>(&Ht[r * 65 + fq * 4]) = v;
    }
    __syncthreads();
    int r = t & 63;
    int k = t >> 6;
    float a0 = 0.f, a1 = 0.f, a2 = 0.f, a3 = 0.f;
#pragma unroll 8
    for (int c = 0; c < 64; ++c) {
        float hv = Ht[r * 65 + c];
        const float* wp = &Wl[k * 256 + c * 4];
        a0 += hv * wp[0];
        a1 += hv * wp[1];
        a2 += hv * wp[2];
        a3 += hv * wp[3];
    }
    int row = r0 + r;
    if (row < Nn) {
        float4 o; o.x = a0; o.y = a1; o.z = a2; o.w = a3;
        *reinterpret_cast<float4*>(G + (size_t)k * Nn * 4 + (size_t)row * 4) = o;
    }
}

// ================= host driver =================

extern "C" void kernel_launch(void* const* d_in, const int* in_sizes, int n_in,
                              void* d_out, int out_size, void* d_ws, size_t ws_size,
                              hipStream_t stream) {
    const float* x   = (const float*)d_in[0];
    const int*   ei  = (const int*)d_in[1];   // [2, E] int32
    const float* W0  = (const float*)d_in[2]; // [4,16,64]
    const float* b0  = (const float*)d_in[3]; // [64]
    const float* Wh  = (const float*)d_in[4]; // [3,4,64,64]
    const float* bh  = (const float*)d_in[5]; // [3,64]
    const float* fcW = (const float*)d_in[6]; // [64,4]
    const float* fcb = (const float*)d_in[7]; // [4]
    float* out = (float*)d_out;

    const int* src = ei;
    const int* dst = ei + Ne;

    // ws layout (ints/floats, 16B-aligned blocks):
    // rowptr[100004] | edge2[2E] | dinv[N] | bsum[128] | Wg[1024] | beff[16]
    // | H0[N*64] | H1[N*64] | H2[N*64] | H3[N*64]
    int*   rowptr = (int*)d_ws;
    int2*  edge2  = (int2*)(rowptr + 100004);
    float* dinv   = (float*)(rowptr + 100004 + 2 * Ne);
    int*   bsum   = (int*)(dinv + Nn);
    float* Wg     = (float*)(bsum + 128);
    float* beff   = Wg + 1024;
    float* H0     = beff + 16;
    float* H1     = H0 + (size_t)Nn * HID;
    float* H2     = H1 + (size_t)Nn * HID;
    float* H3     = H2 + (size_t)Nn * HID;
    int*   cnt    = (int*)H3;  // alias during CSR build only
    // last-layer small buffers alias H1 (free by then): G0..G3, T, T2
    float* G      = H1;                       // G_k at G + k*N*4
    float* G0     = G + 0 * (size_t)Nn * 4;
    float* G1     = G + 1 * (size_t)Nn * 4;
    float* G2     = G + 2 * (size_t)Nn * 4;
    float* G3     = G + 3 * (size_t)Nn * 4;
    float* T      = G + 4 * (size_t)Nn * 4;
    float* T2     = G + 5 * (size_t)Nn * 4;

    const int egrid = (Ne + 255) / 256;
    const int ngrid = (Nn + 255) / 256;
    const int sgrid = (Nn + 1023) / 1024;  // 98
    const int pgrid = Nn / 4;              // 25000
    const int ggrid = (Nn + 127) / 128;    // 782
    const int qgrid = (Nn + 15) / 16;      // 6250
    const int Ggrid = (Nn + 63) / 64;      // 1563

    // --- CSR build + dinv + fused edge records ---
    hipMemsetAsync(cnt, 0, Nn * sizeof(int), stream);
    hist_kernel<<<egrid, 256, 0, stream>>>(dst, cnt);
    scan1_kernel<<<sgrid, 256, 0, stream>>>(cnt, rowptr, bsum);
    scan2_kernel<<<1, 128, 0, stream>>>(bsum, sgrid);
    scan3_kernel<<<ngrid, 256, 0, stream>>>(cnt, rowptr, bsum, dinv);
    hipMemsetAsync(cnt, 0, Nn * sizeof(int), stream);
    scatter_kernel<<<egrid, 256, 0, stream>>>(src, dst, rowptr, cnt, dinv, edge2);
    weff_kernel<<<1, 256, 0, stream>>>(Wh + 2 * 4 * 64 * 64, bh + 2 * 64, fcW, fcb, Wg, beff);

    // --- conv0 (F=16 hops, relu) -> H0 ---
    pull_kernel<NF><<<pgrid, 256, 0, stream>>>(x,  rowptr, edge2, dinv, H1);
    pull_kernel<NF><<<pgrid, 256, 0, stream>>>(H1, rowptr, edge2, dinv, H2);
    pull_kernel<NF><<<pgrid, 256, 0, stream>>>(H2, rowptr, edge2, dinv, H3);
    gemm4_kernel<NF><<<ggrid, 256, 0, stream>>>(x, H1, H2, H3, W0, b0, H0);

    // --- conv1, conv2 (relu) : H0 -> H0 ---
    for (int l = 0; l < 2; ++l) {
        pull_kernel<HID><<<pgrid, 256, 0, stream>>>(H0, rowptr, edge2, dinv, H1);
        pull_kernel<HID><<<pgrid, 256, 0, stream>>>(H1, rowptr, edge2, dinv, H2);
        pull_kernel<HID><<<pgrid, 256, 0, stream>>>(H2, rowptr, edge2, dinv, H3);
        gemm4_kernel<HID><<<ggrid, 256, 0, stream>>>(H0, H1, H2, H3,
                                                     Wh + (size_t)l * 4 * HID * HID,
                                                     bh + (size_t)l * HID, H0);
    }

    // --- conv3 + FC, folded to width 4 + Horner ---
    // out = G0 + A(G1 + A(G2 + A*G3)) + beff
    gemmG_kernel<<<Ggrid, 256, 0, stream>>>(H0, Wg, G);
    pull4_kernel<0><<<qgrid, 256, 0, stream>>>(G3, G2, rowptr, edge2, dinv, beff, T);
    pull4_kernel<0><<<qgrid, 256, 0, stream>>>(T,  G1, rowptr, edge2, dinv, beff, T2);
    pull4_kernel<1><<<qgrid, 256, 0, stream>>>(T2, G0, rowptr, edge2, dinv, beff, out);
}

// Round 5
// 943.513 us; speedup vs baseline: 14.2180x; 1.0204x over previous
//
#include <hip/hip_runtime.h>

// Problem constants (match reference)
constexpr int Nn   = 100000;   // nodes
constexpr int Ne   = 1600000;  // edges
constexpr int NF   = 16;       // input features
constexpr int HID  = 64;
constexpr int NOUT = 4;

// XCD partitioning for the CSR build (8 XCDs on MI355X; blockIdx%8 -> XCD is a
// perf heuristic only — coverage/correctness hold for any placement).
constexpr int NXCD = 8;
constexpr int NRNG = (Nn + NXCD - 1) / NXCD;   // 12500 nodes per XCD range
constexpr int CHB  = 192;                      // edge chunks per XCD group
constexpr int ECH  = (Ne + CHB - 1) / CHB;     // 8334 edges per chunk

// ================= CSR build (XCD-partitioned) =================

__global__ __launch_bounds__(256) void hist_kernel(const int* __restrict__ dst,
                                                   int* __restrict__ cnt) {
    int g = blockIdx.x % NXCD;   // intended XCD / node range
    int c = blockIdx.x / NXCD;   // edge chunk
    int lo = g * NRNG;
    int hi = (lo + NRNG < Nn) ? lo + NRNG : Nn;
    int e0 = c * ECH;
    int e1 = (e0 + ECH < Ne) ? e0 + ECH : Ne;
    for (int e = e0 + threadIdx.x; e < e1; e += 256) {
        int d = dst[e];
        if (d >= lo && d < hi) atomicAdd(&cnt[d], 1);
    }
}

// phase1: each block scans 1024 elements (4/thread), local exclusive scan -> rowptr,
// block total -> bsum[b]
__global__ __launch_bounds__(256) void scan1_kernel(const int* __restrict__ cnt,
                                                    int* __restrict__ rowptr,
                                                    int* __restrict__ bsum) {
    __shared__ int lds[256];
    int t = threadIdx.x;
    int base = blockIdx.x * 1024 + t * 4;
    int v0 = (base + 0 < Nn) ? cnt[base + 0] : 0;
    int v1 = (base + 1 < Nn) ? cnt[base + 1] : 0;
    int v2 = (base + 2 < Nn) ? cnt[base + 2] : 0;
    int v3 = (base + 3 < Nn) ? cnt[base + 3] : 0;
    lds[t] = v0 + v1 + v2 + v3;
    __syncthreads();
    for (int off = 1; off < 256; off <<= 1) {
        int a = lds[t];
        int b = (t >= off) ? lds[t - off] : 0;
        __syncthreads();
        lds[t] = a + b;
        __syncthreads();
    }
    int excl = (t > 0) ? lds[t - 1] : 0;
    if (base + 0 < Nn) rowptr[base + 0] = excl;
    if (base + 1 < Nn) rowptr[base + 1] = excl + v0;
    if (base + 2 < Nn) rowptr[base + 2] = excl + v0 + v1;
    if (base + 3 < Nn) rowptr[base + 3] = excl + v0 + v1 + v2;
    if (t == 255) bsum[blockIdx.x] = lds[255];
}

// phase2: one block scans block sums -> exclusive offsets (nb <= 128)
__global__ __launch_bounds__(128) void scan2_kernel(int* __restrict__ bsum, int nb) {
    __shared__ int lds[128];
    int t = threadIdx.x;
    int v = (t < nb) ? bsum[t] : 0;
    lds[t] = v;
    __syncthreads();
    for (int off = 1; off < 128; off <<= 1) {
        int a = lds[t];
        int b = (t >= off) ? lds[t - off] : 0;
        __syncthreads();
        lds[t] = a + b;
        __syncthreads();
    }
    if (t < nb) bsum[t] = lds[t] - v;  // exclusive
}

// phase3: add block offsets, compute dinv, write rowptr[Nn]
__global__ __launch_bounds__(256) void scan3_kernel(const int* __restrict__ cnt,
                                                    int* __restrict__ rowptr,
                                                    const int* __restrict__ bsum,
                                                    float* __restrict__ dinv) {
    int i = blockIdx.x * 256 + threadIdx.x;
    if (i < Nn) {
        rowptr[i] += bsum[i >> 10];
        int c = cnt[i];
        dinv[i] = (c > 0) ? 1.0f / sqrtf((float)c) : 0.0f;
    }
    if (i == 0) rowptr[Nn] = Ne;
}

// scatter edges into CSR as interleaved {src, dinv[src]} 8B records.
// XCD-partitioned: block (g,c) writes only CSR region g -> dirty lines stay in
// one L2 and coalesce before writeback.
__global__ __launch_bounds__(256) void scatter_kernel(const int* __restrict__ src,
                                                      const int* __restrict__ dst,
                                                      const int* __restrict__ rowptr,
                                                      int* __restrict__ cnt,
                                                      const float* __restrict__ dinv,
                                                      int2* __restrict__ edge2) {
    int g = blockIdx.x % NXCD;
    int c = blockIdx.x / NXCD;
    int lo = g * NRNG;
    int hi = (lo + NRNG < Nn) ? lo + NRNG : Nn;
    int e0 = c * ECH;
    int e1 = (e0 + ECH < Ne) ? e0 + ECH : Ne;
    for (int e = e0 + threadIdx.x; e < e1; e += 256) {
        int d = dst[e];
        if (d >= lo && d < hi) {
            int s = src[e];
            int p = rowptr[d] + atomicAdd(&cnt[d], 1);
            edge2[p] = make_int2(s, __float_as_int(dinv[s]));
        }
    }
}

// ================= pull-mode propagation =================

__device__ inline void fma4(float4& a, float w, const float4& v) {
    a.x += w * v.x; a.y += w * v.y; a.z += w * v.z; a.w += w * v.w;
}
__device__ inline void red4(float4& a, int off) {
    a.x += __shfl_xor(a.x, off);
    a.y += __shfl_xor(a.y, off);
    a.z += __shfl_xor(a.z, off);
    a.w += __shfl_xor(a.w, off);
}

// F=64, max memory-level parallelism: 4 lanes per row (16 cols each), 16 edges
// in flight per wave -> one iteration covers the average degree.
__global__ __launch_bounds__(256) void pull64_kernel(const float* __restrict__ hin,
                                                     const int* __restrict__ rowptr,
                                                     const int2* __restrict__ edge2,
                                                     const float* __restrict__ dinv,
                                                     float* __restrict__ hout) {
    int lane = threadIdx.x & 63;
    int q  = lane & 3;    // col group: [q*16, q*16+16)
    int eo = lane >> 2;   // 0..15 edges in parallel
    int n = blockIdx.x * 4 + (threadIdx.x >> 6);
    if (n >= Nn) return;
    int r0 = rowptr[n];
    int r1 = rowptr[n + 1];
    float4 a0 = {0.f, 0.f, 0.f, 0.f}, a1 = a0, a2 = a0, a3 = a0;
    for (int e = r0 + eo; e < r1; e += 16) {
        int2 ed = edge2[e];
        float w = __int_as_float(ed.y);
        const float4* rp = reinterpret_cast<const float4*>(hin + (size_t)ed.x * 64 + q * 16);
        float4 v0 = rp[0], v1 = rp[1], v2 = rp[2], v3 = rp[3];
        fma4(a0, w, v0);
        fma4(a1, w, v1);
        fma4(a2, w, v2);
        fma4(a3, w, v3);
    }
#pragma unroll
    for (int off = 4; off < 64; off <<= 1) {
        red4(a0, off); red4(a1, off); red4(a2, off); red4(a3, off);
    }
    if (eo == 0) {
        float dn = dinv[n];
        float4* op = reinterpret_cast<float4*>(hout + (size_t)n * 64 + q * 16);
        float4 o0 = a0, o1 = a1, o2 = a2, o3 = a3;
        o0.x *= dn; o0.y *= dn; o0.z *= dn; o0.w *= dn;
        o1.x *= dn; o1.y *= dn; o1.z *= dn; o1.w *= dn;
        o2.x *= dn; o2.y *= dn; o2.z *= dn; o2.w *= dn;
        o3.x *= dn; o3.y *= dn; o3.z *= dn; o3.w *= dn;
        op[0] = o0; op[1] = o1; op[2] = o2; op[3] = o3;
    }
}

// F=16: 4 lanes per row (one float4 each), 16 edges in parallel.
__global__ __launch_bounds__(256) void pull16_kernel(const float* __restrict__ hin,
                                                     const int* __restrict__ rowptr,
                                                     const int2* __restrict__ edge2,
                                                     const float* __restrict__ dinv,
                                                     float* __restrict__ hout) {
    int lane = threadIdx.x & 63;
    int q  = lane & 3;
    int eo = lane >> 2;
    int n = blockIdx.x * 4 + (threadIdx.x >> 6);
    if (n >= Nn) return;
    int r0 = rowptr[n];
    int r1 = rowptr[n + 1];
    float4 a = {0.f, 0.f, 0.f, 0.f};
    for (int e = r0 + eo; e < r1; e += 16) {
        int2 ed = edge2[e];
        float w = __int_as_float(ed.y);
        float4 v = *reinterpret_cast<const float4*>(hin + (size_t)ed.x * 16 + q * 4);
        fma4(a, w, v);
    }
#pragma unroll
    for (int off = 4; off < 64; off <<= 1) red4(a, off);
    if (eo == 0) {
        float dn = dinv[n];
        a.x *= dn; a.y *= dn; a.z *= dn; a.w *= dn;
        *reinterpret_cast<float4*>(hout + (size_t)n * 16 + q * 4) = a;
    }
}

// width-4 pull with fused add: out[n] = gadd[n] + dinv[n]*sum w*uin[s]  (+beff)
template <int ADDBIAS>
__global__ __launch_bounds__(256) void pull4_kernel(const float* __restrict__ uin,
                                                    const float* __restrict__ gadd,
                                                    const int* __restrict__ rowptr,
                                                    const int2* __restrict__ edge2,
                                                    const float* __restrict__ dinv,
                                                    const float* __restrict__ beff,
                                                    float* __restrict__ out) {
    int lane = threadIdx.x & 63;
    int eo = lane & 15;
    int n = blockIdx.x * 16 + ((threadIdx.x >> 6) << 2) + (lane >> 4);
    if (n >= Nn) return;
    int r0 = rowptr[n];
    int r1 = rowptr[n + 1];
    float4 a = {0.f, 0.f, 0.f, 0.f};
    for (int e = r0 + eo; e < r1; e += 16) {
        int2 ed = edge2[e];
        float w = __int_as_float(ed.y);
        float4 v = *reinterpret_cast<const float4*>(uin + (size_t)ed.x * 4);
        fma4(a, w, v);
    }
#pragma unroll
    for (int off = 1; off < 16; off <<= 1) red4(a, off);
    if (eo == 0) {
        float dn = dinv[n];
        float4 g = *reinterpret_cast<const float4*>(gadd + (size_t)n * 4);
        float4 o;
        o.x = g.x + dn * a.x;
        o.y = g.y + dn * a.y;
        o.z = g.z + dn * a.z;
        o.w = g.w + dn * a.w;
        if (ADDBIAS) {
            o.x += beff[0]; o.y += beff[1]; o.z += beff[2]; o.w += beff[3];
        }
        *reinterpret_cast<float4*>(out + (size_t)n * 4) = o;
    }
}

// ================= fused 4-source GEMM =================
// out[N,64] = relu( sum_{k=0..3} Sk[N,KS] @ W[k][KS,64] + bias )

template <int KS>
__global__ __launch_bounds__(256) void gemm4_kernel(const float* __restrict__ S0,
                                                    const float* __restrict__ S1,
                                                    const float* __restrict__ S2,
                                                    const float* __restrict__ S3,
                                                    const float* __restrict__ W,
                                                    const float* __restrict__ bias,
                                                    float* __restrict__ out) {
    constexpr int PITCH = KS + 4;
    __shared__ float Ht[128 * PITCH];
    __shared__ float Wt[KS * 64];
    int t = threadIdx.x;
    int c4 = t & 15;
    int r8 = t >> 4;  // 0..15
    int r0 = blockIdx.x * 128;
    float acc[8][4];
#pragma unroll
    for (int j = 0; j < 8; ++j)
#pragma unroll
        for (int d = 0; d < 4; ++d) acc[j][d] = 0.f;

    const float* Ss[4] = {S0, S1, S2, S3};
#pragma unroll
    for (int k = 0; k < 4; ++k) {
        const float* S = Ss[k];
        for (int i = t; i < KS * 16; i += 256)
            *reinterpret_cast<float4*>(&Wt[i * 4]) =
                *reinterpret_cast<const float4*>(W + (size_t)k * KS * 64 + i * 4);
        for (int i = t; i < 128 * (KS / 4); i += 256) {
            int r = i / (KS / 4);
            int fq = i % (KS / 4);
            int row = r0 + r;
            float4 v;
            if (row < Nn)
                v = *reinterpret_cast<const float4*>(S + (size_t)row * KS + fq * 4);
            else { v.x = v.y = v.z = v.w = 0.f; }
            *reinterpret_cast<float4*>(&Ht[r * PITCH + fq * 4]) = v;
        }
        __syncthreads();
#pragma unroll 4
        for (int f = 0; f < KS; ++f) {
            float4 b4 = *reinterpret_cast<const float4*>(&Wt[f * 64 + c4 * 4]);
#pragma unroll
            for (int j = 0; j < 8; ++j) {
                float a = Ht[(r8 + 16 * j) * PITCH + f];
                acc[j][0] += a * b4.x;
                acc[j][1] += a * b4.y;
                acc[j][2] += a * b4.z;
                acc[j][3] += a * b4.w;
            }
        }
        __syncthreads();
    }
    float4 bi = *reinterpret_cast<const float4*>(bias + c4 * 4);
#pragma unroll
    for (int j = 0; j < 8; ++j) {
        int row = r0 + r8 + 16 * j;
        if (row < Nn) {
            float4 o;
            o.x = fmaxf(acc[j][0] + bi.x, 0.f);
            o.y = fmaxf(acc[j][1] + bi.y, 0.f);
            o.z = fmaxf(acc[j][2] + bi.z, 0.f);
            o.w = fmaxf(acc[j][3] + bi.w, 0.f);
            *reinterpret_cast<float4*>(out + (size_t)row * 64 + c4 * 4) = o;
        }
    }
}

// ================= last conv + FC folding =================
// Wg[k][c][j] = Wh[2][k][c][:] @ fcW[:,j];  beff = bh[2] @ fcW + fcb
__global__ __launch_bounds__(256) void weff_kernel(const float* __restrict__ W,   // Wh[2]: [4][64][64]
                                                   const float* __restrict__ b,   // bh[2]: [64]
                                                   const float* __restrict__ fcW, // [64][4]
                                                   const float* __restrict__ fcb, // [4]
                                                   float* __restrict__ Wg,        // [4][64][4]
                                                   float* __restrict__ beff) {    // [4]
    int t = threadIdx.x;  // t = k*64 + c
    int k = t >> 6, c = t & 63;
    const float* wrow = W + (size_t)t * 64;
    float a0 = 0.f, a1 = 0.f, a2 = 0.f, a3 = 0.f;
    for (int d = 0; d < 64; ++d) {
        float w = wrow[d];
        a0 += w * fcW[d * 4 + 0];
        a1 += w * fcW[d * 4 + 1];
        a2 += w * fcW[d * 4 + 2];
        a3 += w * fcW[d * 4 + 3];
    }
    float4 o; o.x = a0; o.y = a1; o.z = a2; o.w = a3;
    *reinterpret_cast<float4*>(Wg + k * 256 + c * 4) = o;
    if (t < 4) {
        float s = fcb[t];
        for (int d = 0; d < 64; ++d) s += b[d] * fcW[d * 4 + t];
        beff[t] = s;
    }
}

// Gk[n][j] = sum_c h[n][c] * Wg[k][c][j]  -> four [N,4] buffers (G stride N*4)
__global__ __launch_bounds__(256) void gemmG_kernel(const float* __restrict__ h,
                                                    const float* __restrict__ Wg,
                                                    float* __restrict__ G) {
    __shared__ float Ht[64 * 65];
    __shared__ float Wl[1024];
    int t = threadIdx.x;
    int r0 = blockIdx.x * 64;
    for (int i = t; i < 256; i += 256)
        *reinterpret_cast<float4*>(&Wl[i * 4]) = *reinterpret_cast<const float4*>(Wg + i * 4);
    for (int i = t; i < 64 * 16; i += 256) {
        int r = i >> 4;
        int fq = i & 15;
        int row = r0 + r;
        float4 v;
        if (row < Nn)
            v = *reinterpret_cast<const float4*>(h + (size_t)row * 64 + fq * 4);
        else { v.x = v.y = v.z = v.w = 0.f; }
        *reinterpret_cast<float4*>(&Ht[r * 65 + fq * 4]) = v;
    }
    __syncthreads();
    int r = t & 63;
    int k = t >> 6;
    float a0 = 0.f, a1 = 0.f, a2 = 0.f, a3 = 0.f;
#pragma unroll 8
    for (int c = 0; c < 64; ++c) {
        float hv = Ht[r * 65 + c];
        const float* wp = &Wl[k * 256 + c * 4];
        a0 += hv * wp[0];
        a1 += hv * wp[1];
        a2 += hv * wp[2];
        a3 += hv * wp[3];
    }
    int row = r0 + r;
    if (row < Nn) {
        float4 o; o.x = a0; o.y = a1; o.z = a2; o.w = a3;
        *reinterpret_cast<float4*>(G + (size_t)k * Nn * 4 + (size_t)row * 4) = o;
    }
}

// ================= host driver =================

extern "C" void kernel_launch(void* const* d_in, const int* in_sizes, int n_in,
                              void* d_out, int out_size, void* d_ws, size_t ws_size,
                              hipStream_t stream) {
    const float* x   = (const float*)d_in[0];
    const int*   ei  = (const int*)d_in[1];   // [2, E] int32
    const float* W0  = (const float*)d_in[2]; // [4,16,64]
    const float* b0  = (const float*)d_in[3]; // [64]
    const float* Wh  = (const float*)d_in[4]; // [3,4,64,64]
    const float* bh  = (const float*)d_in[5]; // [3,64]
    const float* fcW = (const float*)d_in[6]; // [64,4]
    const float* fcb = (const float*)d_in[7]; // [4]
    float* out = (float*)d_out;

    const int* src = ei;
    const int* dst = ei + Ne;

    // ws layout:
    // rowptr[100004] | edge2[2E] | dinv[N] | bsum[128] | Wg[1024] | beff[16]
    // | H0[N*64] | H1[N*64] | H2[N*64] | H3[N*64]
    int*   rowptr = (int*)d_ws;
    int2*  edge2  = (int2*)(rowptr + 100004);
    float* dinv   = (float*)(rowptr + 100004 + 2 * Ne);
    int*   bsum   = (int*)(dinv + Nn);
    float* Wg     = (float*)(bsum + 128);
    float* beff   = Wg + 1024;
    float* H0     = beff + 16;
    float* H1     = H0 + (size_t)Nn * HID;
    float* H2     = H1 + (size_t)Nn * HID;
    float* H3     = H2 + (size_t)Nn * HID;
    int*   cnt    = (int*)H3;  // alias during CSR build only
    // last-layer small buffers alias H1 (free by then)
    float* G      = H1;
    float* G0     = G + 0 * (size_t)Nn * 4;
    float* G1     = G + 1 * (size_t)Nn * 4;
    float* G2     = G + 2 * (size_t)Nn * 4;
    float* G3     = G + 3 * (size_t)Nn * 4;
    float* T      = G + 4 * (size_t)Nn * 4;
    float* T2     = G + 5 * (size_t)Nn * 4;

    const int xgrid = NXCD * CHB;          // 1536 partitioned build blocks
    const int ngrid = (Nn + 255) / 256;
    const int sgrid = (Nn + 1023) / 1024;  // 98
    const int pgrid = Nn / 4;              // 25000
    const int ggrid = (Nn + 127) / 128;    // 782
    const int qgrid = (Nn + 15) / 16;      // 6250
    const int Ggrid = (Nn + 63) / 64;      // 1563

    // --- CSR build + dinv + fused edge records ---
    hipMemsetAsync(cnt, 0, Nn * sizeof(int), stream);
    hist_kernel<<<xgrid, 256, 0, stream>>>(dst, cnt);
    scan1_kernel<<<sgrid, 256, 0, stream>>>(cnt, rowptr, bsum);
    scan2_kernel<<<1, 128, 0, stream>>>(bsum, sgrid);
    scan3_kernel<<<ngrid, 256, 0, stream>>>(cnt, rowptr, bsum, dinv);
    hipMemsetAsync(cnt, 0, Nn * sizeof(int), stream);
    scatter_kernel<<<xgrid, 256, 0, stream>>>(src, dst, rowptr, cnt, dinv, edge2);
    weff_kernel<<<1, 256, 0, stream>>>(Wh + 2 * 4 * 64 * 64, bh + 2 * 64, fcW, fcb, Wg, beff);

    // --- conv0 (F=16 hops, relu) -> H0 ---
    pull16_kernel<<<pgrid, 256, 0, stream>>>(x,  rowptr, edge2, dinv, H1);
    pull16_kernel<<<pgrid, 256, 0, stream>>>(H1, rowptr, edge2, dinv, H2);
    pull16_kernel<<<pgrid, 256, 0, stream>>>(H2, rowptr, edge2, dinv, H3);
    gemm4_kernel<NF><<<ggrid, 256, 0, stream>>>(x, H1, H2, H3, W0, b0, H0);

    // --- conv1, conv2 (relu) : H0 -> H0 ---
    for (int l = 0; l < 2; ++l) {
        pull64_kernel<<<pgrid, 256, 0, stream>>>(H0, rowptr, edge2, dinv, H1);
        pull64_kernel<<<pgrid, 256, 0, stream>>>(H1, rowptr, edge2, dinv, H2);
        pull64_kernel<<<pgrid, 256, 0, stream>>>(H2, rowptr, edge2, dinv, H3);
        gemm4_kernel<HID><<<ggrid, 256, 0, stream>>>(H0, H1, H2, H3,
                                                     Wh + (size_t)l * 4 * HID * HID,
                                                     bh + (size_t)l * HID, H0);
    }

    // --- conv3 + FC, folded to width 4 + Horner ---
    // out = G0 + A(G1 + A(G2 + A*G3)) + beff
    gemmG_kernel<<<Ggrid, 256, 0, stream>>>(H0, Wg, G);
    pull4_kernel<0><<<qgrid, 256, 0, stream>>>(G3, G2, rowptr, edge2, dinv, beff, T);
    pull4_kernel<0><<<qgrid, 256, 0, stream>>>(T,  G1, rowptr, edge2, dinv, beff, T2);
    pull4_kernel<1><<<qgrid, 256, 0, stream>>>(T2, G0, rowptr, edge2, dinv, beff, out);
}

// Round 6
// 798.433 us; speedup vs baseline: 16.8015x; 1.1817x over previous
//
#include <hip/hip_runtime.h>
#include <hip/hip_fp16.h>

// Problem constants (match reference)
constexpr int Nn   = 100000;   // nodes
constexpr int Ne   = 1600000;  // edges
constexpr int NF   = 16;       // input features
constexpr int HID  = 64;
constexpr int NOUT = 4;

union H8 { float4 f4; __half h[8]; };
union H4 { float2 f2; __half h[4]; };

// ================= CSR build =================

// hist + rank capture: rank[e] = arrival order of edge e within its dst row.
__global__ __launch_bounds__(256) void hist_kernel(const int* __restrict__ dst,
                                                   int* __restrict__ cnt,
                                                   int* __restrict__ rank) {
    int e = blockIdx.x * 256 + threadIdx.x;
    if (e < Ne) rank[e] = atomicAdd(&cnt[dst[e]], 1);
}

// phase1: each block scans 1024 elements (4/thread), local exclusive scan -> rowptr,
// block total -> bsum[b]
__global__ __launch_bounds__(256) void scan1_kernel(const int* __restrict__ cnt,
                                                    int* __restrict__ rowptr,
                                                    int* __restrict__ bsum) {
    __shared__ int lds[256];
    int t = threadIdx.x;
    int base = blockIdx.x * 1024 + t * 4;
    int v0 = (base + 0 < Nn) ? cnt[base + 0] : 0;
    int v1 = (base + 1 < Nn) ? cnt[base + 1] : 0;
    int v2 = (base + 2 < Nn) ? cnt[base + 2] : 0;
    int v3 = (base + 3 < Nn) ? cnt[base + 3] : 0;
    lds[t] = v0 + v1 + v2 + v3;
    __syncthreads();
    for (int off = 1; off < 256; off <<= 1) {
        int a = lds[t];
        int b = (t >= off) ? lds[t - off] : 0;
        __syncthreads();
        lds[t] = a + b;
        __syncthreads();
    }
    int excl = (t > 0) ? lds[t - 1] : 0;
    if (base + 0 < Nn) rowptr[base + 0] = excl;
    if (base + 1 < Nn) rowptr[base + 1] = excl + v0;
    if (base + 2 < Nn) rowptr[base + 2] = excl + v0 + v1;
    if (base + 3 < Nn) rowptr[base + 3] = excl + v0 + v1 + v2;
    if (t == 255) bsum[blockIdx.x] = lds[255];
}

// phase2: one block scans block sums -> exclusive offsets (nb <= 128)
__global__ __launch_bounds__(128) void scan2_kernel(int* __restrict__ bsum, int nb) {
    __shared__ int lds[128];
    int t = threadIdx.x;
    int v = (t < nb) ? bsum[t] : 0;
    lds[t] = v;
    __syncthreads();
    for (int off = 1; off < 128; off <<= 1) {
        int a = lds[t];
        int b = (t >= off) ? lds[t - off] : 0;
        __syncthreads();
        lds[t] = a + b;
        __syncthreads();
    }
    if (t < nb) bsum[t] = lds[t] - v;  // exclusive
}

// phase3: add block offsets, compute dinv, write rowptr[Nn]
__global__ __launch_bounds__(256) void scan3_kernel(const int* __restrict__ cnt,
                                                    int* __restrict__ rowptr,
                                                    const int* __restrict__ bsum,
                                                    float* __restrict__ dinv) {
    int i = blockIdx.x * 256 + threadIdx.x;
    if (i < Nn) {
        rowptr[i] += bsum[i >> 10];
        int c = cnt[i];
        dinv[i] = (c > 0) ? 1.0f / sqrtf((float)c) : 0.0f;
    }
    if (i == 0) rowptr[Nn] = Ne;
}

// scatter edges into CSR as interleaved {src, dinv[src]} 8B records — no atomics.
__global__ __launch_bounds__(256) void scatter_kernel(const int* __restrict__ src,
                                                      const int* __restrict__ dst,
                                                      const int* __restrict__ rowptr,
                                                      const int* __restrict__ rank,
                                                      const float* __restrict__ dinv,
                                                      int2* __restrict__ edge2) {
    int e = blockIdx.x * 256 + threadIdx.x;
    if (e < Ne) {
        int d = dst[e];
        int s = src[e];
        int p = rowptr[d] + rank[e];
        edge2[p] = make_int2(s, __float_as_int(dinv[s]));
    }
}

// x[N,16] f32 -> xh[N,16] fp16
__global__ __launch_bounds__(256) void xcvt_kernel(const float* __restrict__ x,
                                                   __half* __restrict__ xh) {
    int i = blockIdx.x * 256 + threadIdx.x;  // float4 chunk index
    if (i < Nn * NF / 4) {
        float4 v = reinterpret_cast<const float4*>(x)[i];
        H4 o;
        o.h[0] = __float2half(v.x);
        o.h[1] = __float2half(v.y);
        o.h[2] = __float2half(v.z);
        o.h[3] = __float2half(v.w);
        reinterpret_cast<float2*>(xh)[i] = o.f2;
    }
}

// ================= pull-mode propagation (fp16 tables, f32 math) =================

// F=64: 4 lanes per row (16 halves = 32B each), 16 edges in flight per wave.
__global__ __launch_bounds__(256) void pull64h_kernel(const __half* __restrict__ hin,
                                                      const int* __restrict__ rowptr,
                                                      const int2* __restrict__ edge2,
                                                      const float* __restrict__ dinv,
                                                      __half* __restrict__ hout) {
    int lane = threadIdx.x & 63;
    int q  = lane & 3;    // 16-half chunk
    int eo = lane >> 2;   // 0..15 edges in parallel
    int n = blockIdx.x * 4 + (threadIdx.x >> 6);
    if (n >= Nn) return;
    int r0 = rowptr[n];
    int r1 = rowptr[n + 1];
    float a[16];
#pragma unroll
    for (int j = 0; j < 16; ++j) a[j] = 0.f;
    for (int e = r0 + eo; e < r1; e += 16) {
        int2 ed = edge2[e];
        float w = __int_as_float(ed.y);
        const float4* rp = reinterpret_cast<const float4*>(hin + (size_t)ed.x * 64 + q * 16);
        H8 u0, u1;
        u0.f4 = rp[0];
        u1.f4 = rp[1];
#pragma unroll
        for (int j = 0; j < 8; ++j) a[j] += w * __half2float(u0.h[j]);
#pragma unroll
        for (int j = 0; j < 8; ++j) a[8 + j] += w * __half2float(u1.h[j]);
    }
#pragma unroll
    for (int off = 4; off < 64; off <<= 1)
#pragma unroll
        for (int j = 0; j < 16; ++j) a[j] += __shfl_xor(a[j], off);
    if (eo == 0) {
        float dn = dinv[n];
        H8 o0, o1;
#pragma unroll
        for (int j = 0; j < 8; ++j) o0.h[j] = __float2half(a[j] * dn);
#pragma unroll
        for (int j = 0; j < 8; ++j) o1.h[j] = __float2half(a[8 + j] * dn);
        float4* op = reinterpret_cast<float4*>(hout + (size_t)n * 64 + q * 16);
        op[0] = o0.f4;
        op[1] = o1.f4;
    }
}

// F=16: 4 lanes per row (4 halves = 8B each), 16 edges in flight.
__global__ __launch_bounds__(256) void pull16h_kernel(const __half* __restrict__ hin,
                                                      const int* __restrict__ rowptr,
                                                      const int2* __restrict__ edge2,
                                                      const float* __restrict__ dinv,
                                                      __half* __restrict__ hout) {
    int lane = threadIdx.x & 63;
    int q  = lane & 3;
    int eo = lane >> 2;
    int n = blockIdx.x * 4 + (threadIdx.x >> 6);
    if (n >= Nn) return;
    int r0 = rowptr[n];
    int r1 = rowptr[n + 1];
    float a[4];
#pragma unroll
    for (int j = 0; j < 4; ++j) a[j] = 0.f;
    for (int e = r0 + eo; e < r1; e += 16) {
        int2 ed = edge2[e];
        float w = __int_as_float(ed.y);
        H4 u;
        u.f2 = *reinterpret_cast<const float2*>(hin + (size_t)ed.x * 16 + q * 4);
#pragma unroll
        for (int j = 0; j < 4; ++j) a[j] += w * __half2float(u.h[j]);
    }
#pragma unroll
    for (int off = 4; off < 64; off <<= 1)
#pragma unroll
        for (int j = 0; j < 4; ++j) a[j] += __shfl_xor(a[j], off);
    if (eo == 0) {
        float dn = dinv[n];
        H4 o;
#pragma unroll
        for (int j = 0; j < 4; ++j) o.h[j] = __float2half(a[j] * dn);
        *reinterpret_cast<float2*>(hout + (size_t)n * 16 + q * 4) = o.f2;
    }
}

// width-4 pull with fused add (f32 tables): out[n] = gadd[n] + dinv[n]*sum w*uin[s] (+beff)
template <int ADDBIAS>
__global__ __launch_bounds__(256) void pull4_kernel(const float* __restrict__ uin,
                                                    const float* __restrict__ gadd,
                                                    const int* __restrict__ rowptr,
                                                    const int2* __restrict__ edge2,
                                                    const float* __restrict__ dinv,
                                                    const float* __restrict__ beff,
                                                    float* __restrict__ out) {
    int lane = threadIdx.x & 63;
    int eo = lane & 15;
    int n = blockIdx.x * 16 + ((threadIdx.x >> 6) << 2) + (lane >> 4);
    if (n >= Nn) return;
    int r0 = rowptr[n];
    int r1 = rowptr[n + 1];
    float ax = 0.f, ay = 0.f, az = 0.f, aw = 0.f;
    for (int e = r0 + eo; e < r1; e += 16) {
        int2 ed = edge2[e];
        float w = __int_as_float(ed.y);
        float4 v = *reinterpret_cast<const float4*>(uin + (size_t)ed.x * 4);
        ax += w * v.x;
        ay += w * v.y;
        az += w * v.z;
        aw += w * v.w;
    }
#pragma unroll
    for (int off = 1; off < 16; off <<= 1) {
        ax += __shfl_xor(ax, off);
        ay += __shfl_xor(ay, off);
        az += __shfl_xor(az, off);
        aw += __shfl_xor(aw, off);
    }
    if (eo == 0) {
        float dn = dinv[n];
        float4 g = *reinterpret_cast<const float4*>(gadd + (size_t)n * 4);
        float4 o;
        o.x = g.x + dn * ax;
        o.y = g.y + dn * ay;
        o.z = g.z + dn * az;
        o.w = g.w + dn * aw;
        if (ADDBIAS) {
            o.x += beff[0]; o.y += beff[1]; o.z += beff[2]; o.w += beff[3];
        }
        *reinterpret_cast<float4*>(out + (size_t)n * 4) = o;
    }
}

// ================= fused 4-source GEMM (fp16 in, fp16 out, f32 math) =================
// out[N,64] = relu( sum_{k=0..3} Sk[N,KS] @ W[k][KS,64] + bias )

template <int KS>
__global__ __launch_bounds__(256) void gemm4_kernel(const __half* __restrict__ S0,
                                                    const __half* __restrict__ S1,
                                                    const __half* __restrict__ S2,
                                                    const __half* __restrict__ S3,
                                                    const float* __restrict__ W,
                                                    const float* __restrict__ bias,
                                                    __half* __restrict__ out) {
    constexpr int PITCH = KS + 4;
    __shared__ float Ht[128 * PITCH];
    __shared__ float Wt[KS * 64];
    int t = threadIdx.x;
    int c4 = t & 15;
    int r8 = t >> 4;  // 0..15
    int r0 = blockIdx.x * 128;
    float acc[8][4];
#pragma unroll
    for (int j = 0; j < 8; ++j)
#pragma unroll
        for (int d = 0; d < 4; ++d) acc[j][d] = 0.f;

    const __half* Ss[4] = {S0, S1, S2, S3};
#pragma unroll
    for (int k = 0; k < 4; ++k) {
        const __half* S = Ss[k];
        for (int i = t; i < KS * 16; i += 256)
            *reinterpret_cast<float4*>(&Wt[i * 4]) =
                *reinterpret_cast<const float4*>(W + (size_t)k * KS * 64 + i * 4);
        // stage H tile: 128 rows x KS halves -> f32 LDS
        for (int i = t; i < 128 * (KS / 8); i += 256) {
            int r = i / (KS / 8);
            int c8 = i % (KS / 8);
            int row = r0 + r;
            float* hp = &Ht[r * PITCH + c8 * 8];
            if (row < Nn) {
                H8 u;
                u.f4 = *reinterpret_cast<const float4*>(S + (size_t)row * KS + c8 * 8);
#pragma unroll
                for (int j = 0; j < 8; ++j) hp[j] = __half2float(u.h[j]);
            } else {
#pragma unroll
                for (int j = 0; j < 8; ++j) hp[j] = 0.f;
            }
        }
        __syncthreads();
#pragma unroll 4
        for (int f = 0; f < KS; ++f) {
            float4 b4 = *reinterpret_cast<const float4*>(&Wt[f * 64 + c4 * 4]);
#pragma unroll
            for (int j = 0; j < 8; ++j) {
                float a = Ht[(r8 + 16 * j) * PITCH + f];
                acc[j][0] += a * b4.x;
                acc[j][1] += a * b4.y;
                acc[j][2] += a * b4.z;
                acc[j][3] += a * b4.w;
            }
        }
        __syncthreads();
    }
    float4 bi = *reinterpret_cast<const float4*>(bias + c4 * 4);
#pragma unroll
    for (int j = 0; j < 8; ++j) {
        int row = r0 + r8 + 16 * j;
        if (row < Nn) {
            H4 o;
            o.h[0] = __float2half(fmaxf(acc[j][0] + bi.x, 0.f));
            o.h[1] = __float2half(fmaxf(acc[j][1] + bi.y, 0.f));
            o.h[2] = __float2half(fmaxf(acc[j][2] + bi.z, 0.f));
            o.h[3] = __float2half(fmaxf(acc[j][3] + bi.w, 0.f));
            *reinterpret_cast<float2*>(out + (size_t)row * 64 + c4 * 4) = o.f2;
        }
    }
}

// ================= last conv + FC folding =================
// Wg[k][c][j] = Wh[2][k][c][:] @ fcW[:,j];  beff = bh[2] @ fcW + fcb
__global__ __launch_bounds__(256) void weff_kernel(const float* __restrict__ W,   // Wh[2]: [4][64][64]
                                                   const float* __restrict__ b,   // bh[2]: [64]
                                                   const float* __restrict__ fcW, // [64][4]
                                                   const float* __restrict__ fcb, // [4]
                                                   float* __restrict__ Wg,        // [4][64][4]
                                                   float* __restrict__ beff) {    // [4]
    int t = threadIdx.x;  // t = k*64 + c
    int k = t >> 6, c = t & 63;
    const float* wrow = W + (size_t)t * 64;
    float a0 = 0.f, a1 = 0.f, a2 = 0.f, a3 = 0.f;
    for (int d = 0; d < 64; ++d) {
        float w = wrow[d];
        a0 += w * fcW[d * 4 + 0];
        a1 += w * fcW[d * 4 + 1];
        a2 += w * fcW[d * 4 + 2];
        a3 += w * fcW[d * 4 + 3];
    }
    float4 o; o.x = a0; o.y = a1; o.z = a2; o.w = a3;
    *reinterpret_cast<float4*>(Wg + k * 256 + c * 4) = o;
    if (t < 4) {
        float s = fcb[t];
        for (int d = 0; d < 64; ++d) s += b[d] * fcW[d * 4 + t];
        beff[t] = s;
    }
}

// Gk[n][j] = sum_c h[n][c] * Wg[k][c][j]  -> four [N,4] f32 buffers (G stride N*4)
__global__ __launch_bounds__(256) void gemmG_kernel(const __half* __restrict__ h,
                                                    const float* __restrict__ Wg,
                                                    float* __restrict__ G) {
    __shared__ float Ht[64 * 65];
    __shared__ float Wl[1024];
    int t = threadIdx.x;
    int r0 = blockIdx.x * 64;
    for (int i = t; i < 256; i += 256)
        *reinterpret_cast<float4*>(&Wl[i * 4]) = *reinterpret_cast<const float4*>(Wg + i * 4);
    for (int i = t; i < 64 * 8; i += 256) {
        int r = i >> 3;
        int c8 = i & 7;
        int row = r0 + r;
        float* hp = &Ht[r * 65 + c8 * 8];
        if (row < Nn) {
            H8 u;
            u.f4 = *reinterpret_cast<const float4*>(h + (size_t)row * 64 + c8 * 8);
#pragma unroll
            for (int j = 0; j < 8; ++j) hp[j] = __half2float(u.h[j]);
        } else {
#pragma unroll
            for (int j = 0; j < 8; ++j) hp[j] = 0.f;
        }
    }
    __syncthreads();
    int r = t & 63;
    int k = t >> 6;
    float a0 = 0.f, a1 = 0.f, a2 = 0.f, a3 = 0.f;
#pragma unroll 8
    for (int c = 0; c < 64; ++c) {
        float hv = Ht[r * 65 + c];
        const float* wp = &Wl[k * 256 + c * 4];
        a0 += hv * wp[0];
        a1 += hv * wp[1];
        a2 += hv * wp[2];
        a3 += hv * wp[3];
    }
    int row = r0 + r;
    if (row < Nn) {
        float4 o; o.x = a0; o.y = a1; o.z = a2; o.w = a3;
        *reinterpret_cast<float4*>(G + (size_t)k * Nn * 4 + (size_t)row * 4) = o;
    }
}

// ================= host driver =================

extern "C" void kernel_launch(void* const* d_in, const int* in_sizes, int n_in,
                              void* d_out, int out_size, void* d_ws, size_t ws_size,
                              hipStream_t stream) {
    const float* x   = (const float*)d_in[0];
    const int*   ei  = (const int*)d_in[1];   // [2, E] int32
    const float* W0  = (const float*)d_in[2]; // [4,16,64]
    const float* b0  = (const float*)d_in[3]; // [64]
    const float* Wh  = (const float*)d_in[4]; // [3,4,64,64]
    const float* bh  = (const float*)d_in[5]; // [3,64]
    const float* fcW = (const float*)d_in[6]; // [64,4]
    const float* fcb = (const float*)d_in[7]; // [4]
    float* out = (float*)d_out;

    const int* src = ei;
    const int* dst = ei + Ne;

    // ws layout (16B-aligned regions):
    // rowptr[100004] | edge2[2E] | rank[E] | dinv[N] | bsum[128] | Wg[1024] | beff[16]
    // | xh[N*16]h | H0..H3[N*64]h | G(6*N*4 f32)
    int*    rowptr = (int*)d_ws;
    int2*   edge2  = (int2*)(rowptr + 100004);
    int*    rank   = (int*)(rowptr + 100004 + 2 * Ne);
    float*  dinv   = (float*)(rank + Ne);
    int*    bsum   = (int*)(dinv + Nn);
    float*  Wg     = (float*)(bsum + 128);
    float*  beff   = Wg + 1024;
    __half* xh     = (__half*)(beff + 16);
    __half* H0     = xh + (size_t)Nn * NF;
    __half* H1     = H0 + (size_t)Nn * HID;
    __half* H2     = H1 + (size_t)Nn * HID;
    __half* H3     = H2 + (size_t)Nn * HID;
    float*  G      = (float*)(H3 + (size_t)Nn * HID);
    float*  G0     = G + 0 * (size_t)Nn * 4;
    float*  G1     = G + 1 * (size_t)Nn * 4;
    float*  G2     = G + 2 * (size_t)Nn * 4;
    float*  G3     = G + 3 * (size_t)Nn * 4;
    float*  T      = G + 4 * (size_t)Nn * 4;
    float*  T2     = G + 5 * (size_t)Nn * 4;
    int*    cnt    = (int*)(T2 + (size_t)Nn * 4);  // build-time only

    const int egrid = (Ne + 255) / 256;
    const int ngrid = (Nn + 255) / 256;
    const int sgrid = (Nn + 1023) / 1024;  // 98
    const int pgrid = Nn / 4;              // 25000
    const int ggrid = (Nn + 127) / 128;    // 782
    const int qgrid = (Nn + 15) / 16;      // 6250
    const int Ggrid = (Nn + 63) / 64;      // 1563
    const int cgrid = (Nn * NF / 4 + 255) / 256;

    // --- CSR build + dinv + fused edge records ---
    hipMemsetAsync(cnt, 0, Nn * sizeof(int), stream);
    hist_kernel<<<egrid, 256, 0, stream>>>(dst, cnt, rank);
    scan1_kernel<<<sgrid, 256, 0, stream>>>(cnt, rowptr, bsum);
    scan2_kernel<<<1, 128, 0, stream>>>(bsum, sgrid);
    scan3_kernel<<<ngrid, 256, 0, stream>>>(cnt, rowptr, bsum, dinv);
    scatter_kernel<<<egrid, 256, 0, stream>>>(src, dst, rowptr, rank, dinv, edge2);
    weff_kernel<<<1, 256, 0, stream>>>(Wh + 2 * 4 * 64 * 64, bh + 2 * 64, fcW, fcb, Wg, beff);
    xcvt_kernel<<<cgrid, 256, 0, stream>>>(x, xh);

    // --- conv0 (F=16 hops, relu) -> H0 ---
    pull16h_kernel<<<pgrid, 256, 0, stream>>>(xh, rowptr, edge2, dinv, H1);
    pull16h_kernel<<<pgrid, 256, 0, stream>>>(H1, rowptr, edge2, dinv, H2);
    pull16h_kernel<<<pgrid, 256, 0, stream>>>(H2, rowptr, edge2, dinv, H3);
    gemm4_kernel<NF><<<ggrid, 256, 0, stream>>>(xh, H1, H2, H3, W0, b0, H0);

    // --- conv1, conv2 (relu) : H0 -> H0 ---
    for (int l = 0; l < 2; ++l) {
        pull64h_kernel<<<pgrid, 256, 0, stream>>>(H0, rowptr, edge2, dinv, H1);
        pull64h_kernel<<<pgrid, 256, 0, stream>>>(H1, rowptr, edge2, dinv, H2);
        pull64h_kernel<<<pgrid, 256, 0, stream>>>(H2, rowptr, edge2, dinv, H3);
        gemm4_kernel<HID><<<ggrid, 256, 0, stream>>>(H0, H1, H2, H3,
                                                     Wh + (size_t)l * 4 * HID * HID,
                                                     bh + (size_t)l * HID, H0);
    }

    // --- conv3 + FC, folded to width 4 + Horner (f32 chain) ---
    // out = G0 + A(G1 + A(G2 + A*G3)) + beff
    gemmG_kernel<<<Ggrid, 256, 0, stream>>>(H0, Wg, G);
    pull4_kernel<0><<<qgrid, 256, 0, stream>>>(G3, G2, rowptr, edge2, dinv, beff, T);
    pull4_kernel<0><<<qgrid, 256, 0, stream>>>(T,  G1, rowptr, edge2, dinv, beff, T2);
    pull4_kernel<1><<<qgrid, 256, 0, stream>>>(T2, G0, rowptr, edge2, dinv, beff, out);
}

// Round 7
// 629.856 us; speedup vs baseline: 21.2983x; 1.2676x over previous
//
#include <hip/hip_runtime.h>
#include <hip/hip_fp16.h>

// Problem constants (match reference)
constexpr int Nn   = 100000;   // nodes
constexpr int Ne   = 1600000;  // edges
constexpr int NF   = 16;       // input features
constexpr int HID  = 64;
constexpr int NOUT = 4;

union H8 { float4 f4; __half h[8]; };
union H4 { float2 f2; __half h[4]; };

// ================= CSR build =================

// hist + rank capture: rank[e] = arrival order of edge e within its dst row.
__global__ __launch_bounds__(256) void hist_kernel(const int* __restrict__ dst,
                                                   int* __restrict__ cnt,
                                                   int* __restrict__ rank) {
    int e = blockIdx.x * 256 + threadIdx.x;
    if (e < Ne) rank[e] = atomicAdd(&cnt[dst[e]], 1);
}

// phase1: each block scans 1024 elements (4/thread), local exclusive scan -> rowptr,
// block total -> bsum[b]
__global__ __launch_bounds__(256) void scan1_kernel(const int* __restrict__ cnt,
                                                    int* __restrict__ rowptr,
                                                    int* __restrict__ bsum) {
    __shared__ int lds[256];
    int t = threadIdx.x;
    int base = blockIdx.x * 1024 + t * 4;
    int v0 = (base + 0 < Nn) ? cnt[base + 0] : 0;
    int v1 = (base + 1 < Nn) ? cnt[base + 1] : 0;
    int v2 = (base + 2 < Nn) ? cnt[base + 2] : 0;
    int v3 = (base + 3 < Nn) ? cnt[base + 3] : 0;
    lds[t] = v0 + v1 + v2 + v3;
    __syncthreads();
    for (int off = 1; off < 256; off <<= 1) {
        int a = lds[t];
        int b = (t >= off) ? lds[t - off] : 0;
        __syncthreads();
        lds[t] = a + b;
        __syncthreads();
    }
    int excl = (t > 0) ? lds[t - 1] : 0;
    if (base + 0 < Nn) rowptr[base + 0] = excl;
    if (base + 1 < Nn) rowptr[base + 1] = excl + v0;
    if (base + 2 < Nn) rowptr[base + 2] = excl + v0 + v1;
    if (base + 3 < Nn) rowptr[base + 3] = excl + v0 + v1 + v2;
    if (t == 255) bsum[blockIdx.x] = lds[255];
}

// phase2: one block scans block sums -> exclusive offsets (nb <= 128)
__global__ __launch_bounds__(128) void scan2_kernel(int* __restrict__ bsum, int nb) {
    __shared__ int lds[128];
    int t = threadIdx.x;
    int v = (t < nb) ? bsum[t] : 0;
    lds[t] = v;
    __syncthreads();
    for (int off = 1; off < 128; off <<= 1) {
        int a = lds[t];
        int b = (t >= off) ? lds[t - off] : 0;
        __syncthreads();
        lds[t] = a + b;
        __syncthreads();
    }
    if (t < nb) bsum[t] = lds[t] - v;  // exclusive
}

// phase3: add block offsets, compute dinv, write rowptr[Nn]
__global__ __launch_bounds__(256) void scan3_kernel(const int* __restrict__ cnt,
                                                    int* __restrict__ rowptr,
                                                    const int* __restrict__ bsum,
                                                    float* __restrict__ dinv) {
    int i = blockIdx.x * 256 + threadIdx.x;
    if (i < Nn) {
        rowptr[i] += bsum[i >> 10];
        int c = cnt[i];
        dinv[i] = (c > 0) ? 1.0f / sqrtf((float)c) : 0.0f;
    }
    if (i == 0) rowptr[Nn] = Ne;
}

// scatter edges into CSR as interleaved {src, dinv[src]} 8B records — no atomics.
__global__ __launch_bounds__(256) void scatter_kernel(const int* __restrict__ src,
                                                      const int* __restrict__ dst,
                                                      const int* __restrict__ rowptr,
                                                      const int* __restrict__ rank,
                                                      const float* __restrict__ dinv,
                                                      int2* __restrict__ edge2) {
    int e = blockIdx.x * 256 + threadIdx.x;
    if (e < Ne) {
        int d = dst[e];
        int s = src[e];
        int p = rowptr[d] + rank[e];
        edge2[p] = make_int2(s, __float_as_int(dinv[s]));
    }
}

// x[N,16] f32 -> xh[N,16] fp16
__global__ __launch_bounds__(256) void xcvt_kernel(const float* __restrict__ x,
                                                   __half* __restrict__ xh) {
    int i = blockIdx.x * 256 + threadIdx.x;  // float4 chunk index
    if (i < Nn * NF / 4) {
        float4 v = reinterpret_cast<const float4*>(x)[i];
        H4 o;
        o.h[0] = __float2half(v.x);
        o.h[1] = __float2half(v.y);
        o.h[2] = __float2half(v.z);
        o.h[3] = __float2half(v.w);
        reinterpret_cast<float2*>(xh)[i] = o.f2;
    }
}

// ================= pull-mode propagation (fp16 tables, f32 math) =================
// Multi-node-per-wave: shallow shuffle reduce + loads in flight for most of the
// wave lifetime (R6 was whole-wave-per-node: 64 shfl/node and ~1.3 gather iters).

// F=64: 4 nodes per wave (16 lanes each); QL=4 lanes x 16 halves; EO=4 edges in flight.
// lane = g*16 + eo*4 + q
__global__ __launch_bounds__(256) void pull64h_kernel(const __half* __restrict__ hin,
                                                      const int* __restrict__ rowptr,
                                                      const int2* __restrict__ edge2,
                                                      const float* __restrict__ dinv,
                                                      __half* __restrict__ hout) {
    int lane = threadIdx.x & 63;
    int q  = lane & 3;          // 16-half chunk index
    int eo = (lane >> 2) & 3;   // edge slot
    int g  = lane >> 4;         // node sub-index
    int n = blockIdx.x * 16 + (threadIdx.x >> 6) * 4 + g;
    if (n >= Nn) return;  // whole 16-lane group exits together
    int r0 = rowptr[n];
    int r1 = rowptr[n + 1];
    float a[16];
#pragma unroll
    for (int j = 0; j < 16; ++j) a[j] = 0.f;
#pragma unroll 2
    for (int e = r0 + eo; e < r1; e += 4) {
        int2 ed = edge2[e];
        float w = __int_as_float(ed.y);
        const float4* rp = reinterpret_cast<const float4*>(hin + (size_t)ed.x * 64 + q * 16);
        H8 u0, u1;
        u0.f4 = rp[0];
        u1.f4 = rp[1];
#pragma unroll
        for (int j = 0; j < 8; ++j) a[j] += w * __half2float(u0.h[j]);
#pragma unroll
        for (int j = 0; j < 8; ++j) a[8 + j] += w * __half2float(u1.h[j]);
    }
    // reduce across eo (bits 2-3 of lane): offsets 4, 8
#pragma unroll
    for (int off = 4; off <= 8; off <<= 1)
#pragma unroll
        for (int j = 0; j < 16; ++j) a[j] += __shfl_xor(a[j], off);
    if (eo == 0) {
        float dn = dinv[n];
        H8 o0, o1;
#pragma unroll
        for (int j = 0; j < 8; ++j) o0.h[j] = __float2half(a[j] * dn);
#pragma unroll
        for (int j = 0; j < 8; ++j) o1.h[j] = __float2half(a[8 + j] * dn);
        float4* op = reinterpret_cast<float4*>(hout + (size_t)n * 64 + q * 16);
        op[0] = o0.f4;
        op[1] = o1.f4;
    }
}

// F=16: 8 nodes per wave (8 lanes each); QL=2 lanes x 8 halves (16B); EO=4.
// lane = g*8 + eo*2 + q
__global__ __launch_bounds__(256) void pull16h_kernel(const __half* __restrict__ hin,
                                                      const int* __restrict__ rowptr,
                                                      const int2* __restrict__ edge2,
                                                      const float* __restrict__ dinv,
                                                      __half* __restrict__ hout) {
    int lane = threadIdx.x & 63;
    int q  = lane & 1;
    int eo = (lane >> 1) & 3;
    int g  = lane >> 3;
    int n = blockIdx.x * 32 + (threadIdx.x >> 6) * 8 + g;
    if (n >= Nn) return;
    int r0 = rowptr[n];
    int r1 = rowptr[n + 1];
    float a[8];
#pragma unroll
    for (int j = 0; j < 8; ++j) a[j] = 0.f;
#pragma unroll 2
    for (int e = r0 + eo; e < r1; e += 4) {
        int2 ed = edge2[e];
        float w = __int_as_float(ed.y);
        H8 u;
        u.f4 = *reinterpret_cast<const float4*>(hin + (size_t)ed.x * 16 + q * 8);
#pragma unroll
        for (int j = 0; j < 8; ++j) a[j] += w * __half2float(u.h[j]);
    }
    // reduce across eo (bits 1-2): offsets 2, 4
#pragma unroll
    for (int off = 2; off <= 4; off <<= 1)
#pragma unroll
        for (int j = 0; j < 8; ++j) a[j] += __shfl_xor(a[j], off);
    if (eo == 0) {
        float dn = dinv[n];
        H8 o;
#pragma unroll
        for (int j = 0; j < 8; ++j) o.h[j] = __float2half(a[j] * dn);
        *reinterpret_cast<float4*>(hout + (size_t)n * 16 + q * 8) = o.f4;
    }
}

// width-4 pull with fused add (f32 tables): out[n] = gadd[n] + dinv[n]*sum w*uin[s] (+beff)
template <int ADDBIAS>
__global__ __launch_bounds__(256) void pull4_kernel(const float* __restrict__ uin,
                                                    const float* __restrict__ gadd,
                                                    const int* __restrict__ rowptr,
                                                    const int2* __restrict__ edge2,
                                                    const float* __restrict__ dinv,
                                                    const float* __restrict__ beff,
                                                    float* __restrict__ out) {
    int lane = threadIdx.x & 63;
    int eo = lane & 15;
    int n = blockIdx.x * 16 + ((threadIdx.x >> 6) << 2) + (lane >> 4);
    if (n >= Nn) return;
    int r0 = rowptr[n];
    int r1 = rowptr[n + 1];
    float ax = 0.f, ay = 0.f, az = 0.f, aw = 0.f;
    for (int e = r0 + eo; e < r1; e += 16) {
        int2 ed = edge2[e];
        float w = __int_as_float(ed.y);
        float4 v = *reinterpret_cast<const float4*>(uin + (size_t)ed.x * 4);
        ax += w * v.x;
        ay += w * v.y;
        az += w * v.z;
        aw += w * v.w;
    }
#pragma unroll
    for (int off = 1; off < 16; off <<= 1) {
        ax += __shfl_xor(ax, off);
        ay += __shfl_xor(ay, off);
        az += __shfl_xor(az, off);
        aw += __shfl_xor(aw, off);
    }
    if (eo == 0) {
        float dn = dinv[n];
        float4 g = *reinterpret_cast<const float4*>(gadd + (size_t)n * 4);
        float4 o;
        o.x = g.x + dn * ax;
        o.y = g.y + dn * ay;
        o.z = g.z + dn * az;
        o.w = g.w + dn * aw;
        if (ADDBIAS) {
            o.x += beff[0]; o.y += beff[1]; o.z += beff[2]; o.w += beff[3];
        }
        *reinterpret_cast<float4*>(out + (size_t)n * 4) = o;
    }
}

// ================= fused 4-source GEMM (fp16 in, fp16 out, f32 math) =================
// out[N,64] = relu( sum_{k=0..3} Sk[N,KS] @ W[k][KS,64] + bias )

template <int KS>
__global__ __launch_bounds__(256) void gemm4_kernel(const __half* __restrict__ S0,
                                                    const __half* __restrict__ S1,
                                                    const __half* __restrict__ S2,
                                                    const __half* __restrict__ S3,
                                                    const float* __restrict__ W,
                                                    const float* __restrict__ bias,
                                                    __half* __restrict__ out) {
    constexpr int PITCH = KS + 4;
    __shared__ float Ht[128 * PITCH];
    __shared__ float Wt[KS * 64];
    int t = threadIdx.x;
    int c4 = t & 15;
    int r8 = t >> 4;  // 0..15
    int r0 = blockIdx.x * 128;
    float acc[8][4];
#pragma unroll
    for (int j = 0; j < 8; ++j)
#pragma unroll
        for (int d = 0; d < 4; ++d) acc[j][d] = 0.f;

    const __half* Ss[4] = {S0, S1, S2, S3};
#pragma unroll
    for (int k = 0; k < 4; ++k) {
        const __half* S = Ss[k];
        for (int i = t; i < KS * 16; i += 256)
            *reinterpret_cast<float4*>(&Wt[i * 4]) =
                *reinterpret_cast<const float4*>(W + (size_t)k * KS * 64 + i * 4);
        // stage H tile: 128 rows x KS halves -> f32 LDS
        for (int i = t; i < 128 * (KS / 8); i += 256) {
            int r = i / (KS / 8);
            int c8 = i % (KS / 8);
            int row = r0 + r;
            float* hp = &Ht[r * PITCH + c8 * 8];
            if (row < Nn) {
                H8 u;
                u.f4 = *reinterpret_cast<const float4*>(S + (size_t)row * KS + c8 * 8);
#pragma unroll
                for (int j = 0; j < 8; ++j) hp[j] = __half2float(u.h[j]);
            } else {
#pragma unroll
                for (int j = 0; j < 8; ++j) hp[j] = 0.f;
            }
        }
        __syncthreads();
#pragma unroll 4
        for (int f = 0; f < KS; ++f) {
            float4 b4 = *reinterpret_cast<const float4*>(&Wt[f * 64 + c4 * 4]);
#pragma unroll
            for (int j = 0; j < 8; ++j) {
                float a = Ht[(r8 + 16 * j) * PITCH + f];
                acc[j][0] += a * b4.x;
                acc[j][1] += a * b4.y;
                acc[j][2] += a * b4.z;
                acc[j][3] += a * b4.w;
            }
        }
        __syncthreads();
    }
    float4 bi = *reinterpret_cast<const float4*>(bias + c4 * 4);
#pragma unroll
    for (int j = 0; j < 8; ++j) {
        int row = r0 + r8 + 16 * j;
        if (row < Nn) {
            H4 o;
            o.h[0] = __float2half(fmaxf(acc[j][0] + bi.x, 0.f));
            o.h[1] = __float2half(fmaxf(acc[j][1] + bi.y, 0.f));
            o.h[2] = __float2half(fmaxf(acc[j][2] + bi.z, 0.f));
            o.h[3] = __float2half(fmaxf(acc[j][3] + bi.w, 0.f));
            *reinterpret_cast<float2*>(out + (size_t)row * 64 + c4 * 4) = o.f2;
        }
    }
}

// ================= last conv + FC folding =================
// Wg[k][c][j] = Wh[2][k][c][:] @ fcW[:,j];  beff = bh[2] @ fcW + fcb
__global__ __launch_bounds__(256) void weff_kernel(const float* __restrict__ W,   // Wh[2]: [4][64][64]
                                                   const float* __restrict__ b,   // bh[2]: [64]
                                                   const float* __restrict__ fcW, // [64][4]
                                                   const float* __restrict__ fcb, // [4]
                                                   float* __restrict__ Wg,        // [4][64][4]
                                                   float* __restrict__ beff) {    // [4]
    int t = threadIdx.x;  // t = k*64 + c
    int k = t >> 6, c = t & 63;
    const float* wrow = W + (size_t)t * 64;
    float a0 = 0.f, a1 = 0.f, a2 = 0.f, a3 = 0.f;
    for (int d = 0; d < 64; ++d) {
        float w = wrow[d];
        a0 += w * fcW[d * 4 + 0];
        a1 += w * fcW[d * 4 + 1];
        a2 += w * fcW[d * 4 + 2];
        a3 += w * fcW[d * 4 + 3];
    }
    float4 o; o.x = a0; o.y = a1; o.z = a2; o.w = a3;
    *reinterpret_cast<float4*>(Wg + k * 256 + c * 4) = o;
    if (t < 4) {
        float s = fcb[t];
        for (int d = 0; d < 64; ++d) s += b[d] * fcW[d * 4 + t];
        beff[t] = s;
    }
}

// Gk[n][j] = sum_c h[n][c] * Wg[k][c][j]  -> four [N,4] f32 buffers (G stride N*4)
__global__ __launch_bounds__(256) void gemmG_kernel(const __half* __restrict__ h,
                                                    const float* __restrict__ Wg,
                                                    float* __restrict__ G) {
    __shared__ float Ht[64 * 65];
    __shared__ float Wl[1024];
    int t = threadIdx.x;
    int r0 = blockIdx.x * 64;
    for (int i = t; i < 256; i += 256)
        *reinterpret_cast<float4*>(&Wl[i * 4]) = *reinterpret_cast<const float4*>(Wg + i * 4);
    for (int i = t; i < 64 * 8; i += 256) {
        int r = i >> 3;
        int c8 = i & 7;
        int row = r0 + r;
        float* hp = &Ht[r * 65 + c8 * 8];
        if (row < Nn) {
            H8 u;
            u.f4 = *reinterpret_cast<const float4*>(h + (size_t)row * 64 + c8 * 8);
#pragma unroll
            for (int j = 0; j < 8; ++j) hp[j] = __half2float(u.h[j]);
        } else {
#pragma unroll
            for (int j = 0; j < 8; ++j) hp[j] = 0.f;
        }
    }
    __syncthreads();
    int r = t & 63;
    int k = t >> 6;
    float a0 = 0.f, a1 = 0.f, a2 = 0.f, a3 = 0.f;
#pragma unroll 8
    for (int c = 0; c < 64; ++c) {
        float hv = Ht[r * 65 + c];
        const float* wp = &Wl[k * 256 + c * 4];
        a0 += hv * wp[0];
        a1 += hv * wp[1];
        a2 += hv * wp[2];
        a3 += hv * wp[3];
    }
    int row = r0 + r;
    if (row < Nn) {
        float4 o; o.x = a0; o.y = a1; o.z = a2; o.w = a3;
        *reinterpret_cast<float4*>(G + (size_t)k * Nn * 4 + (size_t)row * 4) = o;
    }
}

// ================= host driver =================

extern "C" void kernel_launch(void* const* d_in, const int* in_sizes, int n_in,
                              void* d_out, int out_size, void* d_ws, size_t ws_size,
                              hipStream_t stream) {
    const float* x   = (const float*)d_in[0];
    const int*   ei  = (const int*)d_in[1];   // [2, E] int32
    const float* W0  = (const float*)d_in[2]; // [4,16,64]
    const float* b0  = (const float*)d_in[3]; // [64]
    const float* Wh  = (const float*)d_in[4]; // [3,4,64,64]
    const float* bh  = (const float*)d_in[5]; // [3,64]
    const float* fcW = (const float*)d_in[6]; // [64,4]
    const float* fcb = (const float*)d_in[7]; // [4]
    float* out = (float*)d_out;

    const int* src = ei;
    const int* dst = ei + Ne;

    // ws layout (16B-aligned regions):
    // rowptr[100004] | edge2[2E] | rank[E] | dinv[N] | bsum[128] | Wg[1024] | beff[16]
    // | xh[N*16]h | H0..H3[N*64]h | G(6*N*4 f32)
    int*    rowptr = (int*)d_ws;
    int2*   edge2  = (int2*)(rowptr + 100004);
    int*    rank   = (int*)(rowptr + 100004 + 2 * Ne);
    float*  dinv   = (float*)(rank + Ne);
    int*    bsum   = (int*)(dinv + Nn);
    float*  Wg     = (float*)(bsum + 128);
    float*  beff   = Wg + 1024;
    __half* xh     = (__half*)(beff + 16);
    __half* H0     = xh + (size_t)Nn * NF;
    __half* H1     = H0 + (size_t)Nn * HID;
    __half* H2     = H1 + (size_t)Nn * HID;
    __half* H3     = H2 + (size_t)Nn * HID;
    float*  G      = (float*)(H3 + (size_t)Nn * HID);
    float*  G0     = G + 0 * (size_t)Nn * 4;
    float*  G1     = G + 1 * (size_t)Nn * 4;
    float*  G2     = G + 2 * (size_t)Nn * 4;
    float*  G3     = G + 3 * (size_t)Nn * 4;
    float*  T      = G + 4 * (size_t)Nn * 4;
    float*  T2     = G + 5 * (size_t)Nn * 4;
    int*    cnt    = (int*)(T2 + (size_t)Nn * 4);  // build-time only

    const int egrid  = (Ne + 255) / 256;
    const int ngrid  = (Nn + 255) / 256;
    const int sgrid  = (Nn + 1023) / 1024;  // 98
    const int p64grid = (Nn + 15) / 16;     // 6250 (4 nodes/wave, 4 waves/block)
    const int p16grid = (Nn + 31) / 32;     // 3125 (8 nodes/wave)
    const int ggrid  = (Nn + 127) / 128;    // 782
    const int qgrid  = (Nn + 15) / 16;      // 6250
    const int Ggrid  = (Nn + 63) / 64;      // 1563
    const int cgrid  = (Nn * NF / 4 + 255) / 256;

    // --- CSR build + dinv + fused edge records ---
    hipMemsetAsync(cnt, 0, Nn * sizeof(int), stream);
    hist_kernel<<<egrid, 256, 0, stream>>>(dst, cnt, rank);
    scan1_kernel<<<sgrid, 256, 0, stream>>>(cnt, rowptr, bsum);
    scan2_kernel<<<1, 128, 0, stream>>>(bsum, sgrid);
    scan3_kernel<<<ngrid, 256, 0, stream>>>(cnt, rowptr, bsum, dinv);
    scatter_kernel<<<egrid, 256, 0, stream>>>(src, dst, rowptr, rank, dinv, edge2);
    weff_kernel<<<1, 256, 0, stream>>>(Wh + 2 * 4 * 64 * 64, bh + 2 * 64, fcW, fcb, Wg, beff);
    xcvt_kernel<<<cgrid, 256, 0, stream>>>(x, xh);

    // --- conv0 (F=16 hops, relu) -> H0 ---
    pull16h_kernel<<<p16grid, 256, 0, stream>>>(xh, rowptr, edge2, dinv, H1);
    pull16h_kernel<<<p16grid, 256, 0, stream>>>(H1, rowptr, edge2, dinv, H2);
    pull16h_kernel<<<p16grid, 256, 0, stream>>>(H2, rowptr, edge2, dinv, H3);
    gemm4_kernel<NF><<<ggrid, 256, 0, stream>>>(xh, H1, H2, H3, W0, b0, H0);

    // --- conv1, conv2 (relu) : H0 -> H0 ---
    for (int l = 0; l < 2; ++l) {
        pull64h_kernel<<<p64grid, 256, 0, stream>>>(H0, rowptr, edge2, dinv, H1);
        pull64h_kernel<<<p64grid, 256, 0, stream>>>(H1, rowptr, edge2, dinv, H2);
        pull64h_kernel<<<p64grid, 256, 0, stream>>>(H2, rowptr, edge2, dinv, H3);
        gemm4_kernel<HID><<<ggrid, 256, 0, stream>>>(H0, H1, H2, H3,
                                                     Wh + (size_t)l * 4 * HID * HID,
                                                     bh + (size_t)l * HID, H0);
    }

    // --- conv3 + FC, folded to width 4 + Horner (f32 chain) ---
    // out = G0 + A(G1 + A(G2 + A*G3)) + beff
    gemmG_kernel<<<Ggrid, 256, 0, stream>>>(H0, Wg, G);
    pull4_kernel<0><<<qgrid, 256, 0, stream>>>(G3, G2, rowptr, edge2, dinv, beff, T);
    pull4_kernel<0><<<qgrid, 256, 0, stream>>>(T,  G1, rowptr, edge2, dinv, beff, T2);
    pull4_kernel<1><<<qgrid, 256, 0, stream>>>(T2, G0, rowptr, edge2, dinv, beff, out);
}

// Round 8
// 592.079 us; speedup vs baseline: 22.6572x; 1.0638x over previous
//
#include <hip/hip_runtime.h>
#include <hip/hip_fp16.h>

// Problem constants (match reference)
constexpr int Nn   = 100000;   // nodes
constexpr int Ne   = 1600000;  // edges
constexpr int NF   = 16;       // input features
constexpr int HID  = 64;
constexpr int NOUT = 4;

// Bucket-sort CSR build params
constexpr int NBUK  = 391;                     // dst>>8 buckets (99999>>8 = 390)
constexpr int CHUNK = 2048;                    // edges per phase-1 block
constexpr int NB1   = (Ne + CHUNK - 1) / CHUNK;  // 782
constexpr int NS    = NBUK * NB1;              // 305762 ghist entries
constexpr int STASH = 6144;                    // K2 LDS stash (48 KB); bucket mean 4092, sd 64

union H8 { float4 f4; __half h[8]; };
union H4 { float2 f2; __half h[4]; };

// ================= CSR build (atomic-free, 2-level bucket sort) =================

// K1a: per-block LDS histogram over 391 buckets, bin-major writeout
__global__ __launch_bounds__(256) void bhist_kernel(const int* __restrict__ dst,
                                                    int* __restrict__ ghist) {
    __shared__ int h[NBUK];
    int t = threadIdx.x;
    int b = blockIdx.x;
    for (int i = t; i < NBUK; i += 256) h[i] = 0;
    __syncthreads();
    int e0 = b * CHUNK;
    int e1 = (e0 + CHUNK < Ne) ? e0 + CHUNK : Ne;
    for (int e = e0 + t; e < e1; e += 256) atomicAdd(&h[dst[e] >> 8], 1);
    __syncthreads();
    for (int i = t; i < NBUK; i += 256) ghist[i * NB1 + b] = h[i];
}

// scan phase1: in-place exclusive scan of 1024-elem chunks of ghist; block totals -> bsum
__global__ __launch_bounds__(256) void scan1g_kernel(int* __restrict__ g,
                                                     int* __restrict__ bsum) {
    __shared__ int lds[256];
    int t = threadIdx.x;
    int base = blockIdx.x * 1024 + t * 4;
    int v0 = (base + 0 < NS) ? g[base + 0] : 0;
    int v1 = (base + 1 < NS) ? g[base + 1] : 0;
    int v2 = (base + 2 < NS) ? g[base + 2] : 0;
    int v3 = (base + 3 < NS) ? g[base + 3] : 0;
    lds[t] = v0 + v1 + v2 + v3;
    __syncthreads();
    for (int off = 1; off < 256; off <<= 1) {
        int a = lds[t];
        int b = (t >= off) ? lds[t - off] : 0;
        __syncthreads();
        lds[t] = a + b;
        __syncthreads();
    }
    int excl = (t > 0) ? lds[t - 1] : 0;
    if (base + 0 < NS) g[base + 0] = excl;
    if (base + 1 < NS) g[base + 1] = excl + v0;
    if (base + 2 < NS) g[base + 2] = excl + v0 + v1;
    if (base + 3 < NS) g[base + 3] = excl + v0 + v1 + v2;
    if (t == 255) bsum[blockIdx.x] = lds[255];
}

// scan phase2: one block (512 threads) scans block sums -> exclusive (nb <= 512)
__global__ __launch_bounds__(512) void scan2g_kernel(int* __restrict__ bsum, int nb) {
    __shared__ int lds[512];
    int t = threadIdx.x;
    int v = (t < nb) ? bsum[t] : 0;
    lds[t] = v;
    __syncthreads();
    for (int off = 1; off < 512; off <<= 1) {
        int a = lds[t];
        int b = (t >= off) ? lds[t - off] : 0;
        __syncthreads();
        lds[t] = a + b;
        __syncthreads();
    }
    if (t < nb) bsum[t] = lds[t] - v;  // exclusive
}

// scan phase3: add block offsets
__global__ __launch_bounds__(256) void scan3g_kernel(int* __restrict__ g,
                                                     const int* __restrict__ bsum) {
    int i = blockIdx.x * 256 + threadIdx.x;
    if (i < NS) g[i] += bsum[i >> 10];
}

// K1c: scatter edges into bucket-contiguous tmp ({src,dst} records), LDS ranks
__global__ __launch_bounds__(256) void bscatter_kernel(const int* __restrict__ src,
                                                       const int* __restrict__ dst,
                                                       const int* __restrict__ ghist,
                                                       int2* __restrict__ tmp) {
    __shared__ int hb[NBUK];
    __shared__ int cur[NBUK];
    int t = threadIdx.x;
    int b = blockIdx.x;
    for (int i = t; i < NBUK; i += 256) {
        hb[i] = ghist[i * NB1 + b];
        cur[i] = 0;
    }
    __syncthreads();
    int e0 = b * CHUNK;
    int e1 = (e0 + CHUNK < Ne) ? e0 + CHUNK : Ne;
    for (int e = e0 + t; e < e1; e += 256) {
        int d = dst[e];
        int s = src[e];
        int bin = d >> 8;
        int r = atomicAdd(&cur[bin], 1);
        tmp[hb[bin] + r] = make_int2(s, d);
    }
}

// K2: one block per bucket. Stash bucket in LDS, 256-bin hist on dst&255,
// LDS scan -> rowptr + dinv + final CSR placement (colsrc).
__global__ __launch_bounds__(256) void bcsr_kernel(const int2* __restrict__ tmp,
                                                   const int* __restrict__ ghist,
                                                   int* __restrict__ rowptr,
                                                   float* __restrict__ dinv,
                                                   int* __restrict__ colsrc) {
    __shared__ int2 stash[STASH];
    __shared__ int h[256];
    __shared__ int hs[256];
    __shared__ int cur[256];
    int t = threadIdx.x;
    int b = blockIdx.x;
    int lo = ghist[b * NB1];
    int hi = (b < NBUK - 1) ? ghist[(b + 1) * NB1] : Ne;
    int sz = hi - lo;
    h[t] = 0;
    cur[t] = 0;
    __syncthreads();
    // pass A: load + histogram
    for (int i = t; i < sz; i += 256) {
        int2 rec = tmp[lo + i];
        if (i < STASH) stash[i] = rec;
        atomicAdd(&h[rec.y & 255], 1);
    }
    __syncthreads();
    // LDS exclusive scan over 256 bins
    int myh = h[t];
    hs[t] = myh;
    __syncthreads();
    for (int off = 1; off < 256; off <<= 1) {
        int a = hs[t];
        int bb = (t >= off) ? hs[t - off] : 0;
        __syncthreads();
        hs[t] = a + bb;
        __syncthreads();
    }
    int excl = hs[t] - myh;
    __syncthreads();
    hs[t] = excl;
    // rowptr + dinv for this bucket's 256 node ids
    int d = (b << 8) + t;
    if (d < Nn) {
        rowptr[d] = lo + excl;
        dinv[d] = (myh > 0) ? rsqrtf((float)myh) : 0.0f;
    }
    if (b == NBUK - 1 && t == 0) rowptr[Nn] = Ne;
    __syncthreads();
    // pass C: place edges
    for (int i = t; i < sz; i += 256) {
        int2 rec = (i < STASH) ? stash[i] : tmp[lo + i];
        int bin = rec.y & 255;
        int r = atomicAdd(&cur[bin], 1);
        colsrc[lo + hs[bin] + r] = rec.x;
    }
}

// K4: expand colsrc -> edge2 = {src, dinv[src]}
__global__ __launch_bounds__(256) void fill_kernel(const int* __restrict__ colsrc,
                                                   const float* __restrict__ dinv,
                                                   int2* __restrict__ edge2) {
    int e = blockIdx.x * 256 + threadIdx.x;
    if (e < Ne) {
        int s = colsrc[e];
        edge2[e] = make_int2(s, __float_as_int(dinv[s]));
    }
}

// x[N,16] f32 -> xh[N,16] fp16
__global__ __launch_bounds__(256) void xcvt_kernel(const float* __restrict__ x,
                                                   __half* __restrict__ xh) {
    int i = blockIdx.x * 256 + threadIdx.x;  // float4 chunk index
    if (i < Nn * NF / 4) {
        float4 v = reinterpret_cast<const float4*>(x)[i];
        H4 o;
        o.h[0] = __float2half(v.x);
        o.h[1] = __float2half(v.y);
        o.h[2] = __float2half(v.z);
        o.h[3] = __float2half(v.w);
        reinterpret_cast<float2*>(xh)[i] = o.f2;
    }
}

// ================= pull-mode propagation (fp16 tables, f32 math) =================
// Multi-node-per-wave: shallow shuffle reduce, loads in flight most of wave lifetime.

// F=64: 4 nodes per wave (16 lanes each); QL=4 lanes x 16 halves; EO=4 edges in flight.
__global__ __launch_bounds__(256) void pull64h_kernel(const __half* __restrict__ hin,
                                                      const int* __restrict__ rowptr,
                                                      const int2* __restrict__ edge2,
                                                      const float* __restrict__ dinv,
                                                      __half* __restrict__ hout) {
    int lane = threadIdx.x & 63;
    int q  = lane & 3;          // 16-half chunk index
    int eo = (lane >> 2) & 3;   // edge slot
    int g  = lane >> 4;         // node sub-index
    int n = blockIdx.x * 16 + (threadIdx.x >> 6) * 4 + g;
    if (n >= Nn) return;  // whole 16-lane group exits together
    int r0 = rowptr[n];
    int r1 = rowptr[n + 1];
    float a[16];
#pragma unroll
    for (int j = 0; j < 16; ++j) a[j] = 0.f;
#pragma unroll 2
    for (int e = r0 + eo; e < r1; e += 4) {
        int2 ed = edge2[e];
        float w = __int_as_float(ed.y);
        const float4* rp = reinterpret_cast<const float4*>(hin + (size_t)ed.x * 64 + q * 16);
        H8 u0, u1;
        u0.f4 = rp[0];
        u1.f4 = rp[1];
#pragma unroll
        for (int j = 0; j < 8; ++j) a[j] += w * __half2float(u0.h[j]);
#pragma unroll
        for (int j = 0; j < 8; ++j) a[8 + j] += w * __half2float(u1.h[j]);
    }
#pragma unroll
    for (int off = 4; off <= 8; off <<= 1)
#pragma unroll
        for (int j = 0; j < 16; ++j) a[j] += __shfl_xor(a[j], off);
    if (eo == 0) {
        float dn = dinv[n];
        H8 o0, o1;
#pragma unroll
        for (int j = 0; j < 8; ++j) o0.h[j] = __float2half(a[j] * dn);
#pragma unroll
        for (int j = 0; j < 8; ++j) o1.h[j] = __float2half(a[8 + j] * dn);
        float4* op = reinterpret_cast<float4*>(hout + (size_t)n * 64 + q * 16);
        op[0] = o0.f4;
        op[1] = o1.f4;
    }
}

// F=16: 8 nodes per wave (8 lanes each); QL=2 lanes x 8 halves (16B); EO=4.
__global__ __launch_bounds__(256) void pull16h_kernel(const __half* __restrict__ hin,
                                                      const int* __restrict__ rowptr,
                                                      const int2* __restrict__ edge2,
                                                      const float* __restrict__ dinv,
                                                      __half* __restrict__ hout) {
    int lane = threadIdx.x & 63;
    int q  = lane & 1;
    int eo = (lane >> 1) & 3;
    int g  = lane >> 3;
    int n = blockIdx.x * 32 + (threadIdx.x >> 6) * 8 + g;
    if (n >= Nn) return;
    int r0 = rowptr[n];
    int r1 = rowptr[n + 1];
    float a[8];
#pragma unroll
    for (int j = 0; j < 8; ++j) a[j] = 0.f;
#pragma unroll 2
    for (int e = r0 + eo; e < r1; e += 4) {
        int2 ed = edge2[e];
        float w = __int_as_float(ed.y);
        H8 u;
        u.f4 = *reinterpret_cast<const float4*>(hin + (size_t)ed.x * 16 + q * 8);
#pragma unroll
        for (int j = 0; j < 8; ++j) a[j] += w * __half2float(u.h[j]);
    }
#pragma unroll
    for (int off = 2; off <= 4; off <<= 1)
#pragma unroll
        for (int j = 0; j < 8; ++j) a[j] += __shfl_xor(a[j], off);
    if (eo == 0) {
        float dn = dinv[n];
        H8 o;
#pragma unroll
        for (int j = 0; j < 8; ++j) o.h[j] = __float2half(a[j] * dn);
        *reinterpret_cast<float4*>(hout + (size_t)n * 16 + q * 8) = o.f4;
    }
}

// width-4 pull with fused add (f32 tables): out[n] = gadd[n] + dinv[n]*sum w*uin[s] (+beff)
template <int ADDBIAS>
__global__ __launch_bounds__(256) void pull4_kernel(const float* __restrict__ uin,
                                                    const float* __restrict__ gadd,
                                                    const int* __restrict__ rowptr,
                                                    const int2* __restrict__ edge2,
                                                    const float* __restrict__ dinv,
                                                    const float* __restrict__ beff,
                                                    float* __restrict__ out) {
    int lane = threadIdx.x & 63;
    int eo = lane & 15;
    int n = blockIdx.x * 16 + ((threadIdx.x >> 6) << 2) + (lane >> 4);
    if (n >= Nn) return;
    int r0 = rowptr[n];
    int r1 = rowptr[n + 1];
    float ax = 0.f, ay = 0.f, az = 0.f, aw = 0.f;
    for (int e = r0 + eo; e < r1; e += 16) {
        int2 ed = edge2[e];
        float w = __int_as_float(ed.y);
        float4 v = *reinterpret_cast<const float4*>(uin + (size_t)ed.x * 4);
        ax += w * v.x;
        ay += w * v.y;
        az += w * v.z;
        aw += w * v.w;
    }
#pragma unroll
    for (int off = 1; off < 16; off <<= 1) {
        ax += __shfl_xor(ax, off);
        ay += __shfl_xor(ay, off);
        az += __shfl_xor(az, off);
        aw += __shfl_xor(aw, off);
    }
    if (eo == 0) {
        float dn = dinv[n];
        float4 g = *reinterpret_cast<const float4*>(gadd + (size_t)n * 4);
        float4 o;
        o.x = g.x + dn * ax;
        o.y = g.y + dn * ay;
        o.z = g.z + dn * az;
        o.w = g.w + dn * aw;
        if (ADDBIAS) {
            o.x += beff[0]; o.y += beff[1]; o.z += beff[2]; o.w += beff[3];
        }
        *reinterpret_cast<float4*>(out + (size_t)n * 4) = o;
    }
}

// ================= fused 4-source GEMM (fp16 in, fp16 out, f32 math) =================
// out[N,64] = relu( sum_{k=0..3} Sk[N,KS] @ W[k][KS,64] + bias )

template <int KS>
__global__ __launch_bounds__(256) void gemm4_kernel(const __half* __restrict__ S0,
                                                    const __half* __restrict__ S1,
                                                    const __half* __restrict__ S2,
                                                    const __half* __restrict__ S3,
                                                    const float* __restrict__ W,
                                                    const float* __restrict__ bias,
                                                    __half* __restrict__ out) {
    constexpr int PITCH = KS + 4;
    __shared__ float Ht[128 * PITCH];
    __shared__ float Wt[KS * 64];
    int t = threadIdx.x;
    int c4 = t & 15;
    int r8 = t >> 4;  // 0..15
    int r0 = blockIdx.x * 128;
    float acc[8][4];
#pragma unroll
    for (int j = 0; j < 8; ++j)
#pragma unroll
        for (int d = 0; d < 4; ++d) acc[j][d] = 0.f;

    const __half* Ss[4] = {S0, S1, S2, S3};
#pragma unroll
    for (int k = 0; k < 4; ++k) {
        const __half* S = Ss[k];
        for (int i = t; i < KS * 16; i += 256)
            *reinterpret_cast<float4*>(&Wt[i * 4]) =
                *reinterpret_cast<const float4*>(W + (size_t)k * KS * 64 + i * 4);
        // stage H tile: 128 rows x KS halves -> f32 LDS
        for (int i = t; i < 128 * (KS / 8); i += 256) {
            int r = i / (KS / 8);
            int c8 = i % (KS / 8);
            int row = r0 + r;
            float* hp = &Ht[r * PITCH + c8 * 8];
            if (row < Nn) {
                H8 u;
                u.f4 = *reinterpret_cast<const float4*>(S + (size_t)row * KS + c8 * 8);
#pragma unroll
                for (int j = 0; j < 8; ++j) hp[j] = __half2float(u.h[j]);
            } else {
#pragma unroll
                for (int j = 0; j < 8; ++j) hp[j] = 0.f;
            }
        }
        __syncthreads();
#pragma unroll 4
        for (int f = 0; f < KS; ++f) {
            float4 b4 = *reinterpret_cast<const float4*>(&Wt[f * 64 + c4 * 4]);
#pragma unroll
            for (int j = 0; j < 8; ++j) {
                float a = Ht[(r8 + 16 * j) * PITCH + f];
                acc[j][0] += a * b4.x;
                acc[j][1] += a * b4.y;
                acc[j][2] += a * b4.z;
                acc[j][3] += a * b4.w;
            }
        }
        __syncthreads();
    }
    float4 bi = *reinterpret_cast<const float4*>(bias + c4 * 4);
#pragma unroll
    for (int j = 0; j < 8; ++j) {
        int row = r0 + r8 + 16 * j;
        if (row < Nn) {
            H4 o;
            o.h[0] = __float2half(fmaxf(acc[j][0] + bi.x, 0.f));
            o.h[1] = __float2half(fmaxf(acc[j][1] + bi.y, 0.f));
            o.h[2] = __float2half(fmaxf(acc[j][2] + bi.z, 0.f));
            o.h[3] = __float2half(fmaxf(acc[j][3] + bi.w, 0.f));
            *reinterpret_cast<float2*>(out + (size_t)row * 64 + c4 * 4) = o.f2;
        }
    }
}

// ================= last conv + FC folding =================
// Wg[k][c][j] = Wh[2][k][c][:] @ fcW[:,j];  beff = bh[2] @ fcW + fcb
__global__ __launch_bounds__(256) void weff_kernel(const float* __restrict__ W,   // Wh[2]: [4][64][64]
                                                   const float* __restrict__ b,   // bh[2]: [64]
                                                   const float* __restrict__ fcW, // [64][4]
                                                   const float* __restrict__ fcb, // [4]
                                                   float* __restrict__ Wg,        // [4][64][4]
                                                   float* __restrict__ beff) {    // [4]
    int t = threadIdx.x;  // t = k*64 + c
    int k = t >> 6, c = t & 63;
    const float* wrow = W + (size_t)t * 64;
    float a0 = 0.f, a1 = 0.f, a2 = 0.f, a3 = 0.f;
    for (int d = 0; d < 64; ++d) {
        float w = wrow[d];
        a0 += w * fcW[d * 4 + 0];
        a1 += w * fcW[d * 4 + 1];
        a2 += w * fcW[d * 4 + 2];
        a3 += w * fcW[d * 4 + 3];
    }
    float4 o; o.x = a0; o.y = a1; o.z = a2; o.w = a3;
    *reinterpret_cast<float4*>(Wg + k * 256 + c * 4) = o;
    if (t < 4) {
        float s = fcb[t];
        for (int d = 0; d < 64; ++d) s += b[d] * fcW[d * 4 + t];
        beff[t] = s;
    }
}

// Gk[n][j] = sum_c h[n][c] * Wg[k][c][j]  -> four [N,4] f32 buffers (G stride N*4)
__global__ __launch_bounds__(256) void gemmG_kernel(const __half* __restrict__ h,
                                                    const float* __restrict__ Wg,
                                                    float* __restrict__ G) {
    __shared__ float Ht[64 * 65];
    __shared__ float Wl[1024];
    int t = threadIdx.x;
    int r0 = blockIdx.x * 64;
    for (int i = t; i < 256; i += 256)
        *reinterpret_cast<float4*>(&Wl[i * 4]) = *reinterpret_cast<const float4*>(Wg + i * 4);
    for (int i = t; i < 64 * 8; i += 256) {
        int r = i >> 3;
        int c8 = i & 7;
        int row = r0 + r;
        float* hp = &Ht[r * 65 + c8 * 8];
        if (row < Nn) {
            H8 u;
            u.f4 = *reinterpret_cast<const float4*>(h + (size_t)row * 64 + c8 * 8);
#pragma unroll
            for (int j = 0; j < 8; ++j) hp[j] = __half2float(u.h[j]);
        } else {
#pragma unroll
            for (int j = 0; j < 8; ++j) hp[j] = 0.f;
        }
    }
    __syncthreads();
    int r = t & 63;
    int k = t >> 6;
    float a0 = 0.f, a1 = 0.f, a2 = 0.f, a3 = 0.f;
#pragma unroll 8
    for (int c = 0; c < 64; ++c) {
        float hv = Ht[r * 65 + c];
        const float* wp = &Wl[k * 256 + c * 4];
        a0 += hv * wp[0];
        a1 += hv * wp[1];
        a2 += hv * wp[2];
        a3 += hv * wp[3];
    }
    int row = r0 + r;
    if (row < Nn) {
        float4 o; o.x = a0; o.y = a1; o.z = a2; o.w = a3;
        *reinterpret_cast<float4*>(G + (size_t)k * Nn * 4 + (size_t)row * 4) = o;
    }
}

// ================= host driver =================

extern "C" void kernel_launch(void* const* d_in, const int* in_sizes, int n_in,
                              void* d_out, int out_size, void* d_ws, size_t ws_size,
                              hipStream_t stream) {
    const float* x   = (const float*)d_in[0];
    const int*   ei  = (const int*)d_in[1];   // [2, E] int32
    const float* W0  = (const float*)d_in[2]; // [4,16,64]
    const float* b0  = (const float*)d_in[3]; // [64]
    const float* Wh  = (const float*)d_in[4]; // [3,4,64,64]
    const float* bh  = (const float*)d_in[5]; // [3,64]
    const float* fcW = (const float*)d_in[6]; // [64,4]
    const float* fcb = (const float*)d_in[7]; // [4]
    float* out = (float*)d_out;

    const int* src = ei;
    const int* dst = ei + Ne;

    // ws layout (16B-aligned regions):
    // rowptr[100004] | edge2[2E] | ghist[NS pad 305792] | bsum[512] | dinv[N]
    // | Wg[1024] | beff[16] | xh[N*16]h | H0..H3[N*64]h | G(6*N*4 f32)
    // Aliases: tmp (int2, bucket-sorted {src,dst}) = H2..H3 region; colsrc = H1 region.
    int*    rowptr = (int*)d_ws;
    int2*   edge2  = (int2*)(rowptr + 100004);
    int*    ghist  = (int*)(rowptr + 100004 + 2 * Ne);
    int*    bsum   = ghist + 305792;
    float*  dinv   = (float*)(bsum + 512);
    float*  Wg     = dinv + Nn;
    float*  beff   = Wg + 1024;
    __half* xh     = (__half*)(beff + 16);
    __half* H0     = xh + (size_t)Nn * NF;
    __half* H1     = H0 + (size_t)Nn * HID;
    __half* H2     = H1 + (size_t)Nn * HID;
    __half* H3     = H2 + (size_t)Nn * HID;
    float*  G      = (float*)(H3 + (size_t)Nn * HID);
    float*  G0     = G + 0 * (size_t)Nn * 4;
    float*  G1     = G + 1 * (size_t)Nn * 4;
    float*  G2     = G + 2 * (size_t)Nn * 4;
    float*  G3     = G + 3 * (size_t)Nn * 4;
    float*  T      = G + 4 * (size_t)Nn * 4;
    float*  T2     = G + 5 * (size_t)Nn * 4;
    int2*   tmp    = (int2*)H2;   // 12.8 MB, dead after bcsr
    int*    colsrc = (int*)H1;    // 6.4 MB, dead after fill

    const int egrid  = (Ne + 255) / 256;           // 6250
    const int s1grid = (NS + 1023) / 1024;         // 299
    const int s3grid = (NS + 255) / 256;           // 1195
    const int p64grid = (Nn + 15) / 16;            // 6250
    const int p16grid = (Nn + 31) / 32;            // 3125
    const int ggrid  = (Nn + 127) / 128;           // 782
    const int qgrid  = (Nn + 15) / 16;             // 6250
    const int Ggrid  = (Nn + 63) / 64;             // 1563
    const int cgrid  = (Nn * NF / 4 + 255) / 256;

    // --- CSR build: bucket sort, no global atomics ---
    bhist_kernel<<<NB1, 256, 0, stream>>>(dst, ghist);
    scan1g_kernel<<<s1grid, 256, 0, stream>>>(ghist, bsum);
    scan2g_kernel<<<1, 512, 0, stream>>>(bsum, s1grid);
    scan3g_kernel<<<s3grid, 256, 0, stream>>>(ghist, bsum);
    bscatter_kernel<<<NB1, 256, 0, stream>>>(src, dst, ghist, tmp);
    bcsr_kernel<<<NBUK, 256, 0, stream>>>(tmp, ghist, rowptr, dinv, colsrc);
    fill_kernel<<<egrid, 256, 0, stream>>>(colsrc, dinv, edge2);
    weff_kernel<<<1, 256, 0, stream>>>(Wh + 2 * 4 * 64 * 64, bh + 2 * 64, fcW, fcb, Wg, beff);
    xcvt_kernel<<<cgrid, 256, 0, stream>>>(x, xh);

    // --- conv0 (F=16 hops, relu) -> H0 ---
    pull16h_kernel<<<p16grid, 256, 0, stream>>>(xh, rowptr, edge2, dinv, H1);
    pull16h_kernel<<<p16grid, 256, 0, stream>>>(H1, rowptr, edge2, dinv, H2);
    pull16h_kernel<<<p16grid, 256, 0, stream>>>(H2, rowptr, edge2, dinv, H3);
    gemm4_kernel<NF><<<ggrid, 256, 0, stream>>>(xh, H1, H2, H3, W0, b0, H0);

    // --- conv1, conv2 (relu) : H0 -> H0 ---
    for (int l = 0; l < 2; ++l) {
        pull64h_kernel<<<p64grid, 256, 0, stream>>>(H0, rowptr, edge2, dinv, H1);
        pull64h_kernel<<<p64grid, 256, 0, stream>>>(H1, rowptr, edge2, dinv, H2);
        pull64h_kernel<<<p64grid, 256, 0, stream>>>(H2, rowptr, edge2, dinv, H3);
        gemm4_kernel<HID><<<ggrid, 256, 0, stream>>>(H0, H1, H2, H3,
                                                     Wh + (size_t)l * 4 * HID * HID,
                                                     bh + (size_t)l * HID, H0);
    }

    // --- conv3 + FC, folded to width 4 + Horner (f32 chain) ---
    // out = G0 + A(G1 + A(G2 + A*G3)) + beff
    gemmG_kernel<<<Ggrid, 256, 0, stream>>>(H0, Wg, G);
    pull4_kernel<0><<<qgrid, 256, 0, stream>>>(G3, G2, rowptr, edge2, dinv, beff, T);
    pull4_kernel<0><<<qgrid, 256, 0, stream>>>(T,  G1, rowptr, edge2, dinv, beff, T2);
    pull4_kernel<1><<<qgrid, 256, 0, stream>>>(T2, G0, rowptr, edge2, dinv, beff, out);
}

// Round 9
// 510.334 us; speedup vs baseline: 26.2864x; 1.1602x over previous
//
#include <hip/hip_runtime.h>
#include <hip/hip_fp16.h>

// Problem constants (match reference)
constexpr int Nn   = 100000;   // nodes
constexpr int Ne   = 1600000;  // edges
constexpr int NF   = 16;       // input features
constexpr int HID  = 64;
constexpr int NOUT = 4;

// Bucket-sort CSR build params
constexpr int NBUK  = 391;                     // dst>>8 buckets (99999>>8 = 390)
constexpr int CHUNK = 2048;                    // edges per phase-1 block
constexpr int NB1   = (Ne + CHUNK - 1) / CHUNK;  // 782
constexpr int NS    = NBUK * NB1;              // 305762 ghist entries
constexpr int STASH = 6144;                    // K2 LDS stash (48 KB)

union H8 { float4 f4; __half h[8]; };
union H4 { float2 f2; __half h[4]; };

typedef _Float16 f16x8 __attribute__((ext_vector_type(8)));
typedef float    f32x4 __attribute__((ext_vector_type(4)));

// ================= CSR build (atomic-free, 2-level bucket sort) =================

__global__ __launch_bounds__(256) void bhist_kernel(const int* __restrict__ dst,
                                                    int* __restrict__ ghist) {
    __shared__ int h[NBUK];
    int t = threadIdx.x;
    int b = blockIdx.x;
    for (int i = t; i < NBUK; i += 256) h[i] = 0;
    __syncthreads();
    int e0 = b * CHUNK;
    int e1 = (e0 + CHUNK < Ne) ? e0 + CHUNK : Ne;
    for (int e = e0 + t; e < e1; e += 256) atomicAdd(&h[dst[e] >> 8], 1);
    __syncthreads();
    for (int i = t; i < NBUK; i += 256) ghist[i * NB1 + b] = h[i];
}

__global__ __launch_bounds__(256) void scan1g_kernel(int* __restrict__ g,
                                                     int* __restrict__ bsum) {
    __shared__ int lds[256];
    int t = threadIdx.x;
    int base = blockIdx.x * 1024 + t * 4;
    int v0 = (base + 0 < NS) ? g[base + 0] : 0;
    int v1 = (base + 1 < NS) ? g[base + 1] : 0;
    int v2 = (base + 2 < NS) ? g[base + 2] : 0;
    int v3 = (base + 3 < NS) ? g[base + 3] : 0;
    lds[t] = v0 + v1 + v2 + v3;
    __syncthreads();
    for (int off = 1; off < 256; off <<= 1) {
        int a = lds[t];
        int b = (t >= off) ? lds[t - off] : 0;
        __syncthreads();
        lds[t] = a + b;
        __syncthreads();
    }
    int excl = (t > 0) ? lds[t - 1] : 0;
    if (base + 0 < NS) g[base + 0] = excl;
    if (base + 1 < NS) g[base + 1] = excl + v0;
    if (base + 2 < NS) g[base + 2] = excl + v0 + v1;
    if (base + 3 < NS) g[base + 3] = excl + v0 + v1 + v2;
    if (t == 255) bsum[blockIdx.x] = lds[255];
}

__global__ __launch_bounds__(512) void scan2g_kernel(int* __restrict__ bsum, int nb) {
    __shared__ int lds[512];
    int t = threadIdx.x;
    int v = (t < nb) ? bsum[t] : 0;
    lds[t] = v;
    __syncthreads();
    for (int off = 1; off < 512; off <<= 1) {
        int a = lds[t];
        int b = (t >= off) ? lds[t - off] : 0;
        __syncthreads();
        lds[t] = a + b;
        __syncthreads();
    }
    if (t < nb) bsum[t] = lds[t] - v;  // exclusive
}

__global__ __launch_bounds__(256) void scan3g_kernel(int* __restrict__ g,
                                                     const int* __restrict__ bsum) {
    int i = blockIdx.x * 256 + threadIdx.x;
    if (i < NS) g[i] += bsum[i >> 10];
}

__global__ __launch_bounds__(256) void bscatter_kernel(const int* __restrict__ src,
                                                       const int* __restrict__ dst,
                                                       const int* __restrict__ ghist,
                                                       int2* __restrict__ tmp) {
    __shared__ int hb[NBUK];
    __shared__ int cur[NBUK];
    int t = threadIdx.x;
    int b = blockIdx.x;
    for (int i = t; i < NBUK; i += 256) {
        hb[i] = ghist[i * NB1 + b];
        cur[i] = 0;
    }
    __syncthreads();
    int e0 = b * CHUNK;
    int e1 = (e0 + CHUNK < Ne) ? e0 + CHUNK : Ne;
    for (int e = e0 + t; e < e1; e += 256) {
        int d = dst[e];
        int s = src[e];
        int bin = d >> 8;
        int r = atomicAdd(&cur[bin], 1);
        tmp[hb[bin] + r] = make_int2(s, d);
    }
}

__global__ __launch_bounds__(256) void bcsr_kernel(const int2* __restrict__ tmp,
                                                   const int* __restrict__ ghist,
                                                   int* __restrict__ rowptr,
                                                   float* __restrict__ dinv,
                                                   int* __restrict__ colsrc) {
    __shared__ int2 stash[STASH];
    __shared__ int h[256];
    __shared__ int hs[256];
    __shared__ int cur[256];
    int t = threadIdx.x;
    int b = blockIdx.x;
    int lo = ghist[b * NB1];
    int hi = (b < NBUK - 1) ? ghist[(b + 1) * NB1] : Ne;
    int sz = hi - lo;
    h[t] = 0;
    cur[t] = 0;
    __syncthreads();
    for (int i = t; i < sz; i += 256) {
        int2 rec = tmp[lo + i];
        if (i < STASH) stash[i] = rec;
        atomicAdd(&h[rec.y & 255], 1);
    }
    __syncthreads();
    int myh = h[t];
    hs[t] = myh;
    __syncthreads();
    for (int off = 1; off < 256; off <<= 1) {
        int a = hs[t];
        int bb = (t >= off) ? hs[t - off] : 0;
        __syncthreads();
        hs[t] = a + bb;
        __syncthreads();
    }
    int excl = hs[t] - myh;
    __syncthreads();
    hs[t] = excl;
    int d = (b << 8) + t;
    if (d < Nn) {
        rowptr[d] = lo + excl;
        dinv[d] = (myh > 0) ? rsqrtf((float)myh) : 0.0f;
    }
    if (b == NBUK - 1 && t == 0) rowptr[Nn] = Ne;
    __syncthreads();
    for (int i = t; i < sz; i += 256) {
        int2 rec = (i < STASH) ? stash[i] : tmp[lo + i];
        int bin = rec.y & 255;
        int r = atomicAdd(&cur[bin], 1);
        colsrc[lo + hs[bin] + r] = rec.x;
    }
}

__global__ __launch_bounds__(256) void fill_kernel(const int* __restrict__ colsrc,
                                                   const float* __restrict__ dinv,
                                                   int2* __restrict__ edge2) {
    int e = blockIdx.x * 256 + threadIdx.x;
    if (e < Ne) {
        int s = colsrc[e];
        edge2[e] = make_int2(s, __float_as_int(dinv[s]));
    }
}

// x[N,16] f32 -> xh[N,16] fp16
__global__ __launch_bounds__(256) void xcvt_kernel(const float* __restrict__ x,
                                                   __half* __restrict__ xh) {
    int i = blockIdx.x * 256 + threadIdx.x;
    if (i < Nn * NF / 4) {
        float4 v = reinterpret_cast<const float4*>(x)[i];
        H4 o;
        o.h[0] = __float2half(v.x);
        o.h[1] = __float2half(v.y);
        o.h[2] = __float2half(v.z);
        o.h[3] = __float2half(v.w);
        reinterpret_cast<float2*>(xh)[i] = o.f2;
    }
}

// ================= pull-mode propagation (fp16 tables, f32 math) =================

// F=64: 4 nodes per wave (16 lanes each); QL=4 lanes x 16 halves; EO=4 edges in flight.
__global__ __launch_bounds__(256) void pull64h_kernel(const __half* __restrict__ hin,
                                                      const int* __restrict__ rowptr,
                                                      const int2* __restrict__ edge2,
                                                      const float* __restrict__ dinv,
                                                      __half* __restrict__ hout) {
    int lane = threadIdx.x & 63;
    int q  = lane & 3;
    int eo = (lane >> 2) & 3;
    int g  = lane >> 4;
    int n = blockIdx.x * 16 + (threadIdx.x >> 6) * 4 + g;
    if (n >= Nn) return;
    int r0 = rowptr[n];
    int r1 = rowptr[n + 1];
    float a[16];
#pragma unroll
    for (int j = 0; j < 16; ++j) a[j] = 0.f;
#pragma unroll 2
    for (int e = r0 + eo; e < r1; e += 4) {
        int2 ed = edge2[e];
        float w = __int_as_float(ed.y);
        const float4* rp = reinterpret_cast<const float4*>(hin + (size_t)ed.x * 64 + q * 16);
        H8 u0, u1;
        u0.f4 = rp[0];
        u1.f4 = rp[1];
#pragma unroll
        for (int j = 0; j < 8; ++j) a[j] += w * __half2float(u0.h[j]);
#pragma unroll
        for (int j = 0; j < 8; ++j) a[8 + j] += w * __half2float(u1.h[j]);
    }
#pragma unroll
    for (int off = 4; off <= 8; off <<= 1)
#pragma unroll
        for (int j = 0; j < 16; ++j) a[j] += __shfl_xor(a[j], off);
    if (eo == 0) {
        float dn = dinv[n];
        H8 o0, o1;
#pragma unroll
        for (int j = 0; j < 8; ++j) o0.h[j] = __float2half(a[j] * dn);
#pragma unroll
        for (int j = 0; j < 8; ++j) o1.h[j] = __float2half(a[8 + j] * dn);
        float4* op = reinterpret_cast<float4*>(hout + (size_t)n * 64 + q * 16);
        op[0] = o0.f4;
        op[1] = o1.f4;
    }
}

// F=16: 8 nodes per wave (8 lanes each); QL=2 lanes x 8 halves (16B); EO=4.
__global__ __launch_bounds__(256) void pull16h_kernel(const __half* __restrict__ hin,
                                                      const int* __restrict__ rowptr,
                                                      const int2* __restrict__ edge2,
                                                      const float* __restrict__ dinv,
                                                      __half* __restrict__ hout) {
    int lane = threadIdx.x & 63;
    int q  = lane & 1;
    int eo = (lane >> 1) & 3;
    int g  = lane >> 3;
    int n = blockIdx.x * 32 + (threadIdx.x >> 6) * 8 + g;
    if (n >= Nn) return;
    int r0 = rowptr[n];
    int r1 = rowptr[n + 1];
    float a[8];
#pragma unroll
    for (int j = 0; j < 8; ++j) a[j] = 0.f;
#pragma unroll 2
    for (int e = r0 + eo; e < r1; e += 4) {
        int2 ed = edge2[e];
        float w = __int_as_float(ed.y);
        H8 u;
        u.f4 = *reinterpret_cast<const float4*>(hin + (size_t)ed.x * 16 + q * 8);
#pragma unroll
        for (int j = 0; j < 8; ++j) a[j] += w * __half2float(u.h[j]);
    }
#pragma unroll
    for (int off = 2; off <= 4; off <<= 1)
#pragma unroll
        for (int j = 0; j < 8; ++j) a[j] += __shfl_xor(a[j], off);
    if (eo == 0) {
        float dn = dinv[n];
        H8 o;
#pragma unroll
        for (int j = 0; j < 8; ++j) o.h[j] = __float2half(a[j] * dn);
        *reinterpret_cast<float4*>(hout + (size_t)n * 16 + q * 8) = o.f4;
    }
}

// width-4 pull with fused add (f32 tables)
template <int ADDBIAS>
__global__ __launch_bounds__(256) void pull4_kernel(const float* __restrict__ uin,
                                                    const float* __restrict__ gadd,
                                                    const int* __restrict__ rowptr,
                                                    const int2* __restrict__ edge2,
                                                    const float* __restrict__ dinv,
                                                    const float* __restrict__ beff,
                                                    float* __restrict__ out) {
    int lane = threadIdx.x & 63;
    int eo = lane & 15;
    int n = blockIdx.x * 16 + ((threadIdx.x >> 6) << 2) + (lane >> 4);
    if (n >= Nn) return;
    int r0 = rowptr[n];
    int r1 = rowptr[n + 1];
    float ax = 0.f, ay = 0.f, az = 0.f, aw = 0.f;
    for (int e = r0 + eo; e < r1; e += 16) {
        int2 ed = edge2[e];
        float w = __int_as_float(ed.y);
        float4 v = *reinterpret_cast<const float4*>(uin + (size_t)ed.x * 4);
        ax += w * v.x;
        ay += w * v.y;
        az += w * v.z;
        aw += w * v.w;
    }
#pragma unroll
    for (int off = 1; off < 16; off <<= 1) {
        ax += __shfl_xor(ax, off);
        ay += __shfl_xor(ay, off);
        az += __shfl_xor(az, off);
        aw += __shfl_xor(aw, off);
    }
    if (eo == 0) {
        float dn = dinv[n];
        float4 g = *reinterpret_cast<const float4*>(gadd + (size_t)n * 4);
        float4 o;
        o.x = g.x + dn * ax;
        o.y = g.y + dn * ay;
        o.z = g.z + dn * az;
        o.w = g.w + dn * aw;
        if (ADDBIAS) {
            o.x += beff[0]; o.y += beff[1]; o.z += beff[2]; o.w += beff[3];
        }
        *reinterpret_cast<float4*>(out + (size_t)n * 4) = o;
    }
}

// ================= weight fragment prep =================
// Wfrag[ks][ct][lane][j] = fp16( W[k/KS][k%KS][ct*16 + (lane&15)] ), k = ks*32+(lane>>4)*8+j
template <int KS>
__global__ __launch_bounds__(256) void wfrag_kernel(const float* __restrict__ W,  // [4][KS][64]
                                                    __half* __restrict__ Wfrag) {
    constexpr int NT = (4 * KS / 32) * 4 * 64;
    int tid = blockIdx.x * 256 + threadIdx.x;
    if (tid >= NT) return;
    int l  = tid & 63;
    int ct = (tid >> 6) & 3;
    int ks = tid >> 8;
    int c  = ct * 16 + (l & 15);
    int kb = ks * 32 + (l >> 4) * 8;
    H8 o;
#pragma unroll
    for (int j = 0; j < 8; ++j) {
        int k = kb + j;
        o.h[j] = __float2half(W[(size_t)(k / KS) * KS * 64 + (size_t)(k % KS) * 64 + c]);
    }
    *reinterpret_cast<float4*>(Wfrag + (size_t)tid * 8) = o.f4;
}

// ================= fused 4-source MFMA GEMM =================
// out[N,64] = maybe_relu( concat_K(S0..S3)[N,4K] @ Wfrag + bias ), fp16 in/out, f32 acc.
// LDS-free: A fragments direct from global (block reads exactly the rows it writes),
// B fragments from the pre-swizzled Wfrag (L2-hot). 4 waves/block, wave = 32 rows.

template <int KS, int RELU>
__global__ __launch_bounds__(256) void gemm4m_kernel(const __half* __restrict__ S0,
                                                     const __half* __restrict__ S1,
                                                     const __half* __restrict__ S2,
                                                     const __half* __restrict__ S3,
                                                     const __half* __restrict__ Wfrag,
                                                     const float* __restrict__ bias,
                                                     __half* __restrict__ out) {
    constexpr int NKS = 4 * KS / 32;  // K-steps of 32
    int lane = threadIdx.x & 63;
    int wv = threadIdx.x >> 6;
    int base = blockIdx.x * 128 + wv * 32;
    int r = lane & 15;
    int qa = lane >> 4;            // 0..3
    int acol = qa * 8;             // col offset within the 32-wide k-tile
    const __half* Ss[4] = {S0, S1, S2, S3};
    f32x4 acc[2][4] = {};
    int row0 = base + r;       if (row0 >= Nn) row0 = Nn - 1;
    int row1 = base + 16 + r;  if (row1 >= Nn) row1 = Nn - 1;
#pragma unroll
    for (int ks = 0; ks < NKS; ++ks) {
        int k0 = ks * 32 + acol;
        const __half* Sa = Ss[k0 / KS];
        int col = k0 % KS;
        f16x8 a0 = *reinterpret_cast<const f16x8*>(Sa + (size_t)row0 * KS + col);
        f16x8 a1 = *reinterpret_cast<const f16x8*>(Sa + (size_t)row1 * KS + col);
        const __half* wp = Wfrag + ((size_t)(ks * 4) * 64 + lane) * 8;
#pragma unroll
        for (int ct = 0; ct < 4; ++ct) {
            f16x8 b = *reinterpret_cast<const f16x8*>(wp + (size_t)ct * 64 * 8);
            acc[0][ct] = __builtin_amdgcn_mfma_f32_16x16x32_f16(a0, b, acc[0][ct], 0, 0, 0);
            acc[1][ct] = __builtin_amdgcn_mfma_f32_16x16x32_f16(a1, b, acc[1][ct], 0, 0, 0);
        }
    }
    // epilogue: C/D layout col = lane&15, row = (lane>>4)*4 + reg
    int ccol = lane & 15;
    int rb = (lane >> 4) * 4;
#pragma unroll
    for (int rt = 0; rt < 2; ++rt) {
#pragma unroll
        for (int ct = 0; ct < 4; ++ct) {
            float bi = bias[ct * 16 + ccol];
#pragma unroll
            for (int i = 0; i < 4; ++i) {
                int row = base + rt * 16 + rb + i;
                if (row < Nn) {
                    float v = acc[rt][ct][i] + bi;
                    if (RELU) v = fmaxf(v, 0.f);
                    out[(size_t)row * 64 + ct * 16 + ccol] = __float2half(v);
                }
            }
        }
    }
}

// ================= last conv + FC folding =================
__global__ __launch_bounds__(256) void weff_kernel(const float* __restrict__ W,   // Wh[2]: [4][64][64]
                                                   const float* __restrict__ b,   // bh[2]: [64]
                                                   const float* __restrict__ fcW, // [64][4]
                                                   const float* __restrict__ fcb, // [4]
                                                   float* __restrict__ Wg,        // [4][64][4]
                                                   float* __restrict__ beff) {    // [4]
    int t = threadIdx.x;  // t = k*64 + c
    int k = t >> 6, c = t & 63;
    const float* wrow = W + (size_t)t * 64;
    float a0 = 0.f, a1 = 0.f, a2 = 0.f, a3 = 0.f;
    for (int d = 0; d < 64; ++d) {
        float w = wrow[d];
        a0 += w * fcW[d * 4 + 0];
        a1 += w * fcW[d * 4 + 1];
        a2 += w * fcW[d * 4 + 2];
        a3 += w * fcW[d * 4 + 3];
    }
    float4 o; o.x = a0; o.y = a1; o.z = a2; o.w = a3;
    *reinterpret_cast<float4*>(Wg + k * 256 + c * 4) = o;
    if (t < 4) {
        float s = fcb[t];
        for (int d = 0; d < 64; ++d) s += b[d] * fcW[d * 4 + t];
        beff[t] = s;
    }
}

// Gk[n][j] = sum_c h[n][c] * Wg[k][c][j]  -> four [N,4] f32 buffers (G stride N*4)
__global__ __launch_bounds__(256) void gemmG_kernel(const __half* __restrict__ h,
                                                    const float* __restrict__ Wg,
                                                    float* __restrict__ G) {
    __shared__ float Ht[64 * 65];
    __shared__ float Wl[1024];
    int t = threadIdx.x;
    int r0 = blockIdx.x * 64;
    for (int i = t; i < 256; i += 256)
        *reinterpret_cast<float4*>(&Wl[i * 4]) = *reinterpret_cast<const float4*>(Wg + i * 4);
    for (int i = t; i < 64 * 8; i += 256) {
        int r = i >> 3;
        int c8 = i & 7;
        int row = r0 + r;
        float* hp = &Ht[r * 65 + c8 * 8];
        if (row < Nn) {
            H8 u;
            u.f4 = *reinterpret_cast<const float4*>(h + (size_t)row * 64 + c8 * 8);
#pragma unroll
            for (int j = 0; j < 8; ++j) hp[j] = __half2float(u.h[j]);
        } else {
#pragma unroll
            for (int j = 0; j < 8; ++j) hp[j] = 0.f;
        }
    }
    __syncthreads();
    int r = t & 63;
    int k = t >> 6;
    float a0 = 0.f, a1 = 0.f, a2 = 0.f, a3 = 0.f;
#pragma unroll 8
    for (int c = 0; c < 64; ++c) {
        float hv = Ht[r * 65 + c];
        const float* wp = &Wl[k * 256 + c * 4];
        a0 += hv * wp[0];
        a1 += hv * wp[1];
        a2 += hv * wp[2];
        a3 += hv * wp[3];
    }
    int row = r0 + r;
    if (row < Nn) {
        float4 o; o.x = a0; o.y = a1; o.z = a2; o.w = a3;
        *reinterpret_cast<float4*>(G + (size_t)k * Nn * 4 + (size_t)row * 4) = o;
    }
}

// ================= host driver =================

extern "C" void kernel_launch(void* const* d_in, const int* in_sizes, int n_in,
                              void* d_out, int out_size, void* d_ws, size_t ws_size,
                              hipStream_t stream) {
    const float* x   = (const float*)d_in[0];
    const int*   ei  = (const int*)d_in[1];   // [2, E] int32
    const float* W0  = (const float*)d_in[2]; // [4,16,64]
    const float* b0  = (const float*)d_in[3]; // [64]
    const float* Wh  = (const float*)d_in[4]; // [3,4,64,64]
    const float* bh  = (const float*)d_in[5]; // [3,64]
    const float* fcW = (const float*)d_in[6]; // [64,4]
    const float* fcb = (const float*)d_in[7]; // [4]
    float* out = (float*)d_out;

    const int* src = ei;
    const int* dst = ei + Ne;

    // ws layout:
    // rowptr[100004] | edge2[2E] | ghist[305792] | bsum[512] | dinv[N] | Wg[1024] | beff[16]
    // | Wf0[4096]h | Wf1[16384]h | Wf2[16384]h | xh[N*16]h | H0..H3[N*64]h | G(6*N*4 f32)
    int*    rowptr = (int*)d_ws;
    int2*   edge2  = (int2*)(rowptr + 100004);
    int*    ghist  = (int*)(rowptr + 100004 + 2 * Ne);
    int*    bsum   = ghist + 305792;
    float*  dinv   = (float*)(bsum + 512);
    float*  Wg     = dinv + Nn;
    float*  beff   = Wg + 1024;
    __half* Wf0    = (__half*)(beff + 16);
    __half* Wf1    = Wf0 + 4096;
    __half* Wf2    = Wf1 + 16384;
    __half* xh     = Wf2 + 16384;
    __half* H0     = xh + (size_t)Nn * NF;
    __half* H1     = H0 + (size_t)Nn * HID;
    __half* H2     = H1 + (size_t)Nn * HID;
    __half* H3     = H2 + (size_t)Nn * HID;
    float*  G      = (float*)(H3 + (size_t)Nn * HID);
    float*  G0     = G + 0 * (size_t)Nn * 4;
    float*  G1     = G + 1 * (size_t)Nn * 4;
    float*  G2     = G + 2 * (size_t)Nn * 4;
    float*  G3     = G + 3 * (size_t)Nn * 4;
    float*  T      = G + 4 * (size_t)Nn * 4;
    float*  T2     = G + 5 * (size_t)Nn * 4;
    int2*   tmp    = (int2*)H2;   // 12.8 MB, dead after bcsr
    int*    colsrc = (int*)H1;    // 6.4 MB, dead after fill

    const int egrid  = (Ne + 255) / 256;           // 6250
    const int s1grid = (NS + 1023) / 1024;         // 299
    const int s3grid = (NS + 255) / 256;           // 1195
    const int p64grid = (Nn + 15) / 16;            // 6250
    const int p16grid = (Nn + 31) / 32;            // 3125
    const int ggrid  = (Nn + 127) / 128;           // 782
    const int qgrid  = (Nn + 15) / 16;             // 6250
    const int Ggrid  = (Nn + 63) / 64;             // 1563
    const int cgrid  = (Nn * NF / 4 + 255) / 256;

    // --- CSR build: bucket sort, no global atomics ---
    bhist_kernel<<<NB1, 256, 0, stream>>>(dst, ghist);
    scan1g_kernel<<<s1grid, 256, 0, stream>>>(ghist, bsum);
    scan2g_kernel<<<1, 512, 0, stream>>>(bsum, s1grid);
    scan3g_kernel<<<s3grid, 256, 0, stream>>>(ghist, bsum);
    bscatter_kernel<<<NB1, 256, 0, stream>>>(src, dst, ghist, tmp);
    bcsr_kernel<<<NBUK, 256, 0, stream>>>(tmp, ghist, rowptr, dinv, colsrc);
    fill_kernel<<<egrid, 256, 0, stream>>>(colsrc, dinv, edge2);
    weff_kernel<<<1, 256, 0, stream>>>(Wh + 2 * 4 * 64 * 64, bh + 2 * 64, fcW, fcb, Wg, beff);
    xcvt_kernel<<<cgrid, 256, 0, stream>>>(x, xh);
    wfrag_kernel<16><<<2, 256, 0, stream>>>(W0, Wf0);
    wfrag_kernel<64><<<8, 256, 0, stream>>>(Wh + 0 * 4 * 64 * 64, Wf1);
    wfrag_kernel<64><<<8, 256, 0, stream>>>(Wh + 1 * 4 * 64 * 64, Wf2);

    // --- conv0 (F=16 hops, relu) -> H0 ---
    pull16h_kernel<<<p16grid, 256, 0, stream>>>(xh, rowptr, edge2, dinv, H1);
    pull16h_kernel<<<p16grid, 256, 0, stream>>>(H1, rowptr, edge2, dinv, H2);
    pull16h_kernel<<<p16grid, 256, 0, stream>>>(H2, rowptr, edge2, dinv, H3);
    gemm4m_kernel<16, 1><<<ggrid, 256, 0, stream>>>(xh, H1, H2, H3, Wf0, b0, H0);

    // --- conv1, conv2 (relu) : H0 -> H0 ---
    for (int l = 0; l < 2; ++l) {
        pull64h_kernel<<<p64grid, 256, 0, stream>>>(H0, rowptr, edge2, dinv, H1);
        pull64h_kernel<<<p64grid, 256, 0, stream>>>(H1, rowptr, edge2, dinv, H2);
        pull64h_kernel<<<p64grid, 256, 0, stream>>>(H2, rowptr, edge2, dinv, H3);
        gemm4m_kernel<64, 1><<<ggrid, 256, 0, stream>>>(H0, H1, H2, H3,
                                                        (l == 0) ? Wf1 : Wf2,
                                                        bh + (size_t)l * HID, H0);
    }

    // --- conv3 + FC, folded to width 4 + Horner (f32 chain) ---
    // out = G0 + A(G1 + A(G2 + A*G3)) + beff
    gemmG_kernel<<<Ggrid, 256, 0, stream>>>(H0, Wg, G);
    pull4_kernel<0><<<qgrid, 256, 0, stream>>>(G3, G2, rowptr, edge2, dinv, beff, T);
    pull4_kernel<0><<<qgrid, 256, 0, stream>>>(T,  G1, rowptr, edge2, dinv, beff, T2);
    pull4_kernel<1><<<qgrid, 256, 0, stream>>>(T2, G0, rowptr, edge2, dinv, beff, out);
}

// Round 10
// 504.265 us; speedup vs baseline: 26.6028x; 1.0120x over previous
//
#include <hip/hip_runtime.h>
#include <hip/hip_fp16.h>

// Problem constants (match reference)
constexpr int Nn   = 100000;   // nodes
constexpr int Ne   = 1600000;  // edges
constexpr int NF   = 16;       // input features
constexpr int HID  = 64;
constexpr int NOUT = 4;

// Bucket-sort CSR build params
constexpr int NBUK  = 391;                     // dst>>8 buckets (99999>>8 = 390)
constexpr int CHUNK = 2048;                    // edges per phase-1 block
constexpr int NB1   = (Ne + CHUNK - 1) / CHUNK;  // 782
constexpr int NS    = NBUK * NB1;              // 305762 ghist entries
constexpr int STASH = 6144;                    // K2 LDS stash (48 KB)

union H8 { float4 f4; __half h[8]; };
union H4 { float2 f2; __half h[4]; };

typedef _Float16 f16x8 __attribute__((ext_vector_type(8)));
typedef float    f32x4 __attribute__((ext_vector_type(4)));

// ================= CSR build (atomic-free, 2-level bucket sort) =================

__global__ __launch_bounds__(256) void bhist_kernel(const int* __restrict__ dst,
                                                    int* __restrict__ ghist) {
    __shared__ int h[NBUK];
    int t = threadIdx.x;
    int b = blockIdx.x;
    for (int i = t; i < NBUK; i += 256) h[i] = 0;
    __syncthreads();
    int e0 = b * CHUNK;
    int e1 = (e0 + CHUNK < Ne) ? e0 + CHUNK : Ne;
    for (int e = e0 + t; e < e1; e += 256) atomicAdd(&h[dst[e] >> 8], 1);
    __syncthreads();
    for (int i = t; i < NBUK; i += 256) ghist[i * NB1 + b] = h[i];
}

__global__ __launch_bounds__(256) void scan1g_kernel(int* __restrict__ g,
                                                     int* __restrict__ bsum) {
    __shared__ int lds[256];
    int t = threadIdx.x;
    int base = blockIdx.x * 1024 + t * 4;
    int v0 = (base + 0 < NS) ? g[base + 0] : 0;
    int v1 = (base + 1 < NS) ? g[base + 1] : 0;
    int v2 = (base + 2 < NS) ? g[base + 2] : 0;
    int v3 = (base + 3 < NS) ? g[base + 3] : 0;
    lds[t] = v0 + v1 + v2 + v3;
    __syncthreads();
    for (int off = 1; off < 256; off <<= 1) {
        int a = lds[t];
        int b = (t >= off) ? lds[t - off] : 0;
        __syncthreads();
        lds[t] = a + b;
        __syncthreads();
    }
    int excl = (t > 0) ? lds[t - 1] : 0;
    if (base + 0 < NS) g[base + 0] = excl;
    if (base + 1 < NS) g[base + 1] = excl + v0;
    if (base + 2 < NS) g[base + 2] = excl + v0 + v1;
    if (base + 3 < NS) g[base + 3] = excl + v0 + v1 + v2;
    if (t == 255) bsum[blockIdx.x] = lds[255];
}

__global__ __launch_bounds__(512) void scan2g_kernel(int* __restrict__ bsum, int nb) {
    __shared__ int lds[512];
    int t = threadIdx.x;
    int v = (t < nb) ? bsum[t] : 0;
    lds[t] = v;
    __syncthreads();
    for (int off = 1; off < 512; off <<= 1) {
        int a = lds[t];
        int b = (t >= off) ? lds[t - off] : 0;
        __syncthreads();
        lds[t] = a + b;
        __syncthreads();
    }
    if (t < nb) bsum[t] = lds[t] - v;  // exclusive
}

__global__ __launch_bounds__(256) void scan3g_kernel(int* __restrict__ g,
                                                     const int* __restrict__ bsum) {
    int i = blockIdx.x * 256 + threadIdx.x;
    if (i < NS) g[i] += bsum[i >> 10];
}

__global__ __launch_bounds__(256) void bscatter_kernel(const int* __restrict__ src,
                                                       const int* __restrict__ dst,
                                                       const int* __restrict__ ghist,
                                                       int2* __restrict__ tmp) {
    __shared__ int hb[NBUK];
    __shared__ int cur[NBUK];
    int t = threadIdx.x;
    int b = blockIdx.x;
    for (int i = t; i < NBUK; i += 256) {
        hb[i] = ghist[i * NB1 + b];
        cur[i] = 0;
    }
    __syncthreads();
    int e0 = b * CHUNK;
    int e1 = (e0 + CHUNK < Ne) ? e0 + CHUNK : Ne;
    for (int e = e0 + t; e < e1; e += 256) {
        int d = dst[e];
        int s = src[e];
        int bin = d >> 8;
        int r = atomicAdd(&cur[bin], 1);
        tmp[hb[bin] + r] = make_int2(s, d);
    }
}

__global__ __launch_bounds__(256) void bcsr_kernel(const int2* __restrict__ tmp,
                                                   const int* __restrict__ ghist,
                                                   int* __restrict__ rowptr,
                                                   float* __restrict__ dinv,
                                                   int* __restrict__ colsrc) {
    __shared__ int2 stash[STASH];
    __shared__ int h[256];
    __shared__ int hs[256];
    __shared__ int cur[256];
    int t = threadIdx.x;
    int b = blockIdx.x;
    int lo = ghist[b * NB1];
    int hi = (b < NBUK - 1) ? ghist[(b + 1) * NB1] : Ne;
    int sz = hi - lo;
    h[t] = 0;
    cur[t] = 0;
    __syncthreads();
    for (int i = t; i < sz; i += 256) {
        int2 rec = tmp[lo + i];
        if (i < STASH) stash[i] = rec;
        atomicAdd(&h[rec.y & 255], 1);
    }
    __syncthreads();
    int myh = h[t];
    hs[t] = myh;
    __syncthreads();
    for (int off = 1; off < 256; off <<= 1) {
        int a = hs[t];
        int bb = (t >= off) ? hs[t - off] : 0;
        __syncthreads();
        hs[t] = a + bb;
        __syncthreads();
    }
    int excl = hs[t] - myh;
    __syncthreads();
    hs[t] = excl;
    int d = (b << 8) + t;
    if (d < Nn) {
        rowptr[d] = lo + excl;
        dinv[d] = (myh > 0) ? rsqrtf((float)myh) : 0.0f;
    }
    if (b == NBUK - 1 && t == 0) rowptr[Nn] = Ne;
    __syncthreads();
    for (int i = t; i < sz; i += 256) {
        int2 rec = (i < STASH) ? stash[i] : tmp[lo + i];
        int bin = rec.y & 255;
        int r = atomicAdd(&cur[bin], 1);
        colsrc[lo + hs[bin] + r] = rec.x;
    }
}

__global__ __launch_bounds__(256) void fill_kernel(const int* __restrict__ colsrc,
                                                   const float* __restrict__ dinv,
                                                   int2* __restrict__ edge2) {
    int e = blockIdx.x * 256 + threadIdx.x;
    if (e < Ne) {
        int s = colsrc[e];
        edge2[e] = make_int2(s, __float_as_int(dinv[s]));
    }
}

// x[N,16] f32 -> xh[N,16] fp16
__global__ __launch_bounds__(256) void xcvt_kernel(const float* __restrict__ x,
                                                   __half* __restrict__ xh) {
    int i = blockIdx.x * 256 + threadIdx.x;
    if (i < Nn * NF / 4) {
        float4 v = reinterpret_cast<const float4*>(x)[i];
        H4 o;
        o.h[0] = __float2half(v.x);
        o.h[1] = __float2half(v.y);
        o.h[2] = __float2half(v.z);
        o.h[3] = __float2half(v.w);
        reinterpret_cast<float2*>(xh)[i] = o.f2;
    }
}

// ================= pull-mode propagation (fp16 tables, f32 math) =================
// 2-deep software pipeline: edge record i+2 and row gather i+1 in flight while
// consuming edge i. Dummy slots gather row 0 with w=0 (harmless, L2-hot).

// F=64: 4 nodes per wave (16 lanes each); QL=4 lanes x 16 halves; EO=4 edges in flight.
__global__ __launch_bounds__(256) void pull64h_kernel(const __half* __restrict__ hin,
                                                      const int* __restrict__ rowptr,
                                                      const int2* __restrict__ edge2,
                                                      const float* __restrict__ dinv,
                                                      __half* __restrict__ hout) {
    int lane = threadIdx.x & 63;
    int q  = lane & 3;
    int eo = (lane >> 2) & 3;
    int g  = lane >> 4;
    int n = blockIdx.x * 16 + (threadIdx.x >> 6) * 4 + g;
    if (n >= Nn) return;
    int r0 = rowptr[n];
    int r1 = rowptr[n + 1];
    float a[16];
#pragma unroll
    for (int j = 0; j < 16; ++j) a[j] = 0.f;

    int e = r0 + eo;
    int2 ed0 = (e < r1) ? edge2[e] : make_int2(0, 0);
    int2 ed1 = (e + 4 < r1) ? edge2[e + 4] : make_int2(0, 0);
    const float4* rp0 = reinterpret_cast<const float4*>(hin + (size_t)ed0.x * 64 + q * 16);
    float4 ga = rp0[0], gb = rp0[1];
#pragma unroll 1
    for (; e < r1; e += 4) {
        int2 ed2 = (e + 8 < r1) ? edge2[e + 8] : make_int2(0, 0);
        const float4* rp1 = reinterpret_cast<const float4*>(hin + (size_t)ed1.x * 64 + q * 16);
        float4 na = rp1[0], nb = rp1[1];
        float w = __int_as_float(ed0.y);
        H8 u0, u1;
        u0.f4 = ga;
        u1.f4 = gb;
#pragma unroll
        for (int j = 0; j < 8; ++j) a[j] += w * __half2float(u0.h[j]);
#pragma unroll
        for (int j = 0; j < 8; ++j) a[8 + j] += w * __half2float(u1.h[j]);
        ed0 = ed1; ed1 = ed2; ga = na; gb = nb;
    }
#pragma unroll
    for (int off = 4; off <= 8; off <<= 1)
#pragma unroll
        for (int j = 0; j < 16; ++j) a[j] += __shfl_xor(a[j], off);
    if (eo == 0) {
        float dn = dinv[n];
        H8 o0, o1;
#pragma unroll
        for (int j = 0; j < 8; ++j) o0.h[j] = __float2half(a[j] * dn);
#pragma unroll
        for (int j = 0; j < 8; ++j) o1.h[j] = __float2half(a[8 + j] * dn);
        float4* op = reinterpret_cast<float4*>(hout + (size_t)n * 64 + q * 16);
        op[0] = o0.f4;
        op[1] = o1.f4;
    }
}

// F=16: 8 nodes per wave (8 lanes each); QL=2 lanes x 8 halves (16B); EO=4.
__global__ __launch_bounds__(256) void pull16h_kernel(const __half* __restrict__ hin,
                                                      const int* __restrict__ rowptr,
                                                      const int2* __restrict__ edge2,
                                                      const float* __restrict__ dinv,
                                                      __half* __restrict__ hout) {
    int lane = threadIdx.x & 63;
    int q  = lane & 1;
    int eo = (lane >> 1) & 3;
    int g  = lane >> 3;
    int n = blockIdx.x * 32 + (threadIdx.x >> 6) * 8 + g;
    if (n >= Nn) return;
    int r0 = rowptr[n];
    int r1 = rowptr[n + 1];
    float a[8];
#pragma unroll
    for (int j = 0; j < 8; ++j) a[j] = 0.f;

    int e = r0 + eo;
    int2 ed0 = (e < r1) ? edge2[e] : make_int2(0, 0);
    int2 ed1 = (e + 4 < r1) ? edge2[e + 4] : make_int2(0, 0);
    float4 ga = *reinterpret_cast<const float4*>(hin + (size_t)ed0.x * 16 + q * 8);
#pragma unroll 1
    for (; e < r1; e += 4) {
        int2 ed2 = (e + 8 < r1) ? edge2[e + 8] : make_int2(0, 0);
        float4 na = *reinterpret_cast<const float4*>(hin + (size_t)ed1.x * 16 + q * 8);
        float w = __int_as_float(ed0.y);
        H8 u;
        u.f4 = ga;
#pragma unroll
        for (int j = 0; j < 8; ++j) a[j] += w * __half2float(u.h[j]);
        ed0 = ed1; ed1 = ed2; ga = na;
    }
#pragma unroll
    for (int off = 2; off <= 4; off <<= 1)
#pragma unroll
        for (int j = 0; j < 8; ++j) a[j] += __shfl_xor(a[j], off);
    if (eo == 0) {
        float dn = dinv[n];
        H8 o;
#pragma unroll
        for (int j = 0; j < 8; ++j) o.h[j] = __float2half(a[j] * dn);
        *reinterpret_cast<float4*>(hout + (size_t)n * 16 + q * 8) = o.f4;
    }
}

// width-4 pull with fused add (f32 tables), 2-deep pipeline
template <int ADDBIAS>
__global__ __launch_bounds__(256) void pull4_kernel(const float* __restrict__ uin,
                                                    const float* __restrict__ gadd,
                                                    const int* __restrict__ rowptr,
                                                    const int2* __restrict__ edge2,
                                                    const float* __restrict__ dinv,
                                                    const float* __restrict__ beff,
                                                    float* __restrict__ out) {
    int lane = threadIdx.x & 63;
    int eo = lane & 15;
    int n = blockIdx.x * 16 + ((threadIdx.x >> 6) << 2) + (lane >> 4);
    if (n >= Nn) return;
    int r0 = rowptr[n];
    int r1 = rowptr[n + 1];
    float ax = 0.f, ay = 0.f, az = 0.f, aw = 0.f;

    int e = r0 + eo;
    int2 ed0 = (e < r1) ? edge2[e] : make_int2(0, 0);
    int2 ed1 = (e + 16 < r1) ? edge2[e + 16] : make_int2(0, 0);
    float4 ga = *reinterpret_cast<const float4*>(uin + (size_t)ed0.x * 4);
#pragma unroll 1
    for (; e < r1; e += 16) {
        int2 ed2 = (e + 32 < r1) ? edge2[e + 32] : make_int2(0, 0);
        float4 na = *reinterpret_cast<const float4*>(uin + (size_t)ed1.x * 4);
        float w = __int_as_float(ed0.y);
        ax += w * ga.x;
        ay += w * ga.y;
        az += w * ga.z;
        aw += w * ga.w;
        ed0 = ed1; ed1 = ed2; ga = na;
    }
#pragma unroll
    for (int off = 1; off < 16; off <<= 1) {
        ax += __shfl_xor(ax, off);
        ay += __shfl_xor(ay, off);
        az += __shfl_xor(az, off);
        aw += __shfl_xor(aw, off);
    }
    if (eo == 0) {
        float dn = dinv[n];
        float4 g = *reinterpret_cast<const float4*>(gadd + (size_t)n * 4);
        float4 o;
        o.x = g.x + dn * ax;
        o.y = g.y + dn * ay;
        o.z = g.z + dn * az;
        o.w = g.w + dn * aw;
        if (ADDBIAS) {
            o.x += beff[0]; o.y += beff[1]; o.z += beff[2]; o.w += beff[3];
        }
        *reinterpret_cast<float4*>(out + (size_t)n * 4) = o;
    }
}

// ================= weight fragment prep =================
template <int KS>
__global__ __launch_bounds__(256) void wfrag_kernel(const float* __restrict__ W,  // [4][KS][64]
                                                    __half* __restrict__ Wfrag) {
    constexpr int NT = (4 * KS / 32) * 4 * 64;
    int tid = blockIdx.x * 256 + threadIdx.x;
    if (tid >= NT) return;
    int l  = tid & 63;
    int ct = (tid >> 6) & 3;
    int ks = tid >> 8;
    int c  = ct * 16 + (l & 15);
    int kb = ks * 32 + (l >> 4) * 8;
    H8 o;
#pragma unroll
    for (int j = 0; j < 8; ++j) {
        int k = kb + j;
        o.h[j] = __float2half(W[(size_t)(k / KS) * KS * 64 + (size_t)(k % KS) * 64 + c]);
    }
    *reinterpret_cast<float4*>(Wfrag + (size_t)tid * 8) = o.f4;
}

// ================= fused 4-source MFMA GEMM =================
template <int KS, int RELU>
__global__ __launch_bounds__(256) void gemm4m_kernel(const __half* __restrict__ S0,
                                                     const __half* __restrict__ S1,
                                                     const __half* __restrict__ S2,
                                                     const __half* __restrict__ S3,
                                                     const __half* __restrict__ Wfrag,
                                                     const float* __restrict__ bias,
                                                     __half* __restrict__ out) {
    constexpr int NKS = 4 * KS / 32;  // K-steps of 32
    int lane = threadIdx.x & 63;
    int wv = threadIdx.x >> 6;
    int base = blockIdx.x * 128 + wv * 32;
    int r = lane & 15;
    int qa = lane >> 4;
    int acol = qa * 8;
    const __half* Ss[4] = {S0, S1, S2, S3};
    f32x4 acc[2][4] = {};
    int row0 = base + r;       if (row0 >= Nn) row0 = Nn - 1;
    int row1 = base + 16 + r;  if (row1 >= Nn) row1 = Nn - 1;
#pragma unroll
    for (int ks = 0; ks < NKS; ++ks) {
        int k0 = ks * 32 + acol;
        const __half* Sa = Ss[k0 / KS];
        int col = k0 % KS;
        f16x8 a0 = *reinterpret_cast<const f16x8*>(Sa + (size_t)row0 * KS + col);
        f16x8 a1 = *reinterpret_cast<const f16x8*>(Sa + (size_t)row1 * KS + col);
        const __half* wp = Wfrag + ((size_t)(ks * 4) * 64 + lane) * 8;
#pragma unroll
        for (int ct = 0; ct < 4; ++ct) {
            f16x8 b = *reinterpret_cast<const f16x8*>(wp + (size_t)ct * 64 * 8);
            acc[0][ct] = __builtin_amdgcn_mfma_f32_16x16x32_f16(a0, b, acc[0][ct], 0, 0, 0);
            acc[1][ct] = __builtin_amdgcn_mfma_f32_16x16x32_f16(a1, b, acc[1][ct], 0, 0, 0);
        }
    }
    int ccol = lane & 15;
    int rb = (lane >> 4) * 4;
#pragma unroll
    for (int rt = 0; rt < 2; ++rt) {
#pragma unroll
        for (int ct = 0; ct < 4; ++ct) {
            float bi = bias[ct * 16 + ccol];
#pragma unroll
            for (int i = 0; i < 4; ++i) {
                int row = base + rt * 16 + rb + i;
                if (row < Nn) {
                    float v = acc[rt][ct][i] + bi;
                    if (RELU) v = fmaxf(v, 0.f);
                    out[(size_t)row * 64 + ct * 16 + ccol] = __float2half(v);
                }
            }
        }
    }
}

// ================= last conv + FC folding =================
__global__ __launch_bounds__(256) void weff_kernel(const float* __restrict__ W,   // Wh[2]: [4][64][64]
                                                   const float* __restrict__ b,   // bh[2]: [64]
                                                   const float* __restrict__ fcW, // [64][4]
                                                   const float* __restrict__ fcb, // [4]
                                                   float* __restrict__ Wg,        // [4][64][4]
                                                   float* __restrict__ beff) {    // [4]
    int t = threadIdx.x;  // t = k*64 + c
    int k = t >> 6, c = t & 63;
    const float* wrow = W + (size_t)t * 64;
    float a0 = 0.f, a1 = 0.f, a2 = 0.f, a3 = 0.f;
    for (int d = 0; d < 64; ++d) {
        float w = wrow[d];
        a0 += w * fcW[d * 4 + 0];
        a1 += w * fcW[d * 4 + 1];
        a2 += w * fcW[d * 4 + 2];
        a3 += w * fcW[d * 4 + 3];
    }
    float4 o; o.x = a0; o.y = a1; o.z = a2; o.w = a3;
    *reinterpret_cast<float4*>(Wg + k * 256 + c * 4) = o;
    if (t < 4) {
        float s = fcb[t];
        for (int d = 0; d < 64; ++d) s += b[d] * fcW[d * 4 + t];
        beff[t] = s;
    }
}

// Gk[n][j] = sum_c h[n][c] * Wg[k][c][j]
__global__ __launch_bounds__(256) void gemmG_kernel(const __half* __restrict__ h,
                                                    const float* __restrict__ Wg,
                                                    float* __restrict__ G) {
    __shared__ float Ht[64 * 65];
    __shared__ float Wl[1024];
    int t = threadIdx.x;
    int r0 = blockIdx.x * 64;
    for (int i = t; i < 256; i += 256)
        *reinterpret_cast<float4*>(&Wl[i * 4]) = *reinterpret_cast<const float4*>(Wg + i * 4);
    for (int i = t; i < 64 * 8; i += 256) {
        int r = i >> 3;
        int c8 = i & 7;
        int row = r0 + r;
        float* hp = &Ht[r * 65 + c8 * 8];
        if (row < Nn) {
            H8 u;
            u.f4 = *reinterpret_cast<const float4*>(h + (size_t)row * 64 + c8 * 8);
#pragma unroll
            for (int j = 0; j < 8; ++j) hp[j] = __half2float(u.h[j]);
        } else {
#pragma unroll
            for (int j = 0; j < 8; ++j) hp[j] = 0.f;
        }
    }
    __syncthreads();
    int r = t & 63;
    int k = t >> 6;
    float a0 = 0.f, a1 = 0.f, a2 = 0.f, a3 = 0.f;
#pragma unroll 8
    for (int c = 0; c < 64; ++c) {
        float hv = Ht[r * 65 + c];
        const float* wp = &Wl[k * 256 + c * 4];
        a0 += hv * wp[0];
        a1 += hv * wp[1];
        a2 += hv * wp[2];
        a3 += hv * wp[3];
    }
    int row = r0 + r;
    if (row < Nn) {
        float4 o; o.x = a0; o.y = a1; o.z = a2; o.w = a3;
        *reinterpret_cast<float4*>(G + (size_t)k * Nn * 4 + (size_t)row * 4) = o;
    }
}

// ================= host driver =================

extern "C" void kernel_launch(void* const* d_in, const int* in_sizes, int n_in,
                              void* d_out, int out_size, void* d_ws, size_t ws_size,
                              hipStream_t stream) {
    const float* x   = (const float*)d_in[0];
    const int*   ei  = (const int*)d_in[1];   // [2, E] int32
    const float* W0  = (const float*)d_in[2]; // [4,16,64]
    const float* b0  = (const float*)d_in[3]; // [64]
    const float* Wh  = (const float*)d_in[4]; // [3,4,64,64]
    const float* bh  = (const float*)d_in[5]; // [3,64]
    const float* fcW = (const float*)d_in[6]; // [64,4]
    const float* fcb = (const float*)d_in[7]; // [4]
    float* out = (float*)d_out;

    const int* src = ei;
    const int* dst = ei + Ne;

    // ws layout:
    // rowptr[100004] | edge2[2E] | ghist[305792] | bsum[512] | dinv[N] | Wg[1024] | beff[16]
    // | Wf0[4096]h | Wf1[16384]h | Wf2[16384]h | xh[N*16]h | H0..H3[N*64]h | G(6*N*4 f32)
    int*    rowptr = (int*)d_ws;
    int2*   edge2  = (int2*)(rowptr + 100004);
    int*    ghist  = (int*)(rowptr + 100004 + 2 * Ne);
    int*    bsum   = ghist + 305792;
    float*  dinv   = (float*)(bsum + 512);
    float*  Wg     = dinv + Nn;
    float*  beff   = Wg + 1024;
    __half* Wf0    = (__half*)(beff + 16);
    __half* Wf1    = Wf0 + 4096;
    __half* Wf2    = Wf1 + 16384;
    __half* xh     = Wf2 + 16384;
    __half* H0     = xh + (size_t)Nn * NF;
    __half* H1     = H0 + (size_t)Nn * HID;
    __half* H2     = H1 + (size_t)Nn * HID;
    __half* H3     = H2 + (size_t)Nn * HID;
    float*  G      = (float*)(H3 + (size_t)Nn * HID);
    float*  G0     = G + 0 * (size_t)Nn * 4;
    float*  G1     = G + 1 * (size_t)Nn * 4;
    float*  G2     = G + 2 * (size_t)Nn * 4;
    float*  G3     = G + 3 * (size_t)Nn * 4;
    float*  T      = G + 4 * (size_t)Nn * 4;
    float*  T2     = G + 5 * (size_t)Nn * 4;
    int2*   tmp    = (int2*)H2;   // 12.8 MB, dead after bcsr
    int*    colsrc = (int*)H1;    // 6.4 MB, dead after fill

    const int egrid  = (Ne + 255) / 256;           // 6250
    const int s1grid = (NS + 1023) / 1024;         // 299
    const int s3grid = (NS + 255) / 256;           // 1195
    const int p64grid = (Nn + 15) / 16;            // 6250
    const int p16grid = (Nn + 31) / 32;            // 3125
    const int ggrid  = (Nn + 127) / 128;           // 782
    const int qgrid  = (Nn + 15) / 16;             // 6250
    const int Ggrid  = (Nn + 63) / 64;             // 1563
    const int cgrid  = (Nn * NF / 4 + 255) / 256;

    // --- CSR build: bucket sort, no global atomics ---
    bhist_kernel<<<NB1, 256, 0, stream>>>(dst, ghist);
    scan1g_kernel<<<s1grid, 256, 0, stream>>>(ghist, bsum);
    scan2g_kernel<<<1, 512, 0, stream>>>(bsum, s1grid);
    scan3g_kernel<<<s3grid, 256, 0, stream>>>(ghist, bsum);
    bscatter_kernel<<<NB1, 256, 0, stream>>>(src, dst, ghist, tmp);
    bcsr_kernel<<<NBUK, 256, 0, stream>>>(tmp, ghist, rowptr, dinv, colsrc);
    fill_kernel<<<egrid, 256, 0, stream>>>(colsrc, dinv, edge2);
    weff_kernel<<<1, 256, 0, stream>>>(Wh + 2 * 4 * 64 * 64, bh + 2 * 64, fcW, fcb, Wg, beff);
    xcvt_kernel<<<cgrid, 256, 0, stream>>>(x, xh);
    wfrag_kernel<16><<<2, 256, 0, stream>>>(W0, Wf0);
    wfrag_kernel<64><<<8, 256, 0, stream>>>(Wh + 0 * 4 * 64 * 64, Wf1);
    wfrag_kernel<64><<<8, 256, 0, stream>>>(Wh + 1 * 4 * 64 * 64, Wf2);

    // --- conv0 (F=16 hops, relu) -> H0 ---
    pull16h_kernel<<<p16grid, 256, 0, stream>>>(xh, rowptr, edge2, dinv, H1);
    pull16h_kernel<<<p16grid, 256, 0, stream>>>(H1, rowptr, edge2, dinv, H2);
    pull16h_kernel<<<p16grid, 256, 0, stream>>>(H2, rowptr, edge2, dinv, H3);
    gemm4m_kernel<16, 1><<<ggrid, 256, 0, stream>>>(xh, H1, H2, H3, Wf0, b0, H0);

    // --- conv1, conv2 (relu) : H0 -> H0 ---
    for (int l = 0; l < 2; ++l) {
        pull64h_kernel<<<p64grid, 256, 0, stream>>>(H0, rowptr, edge2, dinv, H1);
        pull64h_kernel<<<p64grid, 256, 0, stream>>>(H1, rowptr, edge2, dinv, H2);
        pull64h_kernel<<<p64grid, 256, 0, stream>>>(H2, rowptr, edge2, dinv, H3);
        gemm4m_kernel<64, 1><<<ggrid, 256, 0, stream>>>(H0, H1, H2, H3,
                                                        (l == 0) ? Wf1 : Wf2,
                                                        bh + (size_t)l * HID, H0);
    }

    // --- conv3 + FC, folded to width 4 + Horner (f32 chain) ---
    // out = G0 + A(G1 + A(G2 + A*G3)) + beff
    gemmG_kernel<<<Ggrid, 256, 0, stream>>>(H0, Wg, G);
    pull4_kernel<0><<<qgrid, 256, 0, stream>>>(G3, G2, rowptr, edge2, dinv, beff, T);
    pull4_kernel<0><<<qgrid, 256, 0, stream>>>(T,  G1, rowptr, edge2, dinv, beff, T2);
    pull4_kernel<1><<<qgrid, 256, 0, stream>>>(T2, G0, rowptr, edge2, dinv, beff, out);
}